// Round 5
// baseline (502.401 us; speedup 1.0000x reference)
//
#include <hip/hip_runtime.h>
#include <hip/hip_bf16.h>
#include <cstdint>
#include <cstddef>

#define DEV __device__ __forceinline__

// problem constants: B=128, S=512, V=30000, DS=64, DF=300, H=600, BB=256

typedef __attribute__((ext_vector_type(8))) short bf16x8;
typedef __attribute__((ext_vector_type(4))) float f32x4;

DEV float geluf(float x){ return 0.5f*x*(1.f + erff(x*0.7071067811865475f)); }

DEV float blk_sum512(float* red, int t, float v){
  red[t] = v; __syncthreads();
  for (int o = 256; o > 0; o >>= 1){ if (t < o) red[t] += red[t+o]; __syncthreads(); }
  float r = red[0]; __syncthreads(); return r;
}
DEV float blk_max512(float* red, int t, float v){
  red[t] = v; __syncthreads();
  for (int o = 256; o > 0; o >>= 1){ if (t < o) red[t] = fmaxf(red[t], red[t+o]); __syncthreads(); }
  float r = red[0]; __syncthreads(); return r;
}

DEV ushort f2bf(float v){ __hip_bfloat16 h = __float2bfloat16(v); return *(ushort*)&h; }
DEV float bf2f(ushort u){ __hip_bfloat16 h; *(ushort*)&h = u; return __bfloat162float(h); }

// ---- mask dtype classifier (bool may arrive as u8 / int32 / bf16) ----
DEV int mask_mode(const unsigned char* m){
  bool big = false, off123 = false, off0one = false;
  #pragma unroll
  for (int i = 0; i < 16; ++i){
    unsigned char c = m[i];
    if (c > 1) big = true;
    if ((i & 3) != 0 && c != 0) off123 = true;
    if ((i & 3) == 0 && c == 1) off0one = true;
  }
  if (big) return 2;
  if (!off123 && off0one) return 1;
  return 0;
}
DEV float mask_read(const void* m, int idx, int mode){
  if (mode == 1) return ((const int*)m)[idx] ? 1.f : 0.f;
  if (mode == 2) return ((const unsigned short*)m)[idx] ? 1.f : 0.f;
  return ((const unsigned char*)m)[idx] ? 1.f : 0.f;
}

// ---------------- P0a: per-vocab feature stats ----------------
__global__ __launch_bounds__(256)
void k_feat_stats(const float* __restrict__ feat, float* __restrict__ fsum, float* __restrict__ fsq){
  int v = blockIdx.x*4 + (threadIdx.x >> 6);
  int lane = threadIdx.x & 63;
  if (v >= 30000) return;
  float s = 0.f, q = 0.f;
  for (int i = lane; i < 300; i += 64){ float f = feat[v*300 + i]; s += f; q += f*f; }
  for (int o = 32; o > 0; o >>= 1){ s += __shfl_xor(s, o); q += __shfl_xor(q, o); }
  if (lane == 0){ fsum[v] = s; fsq[v] = q; }
}

// ---------------- P0b: gw1/cv partials ----------------
__global__ __launch_bounds__(256)
void k_gw1_part(const float* __restrict__ w1, const float* __restrict__ g,
                const float* __restrict__ bln, float* __restrict__ pgw, float* __restrict__ pcv){
  int j = blockIdx.x*256 + threadIdx.x;
  int ic = blockIdx.y;
  if (j >= 600) return;
  float a = 0.f, c = 0.f;
  for (int i = ic*75; i < ic*75 + 75; ++i){
    float w = w1[i*600 + j];
    a += g[i]*w; c += bln[i]*w;
  }
  pgw[ic*600 + j] = a; pcv[ic*600 + j] = c;
}

__global__ __launch_bounds__(256)
void k_gw_reduce(const float* __restrict__ pgw, const float* __restrict__ pcv,
                 const float* __restrict__ b1, float* __restrict__ gw_g, float* __restrict__ c_g){
  int j = blockIdx.x*256 + threadIdx.x;
  if (j >= 600) return;
  float a = 0.f, c = 0.f;
  for (int k = 0; k < 8; ++k){ a += pgw[k*600 + j]; c += pcv[k*600 + j]; }
  gw_g[j] = a; c_g[j] = c + b1[j];
}

// ---------------- pack A: feat -> bf16 [30080][320] (K zero-padded) ----------------
__global__ __launch_bounds__(256)
void k_pack_a(const float* __restrict__ feat, ushort* __restrict__ A){
  int idx = blockIdx.x*256 + threadIdx.x;
  if (idx >= 30080*40) return;
  int v = idx / 40, ko = (idx % 40)*8;
  union { ushort u[8]; bf16x8 v8; } pk;
  #pragma unroll
  for (int i = 0; i < 8; ++i){
    int k = ko + i;
    float val = (v < 30000 && k < 300) ? feat[(size_t)v*300 + k] : 0.f;
    pk.u[i] = f2bf(val);
  }
  *(bf16x8*)&A[(size_t)idx*8] = pk.v8;
}

// ---------------- pack B^T: BT[n][k] = g[k]*w1[k*600+n], bf16 [640][320] ----------------
__global__ __launch_bounds__(256)
void k_pack_b(const float* __restrict__ w1, const float* __restrict__ g, ushort* __restrict__ BT){
  int id = blockIdx.x*256 + threadIdx.x;
  if (id >= 640*320) return;
  int n = id % 640, k = id / 640;
  float val = (k < 300 && n < 600) ? g[k]*w1[k*600 + n] : 0.f;
  BT[(size_t)n*320 + k] = f2bf(val);
}

// ---------------- P1: U = A @ B via MFMA 16x16x32 bf16, 128x128 tile ----------------
__global__ __launch_bounds__(256)
void k_ugemm_mfma(const ushort* __restrict__ A, const ushort* __restrict__ BT,
                  __hip_bfloat16* __restrict__ U){
  __shared__ ushort As[128][40];
  __shared__ ushort Bs[128][40];
  int tid = threadIdx.x;
  int bm = blockIdx.x * 128, bn = blockIdx.y * 128;
  int wid = tid >> 6, lane = tid & 63;
  int wr = wid >> 1, wc = wid & 1;
  int lr = lane & 15, lk = lane >> 4;
  f32x4 acc[4][4] = {};
  for (int k0 = 0; k0 < 320; k0 += 32){
    #pragma unroll
    for (int j = 0; j < 2; ++j){
      int idx = tid + 256*j;
      int row = idx >> 2, ko = (idx & 3)*8;
      *(bf16x8*)&As[row][ko] = *(const bf16x8*)&A[(size_t)(bm+row)*320 + k0 + ko];
      *(bf16x8*)&Bs[row][ko] = *(const bf16x8*)&BT[(size_t)(bn+row)*320 + k0 + ko];
    }
    __syncthreads();
    bf16x8 af[4], bfr[4];
    #pragma unroll
    for (int f = 0; f < 4; ++f){
      af[f]  = *(const bf16x8*)&As[wr*64 + f*16 + lr][lk*8];
      bfr[f] = *(const bf16x8*)&Bs[wc*64 + f*16 + lr][lk*8];
    }
    #pragma unroll
    for (int i = 0; i < 4; ++i)
      #pragma unroll
      for (int j = 0; j < 4; ++j)
        acc[i][j] = __builtin_amdgcn_mfma_f32_16x16x32_bf16(af[i], bfr[j], acc[i][j], 0, 0, 0);
    __syncthreads();
  }
  #pragma unroll
  for (int i = 0; i < 4; ++i){
    #pragma unroll
    for (int j = 0; j < 4; ++j){
      #pragma unroll
      for (int r = 0; r < 4; ++r){
        int row = bm + wr*64 + i*16 + lk*4 + r;
        int col = bn + wc*64 + j*16 + lr;
        if (row < 30000 && col < 600)
          U[(size_t)row*600 + col] = __float2bfloat16(acc[i][j][r]);
      }
    }
  }
}

// ---------------- K1: stage 1 ----------------
__global__ __launch_bounds__(512)
void k_encode_stage1(const int* __restrict__ ids_a, const void* __restrict__ mask_a,
                     const int* __restrict__ ids_b, const void* __restrict__ mask_b,
                     const float* __restrict__ mu_tab, const float* __restrict__ logvar_tab,
                     const float* __restrict__ alpha_tab, const ushort* __restrict__ Abf,
                     const float* __restrict__ log_tau, const float* __restrict__ pos_mu,
                     const float* __restrict__ pos_alpha,
                     const float* __restrict__ wq, const float* __restrict__ bq,
                     const float* __restrict__ wk, const float* __restrict__ bk,
                     ushort* __restrict__ MuS,
                     float* __restrict__ sgs_g, float* __restrict__ sgsT_g,
                     float* __restrict__ ssum_g, float* __restrict__ ssq_g,
                     float* __restrict__ wgt_g)
{
  int bb = blockIdx.x;
  const int* ids = (bb < 128) ? ids_a : ids_b;
  const void* msk = (bb < 128) ? mask_a : mask_b;
  int b = bb & 127;
  int t = threadIdx.x;

  __shared__ int   ids_l[512];
  __shared__ float mf_l[512], al_l[512], w_l[512], red[512];
  __shared__ float cent[64], q_l[64], qk_l[64];
  __shared__ float sgs_l[304];
  __shared__ float gpart[32][64];
  __shared__ float pacc[8][304];
  __shared__ float bkq_s;
  __shared__ int mmode;

  if (t == 0) mmode = mask_mode((const unsigned char*)msk);
  __syncthreads();

  {
    int id = ids[b*512 + t];
    float mf = mask_read(msk, b*512 + t, mmode);
    ids_l[t] = id; mf_l[t] = mf;
    float pa = pos_alpha[t];
    al_l[t] = alpha_tab[id] * (1.f/(1.f + expf(-pa))) * mf;
  }
  __syncthreads();
  float msum = blk_sum512(red, t, mf_l[t]);

  int grp = t >> 4, sub = t & 15;
  ushort* MuB = MuS + (size_t)bb*512*64;

  // phase 1: gather mu+pos once, stage bf16, centroid partials
  {
    float cp0=0.f, cp1=0.f, cp2=0.f, cp3=0.f;
    for (int k = 0; k < 16; ++k){
      int s = (grp << 4) | k;
      int id = ids_l[s];
      float4 m4 = *(const float4*)&mu_tab[(size_t)id*64 + sub*4];
      float4 p4 = *(const float4*)&pos_mu[s*64 + sub*4];
      float v0 = m4.x + p4.x, v1 = m4.y + p4.y, v2 = m4.z + p4.z, v3 = m4.w + p4.w;
      ushort4 st; st.x = f2bf(v0); st.y = f2bf(v1); st.z = f2bf(v2); st.w = f2bf(v3);
      *(ushort4*)&MuB[(size_t)s*64 + sub*4] = st;
      float mf = mf_l[s];
      cp0 += mf*v0; cp1 += mf*v1; cp2 += mf*v2; cp3 += mf*v3;
    }
    gpart[grp][sub*4+0] = cp0; gpart[grp][sub*4+1] = cp1;
    gpart[grp][sub*4+2] = cp2; gpart[grp][sub*4+3] = cp3;
  }
  __syncthreads();
  if (t < 64){
    float c = 0.f;
    for (int g = 0; g < 32; ++g) c += gpart[g][t];
    cent[t] = c / fmaxf(msum, 1.f);
  }
  __syncthreads();

  // phase 2: d2 -> w = alpha*K
  {
    float itau = expf(-log_tau[0]);
    float c0 = cent[sub*4+0], c1 = cent[sub*4+1], c2 = cent[sub*4+2], c3 = cent[sub*4+3];
    for (int k = 0; k < 16; ++k){
      int s = (grp << 4) | k;
      int id = ids_l[s];
      float4 lv = *(const float4*)&logvar_tab[(size_t)id*64 + sub*4];
      ushort4 mu = *(const ushort4*)&MuB[(size_t)s*64 + sub*4];
      float d0 = bf2f(mu.x) - c0, d1 = bf2f(mu.y) - c1, d2v = bf2f(mu.z) - c2, d3 = bf2f(mu.w) - c3;
      float val = d0*d0*expf(-lv.x) + d1*d1*expf(-lv.y) + d2v*d2v*expf(-lv.z) + d3*d3*expf(-lv.w);
      val += __shfl_xor(val, 1); val += __shfl_xor(val, 2);
      val += __shfl_xor(val, 4); val += __shfl_xor(val, 8);
      if (sub == 0){
        float K = expf(-0.5f * val * itau) * mf_l[s];
        w_l[s] = al_l[s] * K;
      }
    }
  }
  __syncthreads();
  float wsum = blk_sum512(red, t, w_l[t]);

  // phase 3: sgs render — wave-per-token, bf16x8 gathers from packed Abf
  {
    int wv = t >> 6, ln = t & 63;
    if (ln < 38){
      float a[8] = {};
      for (int k = 0; k < 64; ++k){
        int s = (wv << 6) | k;
        float w = w_l[s];
        bf16x8 f8 = *(const bf16x8*)&Abf[(size_t)ids_l[s]*320 + ln*8];
        #pragma unroll
        for (int r = 0; r < 8; ++r) a[r] += w * bf2f((ushort)f8[r]);
      }
      #pragma unroll
      for (int r = 0; r < 8; ++r) pacc[wv][ln*8 + r] = a[r];
    }
  }
  __syncthreads();
  if (t < 300){
    float sacc = 0.f;
    #pragma unroll
    for (int w = 0; w < 8; ++w) sacc += pacc[w][t];
    float sv = sacc / fmaxf(wsum, 1e-8f);
    sgs_l[t] = sv;
    sgs_g[bb*300 + t] = sv;
    sgsT_g[t*256 + bb] = sv;
  }
  __syncthreads();
  float ssum = blk_sum512(red, t, (t < 300) ? sgs_l[t] : 0.f);
  float ssq  = blk_sum512(red, t, (t < 300) ? sgs_l[t]*sgs_l[t] : 0.f);
  if (t == 0){ ssum_g[bb] = ssum; ssq_g[bb] = ssq; }

  // phase 4: query / qk / bkq
  if (t < 64){
    float q = bq[t];
    for (int i = 0; i < 300; ++i) q += sgs_l[i]*wq[i*64 + t];
    q_l[t] = q;
  }
  __syncthreads();
  if (t < 64){
    float a = 0.f;
    for (int j = 0; j < 64; ++j) a += wk[t*64 + j]*q_l[j];
    qk_l[t] = a;
  }
  if (t == 0){
    float s = 0.f;
    for (int j = 0; j < 64; ++j) s += bk[j]*q_l[j];
    bkq_s = s;
  }
  __syncthreads();

  // phase 5: scores from staged mu
  {
    float q0 = qk_l[sub*4+0], q1 = qk_l[sub*4+1], q2 = qk_l[sub*4+2], q3 = qk_l[sub*4+3];
    for (int k = 0; k < 16; ++k){
      int s = (grp << 4) | k;
      ushort4 mu = *(const ushort4*)&MuB[(size_t)s*64 + sub*4];
      float val = bf2f(mu.x)*q0 + bf2f(mu.y)*q1 + bf2f(mu.z)*q2 + bf2f(mu.w)*q3;
      val += __shfl_xor(val, 1); val += __shfl_xor(val, 2);
      val += __shfl_xor(val, 4); val += __shfl_xor(val, 8);
      if (sub == 0){
        float sv = (val + bkq_s) * 0.125f;
        w_l[s] = (mf_l[s] != 0.f) ? sv : -1e30f;
      }
    }
  }
  __syncthreads();

  // phase 6: softmax
  float mx = blk_max512(red, t, w_l[t]);
  float ex = expf(w_l[t] - mx);
  float Z  = blk_sum512(red, t, ex);
  wgt_g[bb*512 + t] = ex / Z;
}

// ---------------- k_vgemm: V[bb][j] ----------------
__global__ __launch_bounds__(256)
void k_vgemm(const float* __restrict__ sgs_g, const float* __restrict__ w1,
             const float* __restrict__ ln1g, float* __restrict__ V_g){
  int j = blockIdx.x;
  __shared__ float col[300];
  for (int i = threadIdx.x; i < 300; i += 256)
    col[i] = ln1g[300 + i]*w1[(size_t)(300 + i)*600 + j];
  __syncthreads();
  int bb = threadIdx.x;
  const float* sr = &sgs_g[bb*300];
  float acc = 0.f;
  #pragma unroll 4
  for (int i = 0; i < 300; ++i) acc += sr[i]*col[i];
  V_g[bb*600 + j] = acc;
}

// ---------------- K2: hbar + Fbar partials (2 halves per bb) ----------------
__global__ __launch_bounds__(512)
void k_hbar_fbar(const int* __restrict__ ids_a, const int* __restrict__ ids_b,
                 const __hip_bfloat16* __restrict__ U, const ushort* __restrict__ Abf,
                 const float* __restrict__ fsum, const float* __restrict__ fsq,
                 const float* __restrict__ ssum_g, const float* __restrict__ ssq_g,
                 const float* __restrict__ V_g, const float* __restrict__ gw_g,
                 const float* __restrict__ c_g, const float* __restrict__ wgt_g,
                 float* __restrict__ hbarT, float* __restrict__ fbarT)
{
  int blk = blockIdx.x;            // 512 = bb*2 + half
  int bb = blk >> 1, half = blk & 1;
  int b = bb & 127;
  const int* ids = (bb < 128) ? ids_a : ids_b;
  int t = threadIdx.x;
  __shared__ int id_l[256];
  __shared__ float m_l[256], rs_l[256], wg_l[256];
  __shared__ float hp[8][600];
  __shared__ float fp[8][304];
  float ss = ssum_g[bb], sq = ssq_g[bb];
  if (t < 256){
    int s = half*256 + t;
    int id = ids[b*512 + s];
    id_l[t] = id;
    float m = (fsum[id] + ss) * (1.f/600.f);
    float var = (fsq[id] + sq) * (1.f/600.f) - m*m;
    m_l[t] = m;
    rs_l[t] = 1.f / sqrtf(var + 1e-5f);
    wg_l[t] = wgt_g[bb*512 + s];
  }
  __syncthreads();

  int wv = t >> 6, ln = t & 63;
  float Vp[8], gwp[8], cp[8], Vs[8], gws[8], cs[8];
  #pragma unroll
  for (int r = 0; r < 8; ++r){
    int j = ln*8 + r;
    Vp[r] = V_g[bb*600 + j]; gwp[r] = gw_g[j]; cp[r] = c_g[j];
    Vs[r] = 0.f; gws[r] = 0.f; cs[r] = 0.f;
  }
  if (ln < 11){
    #pragma unroll
    for (int r = 0; r < 8; ++r){
      int j = 512 + ln*8 + r;
      Vs[r] = V_g[bb*600 + j]; gws[r] = gw_g[j]; cs[r] = c_g[j];
    }
  }
  float h1[8] = {}, h2[8] = {}, fa[8] = {};

  for (int k = 0; k < 32; ++k){
    int s = (wv << 5) | k;           // token within half
    int id = id_l[s];
    float w = wg_l[s], m = m_l[s], rs = rs_l[s];
    const __hip_bfloat16* ur = &U[(size_t)id*600];
    bf16x8 u8 = *(const bf16x8*)&ur[ln*8];
    #pragma unroll
    for (int r = 0; r < 8; ++r){
      float u = bf2f((ushort)u8[r]);
      float a = (u + Vp[r] - m*gwp[r])*rs + cp[r];
      h1[r] += w*geluf(a);
    }
    if (ln < 11){
      bf16x8 u8b = *(const bf16x8*)&ur[512 + ln*8];
      #pragma unroll
      for (int r = 0; r < 8; ++r){
        float u = bf2f((ushort)u8b[r]);
        float a = (u + Vs[r] - m*gws[r])*rs + cs[r];
        h2[r] += w*geluf(a);
      }
    }
    if (ln < 38){
      bf16x8 f8 = *(const bf16x8*)&Abf[(size_t)id*320 + ln*8];
      #pragma unroll
      for (int r = 0; r < 8; ++r) fa[r] += w * bf2f((ushort)f8[r]);
    }
  }
  #pragma unroll
  for (int r = 0; r < 8; ++r) hp[wv][ln*8 + r] = h1[r];
  if (ln < 11){
    #pragma unroll
    for (int r = 0; r < 8; ++r) hp[wv][512 + ln*8 + r] = h2[r];
  }
  if (ln < 38){
    #pragma unroll
    for (int r = 0; r < 8; ++r) fp[wv][ln*8 + r] = fa[r];
  }
  __syncthreads();
  for (int j = t; j < 600; j += 512){
    float s = 0.f;
    #pragma unroll
    for (int w = 0; w < 8; ++w) s += hp[w][j];
    hbarT[(size_t)(half*600 + j)*256 + bb] = s;
  }
  if (t < 300){
    float s = 0.f;
    #pragma unroll
    for (int w = 0; w < 8; ++w) s += fp[w][t];
    fbarT[(size_t)(half*300 + t)*256 + bb] = s;
  }
}

// ---------------- k_attT: attT[t][bb] = b2 + Fbar + hbar@w2 ----------------
__global__ __launch_bounds__(256)
void k_attT(const float* __restrict__ hbarT, const float* __restrict__ fbarT,
            const float* __restrict__ w2, const float* __restrict__ b2,
            float* __restrict__ attT){
  int t = blockIdx.x;       // 300
  int bb = threadIdx.x;     // 256
  float acc = b2[t] + fbarT[t*256 + bb] + fbarT[(300 + t)*256 + bb];
  const float* H0 = hbarT;
  const float* H1 = hbarT + 600*256;
  #pragma unroll 4
  for (int k = 0; k < 600; ++k){
    float h = H0[k*256 + bb] + H1[k*256 + bb];
    acc += h * w2[k*300 + t];
  }
  attT[t*256 + bb] = acc;
}

// ---------------- k_lnstats: LN2 row stats ----------------
__global__ __launch_bounds__(256)
void k_lnstats(const float* __restrict__ attT, const float* __restrict__ ssum_g,
               const float* __restrict__ ssq_g, float* __restrict__ m_g, float* __restrict__ rs_g){
  int bb = threadIdx.x;
  float s = 0.f, q = 0.f;
  #pragma unroll 4
  for (int t = 0; t < 300; ++t){
    float v = attT[t*256 + bb];
    s += v; q += v*v;
  }
  float m = (ssum_g[bb] + s) * (1.f/600.f);
  float var = (ssq_g[bb] + q) * (1.f/600.f) - m*m;
  m_g[bb] = m;
  rs_g[bb] = 1.f / sqrtf(var + 1e-5f);
}

// ---------------- k_mlp2a: g2T[j][bb] = gelu(LN2(x) @ aw1 + ab1) ----------------
__global__ __launch_bounds__(256)
void k_mlp2a(const float* __restrict__ sgsT, const float* __restrict__ attT,
             const float* __restrict__ m_g, const float* __restrict__ rs_g,
             const float* __restrict__ ln2g, const float* __restrict__ ln2b,
             const float* __restrict__ aw1, const float* __restrict__ ab1,
             float* __restrict__ g2T){
  int j = blockIdx.x;       // 600
  int bb = threadIdx.x;
  float m = m_g[bb], rs = rs_g[bb];
  float acc = ab1[j];
  #pragma unroll 4
  for (int i = 0; i < 300; ++i){
    float x = sgsT[i*256 + bb];
    float t2 = (x - m)*rs*ln2g[i] + ln2b[i];
    acc += t2 * aw1[(size_t)i*600 + j];
  }
  #pragma unroll 4
  for (int i = 0; i < 300; ++i){
    float x = attT[i*256 + bb];
    float t2 = (x - m)*rs*ln2g[300 + i] + ln2b[300 + i];
    acc += t2 * aw1[(size_t)(300 + i)*600 + j];
  }
  g2T[j*256 + bb] = geluf(acc);
}

// ---------------- k_mlp2b: finalT[t][bb] = sgs + g2 @ aw2 + ab2 ----------------
__global__ __launch_bounds__(256)
void k_mlp2b(const float* __restrict__ g2T, const float* __restrict__ sgsT,
             const float* __restrict__ aw2, const float* __restrict__ ab2,
             float* __restrict__ finalT){
  int t = blockIdx.x;       // 300
  int bb = threadIdx.x;
  float acc = ab2[t] + sgsT[t*256 + bb];
  #pragma unroll 4
  for (int j = 0; j < 600; ++j)
    acc += g2T[j*256 + bb] * aw2[(size_t)j*300 + t];
  finalT[t*256 + bb] = acc;
}

// ---------------- K4: cosine (transposed final) ----------------
__global__ __launch_bounds__(64)
void k_cos(const float* __restrict__ finalT, float* __restrict__ out){
  int b = blockIdx.x; int lane = threadIdx.x;
  float dot = 0.f, na = 0.f, nb = 0.f;
  for (int i = lane; i < 300; i += 64){
    float x = finalT[i*256 + b], y = finalT[i*256 + 128 + b];
    dot += x*y; na += x*x; nb += y*y;
  }
  for (int o = 32; o > 0; o >>= 1){
    dot += __shfl_xor(dot, o); na += __shfl_xor(na, o); nb += __shfl_xor(nb, o);
  }
  if (lane == 0){
    float den = fmaxf(sqrtf(na), 1e-8f) * fmaxf(sqrtf(nb), 1e-8f);
    out[b] = 5.f * dot / den;
  }
}

extern "C" void kernel_launch(void* const* d_in, const int* in_sizes, int n_in,
                              void* d_out, int out_size, void* d_ws, size_t ws_size,
                              hipStream_t stream) {
  const int* ids_a = (const int*)d_in[0];
  const void* mask_a = d_in[1];
  const int* ids_b = (const int*)d_in[2];
  const void* mask_b = d_in[3];
  const float* mu_tab     = (const float*)d_in[4];
  const float* logvar_tab = (const float*)d_in[5];
  const float* alpha_tab  = (const float*)d_in[6];
  const float* feat_tab   = (const float*)d_in[7];
  const float* log_tau    = (const float*)d_in[8];
  const float* pos_mu     = (const float*)d_in[9];
  const float* pos_alpha  = (const float*)d_in[10];
  const float* ln1g = (const float*)d_in[11];
  const float* ln1b = (const float*)d_in[12];
  const float* w1   = (const float*)d_in[13];
  const float* b1   = (const float*)d_in[14];
  const float* w2   = (const float*)d_in[15];
  const float* b2   = (const float*)d_in[16];
  const float* wq   = (const float*)d_in[17];
  const float* bq   = (const float*)d_in[18];
  const float* wk   = (const float*)d_in[19];
  const float* bk   = (const float*)d_in[20];
  const float* ln2g = (const float*)d_in[21];
  const float* ln2b = (const float*)d_in[22];
  const float* aw1  = (const float*)d_in[23];
  const float* ab1  = (const float*)d_in[24];
  const float* aw2  = (const float*)d_in[25];
  const float* ab2  = (const float*)d_in[26];
  float* out = (float*)d_out;

  char* wsb = (char*)d_ws;
  size_t off = 0;
  auto take = [&](size_t bytes) -> void* {
    void* p = wsb + off;
    off += (bytes + 255) & ~(size_t)255;
    return p;
  };

  const size_t uBytes  = (size_t)30000 * 600 * 2;   // 36.0 MB
  const size_t aBytes  = (size_t)30080 * 320 * 2;   // 19.3 MB
  const size_t btBytes = (size_t)640 * 320 * 2;     // 0.41 MB
  const size_t muBytes = (size_t)256 * 512 * 64 * 2;// 16.8 MB
  const size_t need = uBytes + aBytes + btBytes + muBytes + ((size_t)6 << 20);
  if (ws_size < need) return;

  __hip_bfloat16* U = (__hip_bfloat16*)take(uBytes);
  ushort* Abf  = (ushort*)take(aBytes);
  ushort* BTbf = (ushort*)take(btBytes);
  ushort* MuS  = (ushort*)take(muBytes);
  float* fsum   = (float*)take(30000*4);
  float* fsq    = (float*)take(30000*4);
  float* pgw    = (float*)take(8*600*4);
  float* pcv    = (float*)take(8*600*4);
  float* gw_g   = (float*)take(600*4);
  float* c_g    = (float*)take(600*4);
  float* sgs_g  = (float*)take(256*300*4);
  float* sgsT   = (float*)take(300*256*4);
  float* ssum_g = (float*)take(256*4);
  float* ssq_g  = (float*)take(256*4);
  float* V_g    = (float*)take(256*600*4);
  float* wgt_g  = (float*)take(256*512*4);
  float* hbarT  = (float*)take((size_t)2*600*256*4);
  float* fbarT  = (float*)take((size_t)2*300*256*4);
  float* attT   = (float*)take(300*256*4);
  float* m_g    = (float*)take(256*4);
  float* rs_g   = (float*)take(256*4);
  float* g2T    = (float*)take(600*256*4);
  float* finalT = (float*)take(300*256*4);

  k_pack_a<<<(30080*40 + 255)/256, 256, 0, stream>>>(feat_tab, Abf);
  k_pack_b<<<(640*320 + 255)/256, 256, 0, stream>>>(w1, ln1g, BTbf);
  k_feat_stats<<<7500, 256, 0, stream>>>(feat_tab, fsum, fsq);
  k_gw1_part<<<dim3(3, 8), 256, 0, stream>>>(w1, ln1g, ln1b, pgw, pcv);
  k_gw_reduce<<<3, 256, 0, stream>>>(pgw, pcv, b1, gw_g, c_g);
  k_ugemm_mfma<<<dim3(235, 5), 256, 0, stream>>>(Abf, BTbf, U);
  k_encode_stage1<<<256, 512, 0, stream>>>(ids_a, mask_a, ids_b, mask_b,
                                           mu_tab, logvar_tab, alpha_tab, Abf,
                                           log_tau, pos_mu, pos_alpha,
                                           wq, bq, wk, bk,
                                           MuS, sgs_g, sgsT, ssum_g, ssq_g, wgt_g);
  k_vgemm<<<600, 256, 0, stream>>>(sgs_g, w1, ln1g, V_g);
  k_hbar_fbar<<<512, 512, 0, stream>>>(ids_a, ids_b, U, Abf, fsum, fsq,
                                       ssum_g, ssq_g, V_g, gw_g, c_g, wgt_g,
                                       hbarT, fbarT);
  k_attT<<<300, 256, 0, stream>>>(hbarT, fbarT, w2, b2, attT);
  k_lnstats<<<1, 256, 0, stream>>>(attT, ssum_g, ssq_g, m_g, rs_g);
  k_mlp2a<<<600, 256, 0, stream>>>(sgsT, attT, m_g, rs_g, ln2g, ln2b, aw1, ab1, g2T);
  k_mlp2b<<<300, 256, 0, stream>>>(g2T, sgsT, aw2, ab2, finalT);
  k_cos<<<128, 64, 0, stream>>>(finalT, out);
}

// Round 6
// 439.743 us; speedup vs baseline: 1.1425x; 1.1425x over previous
//
#include <hip/hip_runtime.h>
#include <hip/hip_bf16.h>
#include <cstdint>
#include <cstddef>

#define DEV __device__ __forceinline__

// problem constants: B=128, S=512, V=30000, DS=64, DF=300, H=600, BB=256

typedef __attribute__((ext_vector_type(8))) short bf16x8;
typedef __attribute__((ext_vector_type(4))) float f32x4;

DEV float geluf(float x){ return 0.5f*x*(1.f + erff(x*0.7071067811865475f)); }
// tanh-form gelu via sigmoid: x*sigmoid(2*0.7978845608*(x+0.044715 x^3))
DEV float gelu_fast(float x){
  float y = 1.5957691216f*(x + 0.044715f*x*x*x);
  return x / (1.f + __expf(-y));
}

DEV float blk_sum512(float* red, int t, float v){
  red[t] = v; __syncthreads();
  for (int o = 256; o > 0; o >>= 1){ if (t < o) red[t] += red[t+o]; __syncthreads(); }
  float r = red[0]; __syncthreads(); return r;
}
DEV float blk_max512(float* red, int t, float v){
  red[t] = v; __syncthreads();
  for (int o = 256; o > 0; o >>= 1){ if (t < o) red[t] = fmaxf(red[t], red[t+o]); __syncthreads(); }
  float r = red[0]; __syncthreads(); return r;
}

DEV ushort f2bf(float v){ __hip_bfloat16 h = __float2bfloat16(v); return *(ushort*)&h; }
DEV float bf2f(ushort u){ __hip_bfloat16 h; *(ushort*)&h = u; return __bfloat162float(h); }

// ---- mask dtype classifier (bool may arrive as u8 / int32 / bf16) ----
DEV int mask_mode(const unsigned char* m){
  bool big = false, off123 = false, off0one = false;
  #pragma unroll
  for (int i = 0; i < 16; ++i){
    unsigned char c = m[i];
    if (c > 1) big = true;
    if ((i & 3) != 0 && c != 0) off123 = true;
    if ((i & 3) == 0 && c == 1) off0one = true;
  }
  if (big) return 2;
  if (!off123 && off0one) return 1;
  return 0;
}
DEV float mask_read(const void* m, int idx, int mode){
  if (mode == 1) return ((const int*)m)[idx] ? 1.f : 0.f;
  if (mode == 2) return ((const unsigned short*)m)[idx] ? 1.f : 0.f;
  return ((const unsigned char*)m)[idx] ? 1.f : 0.f;
}

// ---------------- P0a: per-vocab feature stats ----------------
__global__ __launch_bounds__(256)
void k_feat_stats(const float* __restrict__ feat, float* __restrict__ fsum, float* __restrict__ fsq){
  int v = blockIdx.x*4 + (threadIdx.x >> 6);
  int lane = threadIdx.x & 63;
  if (v >= 30000) return;
  float s = 0.f, q = 0.f;
  for (int i = lane; i < 300; i += 64){ float f = feat[v*300 + i]; s += f; q += f*f; }
  for (int o = 32; o > 0; o >>= 1){ s += __shfl_xor(s, o); q += __shfl_xor(q, o); }
  if (lane == 0){ fsum[v] = s; fsq[v] = q; }
}

// ---------------- P0b: gw1/cv partials ----------------
__global__ __launch_bounds__(256)
void k_gw1_part(const float* __restrict__ w1, const float* __restrict__ g,
                const float* __restrict__ bln, float* __restrict__ pgw, float* __restrict__ pcv){
  int j = blockIdx.x*256 + threadIdx.x;
  int ic = blockIdx.y;
  if (j >= 600) return;
  float a = 0.f, c = 0.f;
  for (int i = ic*75; i < ic*75 + 75; ++i){
    float w = w1[i*600 + j];
    a += g[i]*w; c += bln[i]*w;
  }
  pgw[ic*600 + j] = a; pcv[ic*600 + j] = c;
}

__global__ __launch_bounds__(256)
void k_gw_reduce(const float* __restrict__ pgw, const float* __restrict__ pcv,
                 const float* __restrict__ b1, float* __restrict__ gw_g, float* __restrict__ c_g){
  int j = blockIdx.x*256 + threadIdx.x;
  if (j >= 600) return;
  float a = 0.f, c = 0.f;
  for (int k = 0; k < 8; ++k){ a += pgw[k*600 + j]; c += pcv[k*600 + j]; }
  gw_g[j] = a; c_g[j] = c + b1[j];
}

// ---------------- pack A: feat -> bf16 [30080][320] (K zero-padded) ----------------
__global__ __launch_bounds__(256)
void k_pack_a(const float* __restrict__ feat, ushort* __restrict__ A){
  int idx = blockIdx.x*256 + threadIdx.x;
  if (idx >= 30080*40) return;
  int v = idx / 40, ko = (idx % 40)*8;
  union { ushort u[8]; bf16x8 v8; } pk;
  #pragma unroll
  for (int i = 0; i < 8; ++i){
    int k = ko + i;
    float val = (v < 30000 && k < 300) ? feat[(size_t)v*300 + k] : 0.f;
    pk.u[i] = f2bf(val);
  }
  *(bf16x8*)&A[(size_t)idx*8] = pk.v8;
}

// ---------------- pack B^T: BT[n][k] = g[k]*w1[k*600+n], bf16 [640][320] ----------------
__global__ __launch_bounds__(256)
void k_pack_b(const float* __restrict__ w1, const float* __restrict__ g, ushort* __restrict__ BT){
  int id = blockIdx.x*256 + threadIdx.x;
  if (id >= 640*320) return;
  int n = id % 640, k = id / 640;
  float val = (k < 300 && n < 600) ? g[k]*w1[k*600 + n] : 0.f;
  BT[(size_t)n*320 + k] = f2bf(val);
}

// ---------------- P1: U = A @ B via MFMA 16x16x32 bf16, 128x128 tile ----------------
__global__ __launch_bounds__(256)
void k_ugemm_mfma(const ushort* __restrict__ A, const ushort* __restrict__ BT,
                  __hip_bfloat16* __restrict__ U){
  __shared__ ushort As[128][40];
  __shared__ ushort Bs[128][40];
  int tid = threadIdx.x;
  int bm = blockIdx.x * 128, bn = blockIdx.y * 128;
  int wid = tid >> 6, lane = tid & 63;
  int wr = wid >> 1, wc = wid & 1;
  int lr = lane & 15, lk = lane >> 4;
  f32x4 acc[4][4] = {};
  for (int k0 = 0; k0 < 320; k0 += 32){
    #pragma unroll
    for (int j = 0; j < 2; ++j){
      int idx = tid + 256*j;
      int row = idx >> 2, ko = (idx & 3)*8;
      *(bf16x8*)&As[row][ko] = *(const bf16x8*)&A[(size_t)(bm+row)*320 + k0 + ko];
      *(bf16x8*)&Bs[row][ko] = *(const bf16x8*)&BT[(size_t)(bn+row)*320 + k0 + ko];
    }
    __syncthreads();
    bf16x8 af[4], bfr[4];
    #pragma unroll
    for (int f = 0; f < 4; ++f){
      af[f]  = *(const bf16x8*)&As[wr*64 + f*16 + lr][lk*8];
      bfr[f] = *(const bf16x8*)&Bs[wc*64 + f*16 + lr][lk*8];
    }
    #pragma unroll
    for (int i = 0; i < 4; ++i)
      #pragma unroll
      for (int j = 0; j < 4; ++j)
        acc[i][j] = __builtin_amdgcn_mfma_f32_16x16x32_bf16(af[i], bfr[j], acc[i][j], 0, 0, 0);
    __syncthreads();
  }
  #pragma unroll
  for (int i = 0; i < 4; ++i){
    #pragma unroll
    for (int j = 0; j < 4; ++j){
      #pragma unroll
      for (int r = 0; r < 4; ++r){
        int row = bm + wr*64 + i*16 + lk*4 + r;
        int col = bn + wc*64 + j*16 + lr;
        if (row < 30000 && col < 600)
          U[(size_t)row*600 + col] = __float2bfloat16(acc[i][j][r]);
      }
    }
  }
}

// ---------------- K1: stage 1 ----------------
__global__ __launch_bounds__(512)
void k_encode_stage1(const int* __restrict__ ids_a, const void* __restrict__ mask_a,
                     const int* __restrict__ ids_b, const void* __restrict__ mask_b,
                     const float* __restrict__ mu_tab, const float* __restrict__ logvar_tab,
                     const float* __restrict__ alpha_tab, const ushort* __restrict__ Abf,
                     const float* __restrict__ log_tau, const float* __restrict__ pos_mu,
                     const float* __restrict__ pos_alpha,
                     const float* __restrict__ wq, const float* __restrict__ bq,
                     const float* __restrict__ wk, const float* __restrict__ bk,
                     ushort* __restrict__ MuS,
                     float* __restrict__ sgs_g,
                     float* __restrict__ ssum_g, float* __restrict__ ssq_g,
                     float* __restrict__ wgt_g)
{
  int bb = blockIdx.x;
  const int* ids = (bb < 128) ? ids_a : ids_b;
  const void* msk = (bb < 128) ? mask_a : mask_b;
  int b = bb & 127;
  int t = threadIdx.x;

  __shared__ int   ids_l[512];
  __shared__ float mf_l[512], al_l[512], w_l[512], red[512];
  __shared__ float cent[64], q_l[64], qk_l[64];
  __shared__ float sgs_l[304];
  __shared__ float gpart[32][64];
  __shared__ float pacc[8][304];
  __shared__ float bkq_s;
  __shared__ int mmode;

  if (t == 0) mmode = mask_mode((const unsigned char*)msk);
  __syncthreads();

  {
    int id = ids[b*512 + t];
    float mf = mask_read(msk, b*512 + t, mmode);
    ids_l[t] = id; mf_l[t] = mf;
    float pa = pos_alpha[t];
    al_l[t] = alpha_tab[id] * (1.f/(1.f + expf(-pa))) * mf;
  }
  __syncthreads();
  float msum = blk_sum512(red, t, mf_l[t]);

  int grp = t >> 4, sub = t & 15;
  ushort* MuB = MuS + (size_t)bb*512*64;

  // phase 1: gather mu+pos once, stage bf16, centroid partials
  {
    float cp0=0.f, cp1=0.f, cp2=0.f, cp3=0.f;
    for (int k = 0; k < 16; ++k){
      int s = (grp << 4) | k;
      int id = ids_l[s];
      float4 m4 = *(const float4*)&mu_tab[(size_t)id*64 + sub*4];
      float4 p4 = *(const float4*)&pos_mu[s*64 + sub*4];
      float v0 = m4.x + p4.x, v1 = m4.y + p4.y, v2 = m4.z + p4.z, v3 = m4.w + p4.w;
      ushort4 st; st.x = f2bf(v0); st.y = f2bf(v1); st.z = f2bf(v2); st.w = f2bf(v3);
      *(ushort4*)&MuB[(size_t)s*64 + sub*4] = st;
      float mf = mf_l[s];
      cp0 += mf*v0; cp1 += mf*v1; cp2 += mf*v2; cp3 += mf*v3;
    }
    gpart[grp][sub*4+0] = cp0; gpart[grp][sub*4+1] = cp1;
    gpart[grp][sub*4+2] = cp2; gpart[grp][sub*4+3] = cp3;
  }
  __syncthreads();
  if (t < 64){
    float c = 0.f;
    for (int g = 0; g < 32; ++g) c += gpart[g][t];
    cent[t] = c / fmaxf(msum, 1.f);
  }
  __syncthreads();

  // phase 2: d2 -> w = alpha*K
  {
    float itau = expf(-log_tau[0]);
    float c0 = cent[sub*4+0], c1 = cent[sub*4+1], c2 = cent[sub*4+2], c3 = cent[sub*4+3];
    for (int k = 0; k < 16; ++k){
      int s = (grp << 4) | k;
      int id = ids_l[s];
      float4 lv = *(const float4*)&logvar_tab[(size_t)id*64 + sub*4];
      ushort4 mu = *(const ushort4*)&MuB[(size_t)s*64 + sub*4];
      float d0 = bf2f(mu.x) - c0, d1 = bf2f(mu.y) - c1, d2v = bf2f(mu.z) - c2, d3 = bf2f(mu.w) - c3;
      float val = d0*d0*expf(-lv.x) + d1*d1*expf(-lv.y) + d2v*d2v*expf(-lv.z) + d3*d3*expf(-lv.w);
      val += __shfl_xor(val, 1); val += __shfl_xor(val, 2);
      val += __shfl_xor(val, 4); val += __shfl_xor(val, 8);
      if (sub == 0){
        float K = expf(-0.5f * val * itau) * mf_l[s];
        w_l[s] = al_l[s] * K;
      }
    }
  }
  __syncthreads();
  float wsum = blk_sum512(red, t, w_l[t]);

  // phase 3: sgs render — wave-per-token, bf16x8 gathers from packed Abf
  {
    int wv = t >> 6, ln = t & 63;
    if (ln < 38){
      float a[8] = {};
      for (int k = 0; k < 64; ++k){
        int s = (wv << 6) | k;
        float w = w_l[s];
        bf16x8 f8 = *(const bf16x8*)&Abf[(size_t)ids_l[s]*320 + ln*8];
        #pragma unroll
        for (int r = 0; r < 8; ++r) a[r] += w * bf2f((ushort)f8[r]);
      }
      #pragma unroll
      for (int r = 0; r < 8; ++r) pacc[wv][ln*8 + r] = a[r];
    }
  }
  __syncthreads();
  if (t < 300){
    float sacc = 0.f;
    #pragma unroll
    for (int w = 0; w < 8; ++w) sacc += pacc[w][t];
    float sv = sacc / fmaxf(wsum, 1e-8f);
    sgs_l[t] = sv;
    sgs_g[bb*300 + t] = sv;
  }
  __syncthreads();
  float ssum = blk_sum512(red, t, (t < 300) ? sgs_l[t] : 0.f);
  float ssq  = blk_sum512(red, t, (t < 300) ? sgs_l[t]*sgs_l[t] : 0.f);
  if (t == 0){ ssum_g[bb] = ssum; ssq_g[bb] = ssq; }

  // phase 4: query / qk / bkq
  if (t < 64){
    float q = bq[t];
    for (int i = 0; i < 300; ++i) q += sgs_l[i]*wq[i*64 + t];
    q_l[t] = q;
  }
  __syncthreads();
  if (t < 64){
    float a = 0.f;
    for (int j = 0; j < 64; ++j) a += wk[t*64 + j]*q_l[j];
    qk_l[t] = a;
  }
  if (t == 0){
    float s = 0.f;
    for (int j = 0; j < 64; ++j) s += bk[j]*q_l[j];
    bkq_s = s;
  }
  __syncthreads();

  // phase 5: scores from staged mu
  {
    float q0 = qk_l[sub*4+0], q1 = qk_l[sub*4+1], q2 = qk_l[sub*4+2], q3 = qk_l[sub*4+3];
    for (int k = 0; k < 16; ++k){
      int s = (grp << 4) | k;
      ushort4 mu = *(const ushort4*)&MuB[(size_t)s*64 + sub*4];
      float val = bf2f(mu.x)*q0 + bf2f(mu.y)*q1 + bf2f(mu.z)*q2 + bf2f(mu.w)*q3;
      val += __shfl_xor(val, 1); val += __shfl_xor(val, 2);
      val += __shfl_xor(val, 4); val += __shfl_xor(val, 8);
      if (sub == 0){
        float sv = (val + bkq_s) * 0.125f;
        w_l[s] = (mf_l[s] != 0.f) ? sv : -1e30f;
      }
    }
  }
  __syncthreads();

  // phase 6: softmax
  float mx = blk_max512(red, t, w_l[t]);
  float ex = expf(w_l[t] - mx);
  float Z  = blk_sum512(red, t, ex);
  wgt_g[bb*512 + t] = ex / Z;
}

// ---------------- k_vgemm: V[bb][j] ----------------
__global__ __launch_bounds__(256)
void k_vgemm(const float* __restrict__ sgs_g, const float* __restrict__ w1,
             const float* __restrict__ ln1g, float* __restrict__ V_g){
  int j = blockIdx.x;
  __shared__ float col[300];
  for (int i = threadIdx.x; i < 300; i += 256)
    col[i] = ln1g[300 + i]*w1[(size_t)(300 + i)*600 + j];
  __syncthreads();
  int bb = threadIdx.x;
  const float* sr = &sgs_g[bb*300];
  float acc = 0.f;
  #pragma unroll 4
  for (int i = 0; i < 300; ++i) acc += sr[i]*col[i];
  V_g[bb*600 + j] = acc;
}

// ---------------- K2: merged hbar + Fbar (round-4 structure, fast gelu) ----------------
// hbar_g is [256][608] (cols 600..607 zero-padded for the downstream GEMM)
__global__ __launch_bounds__(512)
void k_hbar_fbar(const int* __restrict__ ids_a, const int* __restrict__ ids_b,
                 const __hip_bfloat16* __restrict__ U, const ushort* __restrict__ Abf,
                 const float* __restrict__ fsum, const float* __restrict__ fsq,
                 const float* __restrict__ ssum_g, const float* __restrict__ ssq_g,
                 const float* __restrict__ V_g, const float* __restrict__ gw_g,
                 const float* __restrict__ c_g, const float* __restrict__ wgt_g,
                 float* __restrict__ hbar_g, float* __restrict__ Fbar_g)
{
  int bb = blockIdx.x; int b = bb & 127;
  const int* ids = (bb < 128) ? ids_a : ids_b;
  int t = threadIdx.x;
  __shared__ int id_l[512];
  __shared__ float m_l[512], rs_l[512], wg_l[512];
  __shared__ float hp[8][600];
  __shared__ float fp[8][304];
  float ss = ssum_g[bb], sq = ssq_g[bb];
  {
    int id = ids[b*512 + t];
    id_l[t] = id;
    float m = (fsum[id] + ss) * (1.f/600.f);
    float var = (fsq[id] + sq) * (1.f/600.f) - m*m;
    m_l[t] = m;
    rs_l[t] = 1.f / sqrtf(var + 1e-5f);
    wg_l[t] = wgt_g[bb*512 + t];
  }
  __syncthreads();

  int wv = t >> 6, ln = t & 63;
  float Vp[8], gwp[8], cp[8], Vs[8], gws[8], cs[8];
  #pragma unroll
  for (int r = 0; r < 8; ++r){
    int j = ln*8 + r;
    Vp[r] = V_g[bb*600 + j]; gwp[r] = gw_g[j]; cp[r] = c_g[j];
    Vs[r] = 0.f; gws[r] = 0.f; cs[r] = 0.f;
  }
  if (ln < 11){
    #pragma unroll
    for (int r = 0; r < 8; ++r){
      int j = 512 + ln*8 + r;
      Vs[r] = V_g[bb*600 + j]; gws[r] = gw_g[j]; cs[r] = c_g[j];
    }
  }
  float h1[8] = {}, h2[8] = {}, fa[8] = {};

  for (int k = 0; k < 64; ++k){
    int s = (wv << 6) | k;
    int id = id_l[s];
    float w = wg_l[s], m = m_l[s], rs = rs_l[s];
    const __hip_bfloat16* ur = &U[(size_t)id*600];
    bf16x8 u8 = *(const bf16x8*)&ur[ln*8];
    #pragma unroll
    for (int r = 0; r < 8; ++r){
      float u = bf2f((ushort)u8[r]);
      float a = (u + Vp[r] - m*gwp[r])*rs + cp[r];
      h1[r] += w*gelu_fast(a);
    }
    if (ln < 11){
      bf16x8 u8b = *(const bf16x8*)&ur[512 + ln*8];
      #pragma unroll
      for (int r = 0; r < 8; ++r){
        float u = bf2f((ushort)u8b[r]);
        float a = (u + Vs[r] - m*gws[r])*rs + cs[r];
        h2[r] += w*gelu_fast(a);
      }
    }
    if (ln < 38){
      bf16x8 f8 = *(const bf16x8*)&Abf[(size_t)id*320 + ln*8];
      #pragma unroll
      for (int r = 0; r < 8; ++r) fa[r] += w * bf2f((ushort)f8[r]);
    }
  }
  #pragma unroll
  for (int r = 0; r < 8; ++r) hp[wv][ln*8 + r] = h1[r];
  if (ln < 11){
    #pragma unroll
    for (int r = 0; r < 8; ++r) hp[wv][512 + ln*8 + r] = h2[r];
  }
  if (ln < 38){
    #pragma unroll
    for (int r = 0; r < 8; ++r) fp[wv][ln*8 + r] = fa[r];
  }
  __syncthreads();
  for (int j = t; j < 600; j += 512){
    float s = 0.f;
    #pragma unroll
    for (int w = 0; w < 8; ++w) s += hp[w][j];
    hbar_g[(size_t)bb*608 + j] = s;
  }
  if (t < 8) hbar_g[(size_t)bb*608 + 600 + t] = 0.f;   // zero pad for GEMM K=608
  if (t < 300){
    float s = 0.f;
    #pragma unroll
    for (int w = 0; w < 8; ++w) s += fp[w][t];
    Fbar_g[bb*300 + t] = s;
  }
}

// ============ final chain as small tiled fp32 GEMMs (32x32 tiles, 2x2/thread) ============

// GEMM1: att[256][300] = b2 + Fbar + hbar[256][608] @ w2[600][300]
__global__ __launch_bounds__(256)
void k_att(const float* __restrict__ hbar, const float* __restrict__ Fbar,
           const float* __restrict__ w2, const float* __restrict__ b2,
           float* __restrict__ att){
  __shared__ float As[32][33], Bs[32][33];
  int t = threadIdx.x;
  int bm = blockIdx.x*32, bn = blockIdx.y*32;
  int tx = t & 15, ty = t >> 4;
  float a00=0.f,a01=0.f,a10=0.f,a11=0.f;
  for (int k0 = 0; k0 < 608; k0 += 32){
    #pragma unroll
    for (int i = 0; i < 4; ++i){
      int idx = t + i*256;
      int kk = idx & 31, m = idx >> 5;
      As[kk][m] = hbar[(size_t)(bm+m)*608 + k0 + kk];
    }
    #pragma unroll
    for (int i = 0; i < 4; ++i){
      int idx = t + i*256;
      int n = idx & 31, kk = idx >> 5;
      int kg = k0 + kk, cg = bn + n;
      Bs[kk][n] = (kg < 600 && cg < 300) ? w2[(size_t)kg*300 + cg] : 0.f;
    }
    __syncthreads();
    #pragma unroll
    for (int kk = 0; kk < 32; ++kk){
      float x0 = As[kk][ty*2], x1 = As[kk][ty*2+1];
      float y0 = Bs[kk][tx*2], y1 = Bs[kk][tx*2+1];
      a00 += x0*y0; a01 += x0*y1; a10 += x1*y0; a11 += x1*y1;
    }
    __syncthreads();
  }
  int r0 = bm + ty*2, c0 = bn + tx*2;
  #pragma unroll
  for (int i = 0; i < 2; ++i){
    #pragma unroll
    for (int j = 0; j < 2; ++j){
      int r = r0 + i, c = c0 + j;
      if (c < 300){
        float acc = (i==0 ? (j==0?a00:a01) : (j==0?a10:a11));
        att[(size_t)r*300 + c] = acc + b2[c] + Fbar[(size_t)r*300 + c];
      }
    }
  }
}

// LN2 stats per row
__global__ __launch_bounds__(64)
void k_lnstats(const float* __restrict__ att, const float* __restrict__ ssum_g,
               const float* __restrict__ ssq_g, float* __restrict__ m_g, float* __restrict__ rs_g){
  int bb = blockIdx.x, lane = threadIdx.x;
  float s = 0.f, q = 0.f;
  for (int i = lane; i < 300; i += 64){
    float v = att[(size_t)bb*300 + i];
    s += v; q += v*v;
  }
  for (int o = 32; o > 0; o >>= 1){ s += __shfl_xor(s, o); q += __shfl_xor(q, o); }
  if (lane == 0){
    float m = (ssum_g[bb] + s) * (1.f/600.f);
    float var = (ssq_g[bb] + q) * (1.f/600.f) - m*m;
    m_g[bb] = m;
    rs_g[bb] = 1.f / sqrtf(var + 1e-5f);
  }
}

// GEMM2: g2[256][608] = gelu(LN2([sgs|att]) @ aw1[600][600] + ab1)   (cols 600..607 = 0)
__global__ __launch_bounds__(256)
void k_mlp1(const float* __restrict__ sgs, const float* __restrict__ att,
            const float* __restrict__ m_g, const float* __restrict__ rs_g,
            const float* __restrict__ ln2g, const float* __restrict__ ln2b,
            const float* __restrict__ aw1, const float* __restrict__ ab1,
            float* __restrict__ g2){
  __shared__ float As[32][33], Bs[32][33];
  int t = threadIdx.x;
  int bm = blockIdx.x*32, bn = blockIdx.y*32;
  int tx = t & 15, ty = t >> 4;
  float a00=0.f,a01=0.f,a10=0.f,a11=0.f;
  for (int k0 = 0; k0 < 608; k0 += 32){
    #pragma unroll
    for (int i = 0; i < 4; ++i){
      int idx = t + i*256;
      int kk = idx & 31, m = idx >> 5;
      int kg = k0 + kk, row = bm + m;
      float t2 = 0.f;
      if (kg < 600){
        float x = (kg < 300) ? sgs[(size_t)row*300 + kg] : att[(size_t)row*300 + kg - 300];
        t2 = (x - m_g[row])*rs_g[row]*ln2g[kg] + ln2b[kg];
      }
      As[kk][m] = t2;
    }
    #pragma unroll
    for (int i = 0; i < 4; ++i){
      int idx = t + i*256;
      int n = idx & 31, kk = idx >> 5;
      int kg = k0 + kk, cg = bn + n;
      Bs[kk][n] = (kg < 600 && cg < 600) ? aw1[(size_t)kg*600 + cg] : 0.f;
    }
    __syncthreads();
    #pragma unroll
    for (int kk = 0; kk < 32; ++kk){
      float x0 = As[kk][ty*2], x1 = As[kk][ty*2+1];
      float y0 = Bs[kk][tx*2], y1 = Bs[kk][tx*2+1];
      a00 += x0*y0; a01 += x0*y1; a10 += x1*y0; a11 += x1*y1;
    }
    __syncthreads();
  }
  int r0 = bm + ty*2, c0 = bn + tx*2;
  #pragma unroll
  for (int i = 0; i < 2; ++i){
    #pragma unroll
    for (int j = 0; j < 2; ++j){
      int r = r0 + i, c = c0 + j;
      float acc = (i==0 ? (j==0?a00:a01) : (j==0?a10:a11));
      g2[(size_t)r*608 + c] = (c < 600) ? geluf(acc + ab1[c]) : 0.f;
    }
  }
}

// GEMM3: final[256][300] = sgs + ab2 + g2[256][608] @ aw2[600][300]
__global__ __launch_bounds__(256)
void k_mlp2(const float* __restrict__ g2, const float* __restrict__ sgs,
            const float* __restrict__ aw2, const float* __restrict__ ab2,
            float* __restrict__ final_g){
  __shared__ float As[32][33], Bs[32][33];
  int t = threadIdx.x;
  int bm = blockIdx.x*32, bn = blockIdx.y*32;
  int tx = t & 15, ty = t >> 4;
  float a00=0.f,a01=0.f,a10=0.f,a11=0.f;
  for (int k0 = 0; k0 < 608; k0 += 32){
    #pragma unroll
    for (int i = 0; i < 4; ++i){
      int idx = t + i*256;
      int kk = idx & 31, m = idx >> 5;
      As[kk][m] = g2[(size_t)(bm+m)*608 + k0 + kk];
    }
    #pragma unroll
    for (int i = 0; i < 4; ++i){
      int idx = t + i*256;
      int n = idx & 31, kk = idx >> 5;
      int kg = k0 + kk, cg = bn + n;
      Bs[kk][n] = (kg < 600 && cg < 300) ? aw2[(size_t)kg*300 + cg] : 0.f;
    }
    __syncthreads();
    #pragma unroll
    for (int kk = 0; kk < 32; ++kk){
      float x0 = As[kk][ty*2], x1 = As[kk][ty*2+1];
      float y0 = Bs[kk][tx*2], y1 = Bs[kk][tx*2+1];
      a00 += x0*y0; a01 += x0*y1; a10 += x1*y0; a11 += x1*y1;
    }
    __syncthreads();
  }
  int r0 = bm + ty*2, c0 = bn + tx*2;
  #pragma unroll
  for (int i = 0; i < 2; ++i){
    #pragma unroll
    for (int j = 0; j < 2; ++j){
      int r = r0 + i, c = c0 + j;
      if (c < 300){
        float acc = (i==0 ? (j==0?a00:a01) : (j==0?a10:a11));
        final_g[(size_t)r*300 + c] = acc + ab2[c] + sgs[(size_t)r*300 + c];
      }
    }
  }
}

// ---------------- K4: cosine ----------------
__global__ __launch_bounds__(64)
void k_cos(const float* __restrict__ final_g, float* __restrict__ out){
  int b = blockIdx.x; int lane = threadIdx.x;
  const float* A  = final_g + b*300;
  const float* Bv = final_g + (128 + b)*300;
  float dot = 0.f, na = 0.f, nb = 0.f;
  for (int i = lane; i < 300; i += 64){
    float x = A[i], y = Bv[i];
    dot += x*y; na += x*x; nb += y*y;
  }
  for (int o = 32; o > 0; o >>= 1){
    dot += __shfl_xor(dot, o); na += __shfl_xor(na, o); nb += __shfl_xor(nb, o);
  }
  if (lane == 0){
    float den = fmaxf(sqrtf(na), 1e-8f) * fmaxf(sqrtf(nb), 1e-8f);
    out[b] = 5.f * dot / den;
  }
}

extern "C" void kernel_launch(void* const* d_in, const int* in_sizes, int n_in,
                              void* d_out, int out_size, void* d_ws, size_t ws_size,
                              hipStream_t stream) {
  const int* ids_a = (const int*)d_in[0];
  const void* mask_a = d_in[1];
  const int* ids_b = (const int*)d_in[2];
  const void* mask_b = d_in[3];
  const float* mu_tab     = (const float*)d_in[4];
  const float* logvar_tab = (const float*)d_in[5];
  const float* alpha_tab  = (const float*)d_in[6];
  const float* feat_tab   = (const float*)d_in[7];
  const float* log_tau    = (const float*)d_in[8];
  const float* pos_mu     = (const float*)d_in[9];
  const float* pos_alpha  = (const float*)d_in[10];
  const float* ln1g = (const float*)d_in[11];
  const float* ln1b = (const float*)d_in[12];
  const float* w1   = (const float*)d_in[13];
  const float* b1   = (const float*)d_in[14];
  const float* w2   = (const float*)d_in[15];
  const float* b2   = (const float*)d_in[16];
  const float* wq   = (const float*)d_in[17];
  const float* bq   = (const float*)d_in[18];
  const float* wk   = (const float*)d_in[19];
  const float* bk   = (const float*)d_in[20];
  const float* ln2g = (const float*)d_in[21];
  const float* ln2b = (const float*)d_in[22];
  const float* aw1  = (const float*)d_in[23];
  const float* ab1  = (const float*)d_in[24];
  const float* aw2  = (const float*)d_in[25];
  const float* ab2  = (const float*)d_in[26];
  float* out = (float*)d_out;

  char* wsb = (char*)d_ws;
  size_t off = 0;
  auto take = [&](size_t bytes) -> void* {
    void* p = wsb + off;
    off += (bytes + 255) & ~(size_t)255;
    return p;
  };

  const size_t uBytes  = (size_t)30000 * 600 * 2;   // 36.0 MB
  const size_t aBytes  = (size_t)30080 * 320 * 2;   // 19.3 MB
  const size_t btBytes = (size_t)640 * 320 * 2;     // 0.41 MB
  const size_t muBytes = (size_t)256 * 512 * 64 * 2;// 16.8 MB
  const size_t need = uBytes + aBytes + btBytes + muBytes + ((size_t)6 << 20);
  if (ws_size < need) return;

  __hip_bfloat16* U = (__hip_bfloat16*)take(uBytes);
  ushort* Abf  = (ushort*)take(aBytes);
  ushort* BTbf = (ushort*)take(btBytes);
  ushort* MuS  = (ushort*)take(muBytes);
  float* fsum   = (float*)take(30000*4);
  float* fsq    = (float*)take(30000*4);
  float* pgw    = (float*)take(8*600*4);
  float* pcv    = (float*)take(8*600*4);
  float* gw_g   = (float*)take(600*4);
  float* c_g    = (float*)take(600*4);
  float* sgs_g  = (float*)take(256*300*4);
  float* ssum_g = (float*)take(256*4);
  float* ssq_g  = (float*)take(256*4);
  float* V_g    = (float*)take(256*600*4);
  float* wgt_g  = (float*)take(256*512*4);
  float* hbar_g = (float*)take((size_t)256*608*4);
  float* Fbar_g = (float*)take(256*300*4);
  float* att_g  = (float*)take(256*300*4);
  float* m_g    = (float*)take(256*4);
  float* rs_g   = (float*)take(256*4);
  float* g2_g   = (float*)take((size_t)256*608*4);
  float* final_g= (float*)take(256*300*4);

  k_pack_a<<<(30080*40 + 255)/256, 256, 0, stream>>>(feat_tab, Abf);
  k_pack_b<<<(640*320 + 255)/256, 256, 0, stream>>>(w1, ln1g, BTbf);
  k_feat_stats<<<7500, 256, 0, stream>>>(feat_tab, fsum, fsq);
  k_gw1_part<<<dim3(3, 8), 256, 0, stream>>>(w1, ln1g, ln1b, pgw, pcv);
  k_gw_reduce<<<3, 256, 0, stream>>>(pgw, pcv, b1, gw_g, c_g);
  k_ugemm_mfma<<<dim3(235, 5), 256, 0, stream>>>(Abf, BTbf, U);
  k_encode_stage1<<<256, 512, 0, stream>>>(ids_a, mask_a, ids_b, mask_b,
                                           mu_tab, logvar_tab, alpha_tab, Abf,
                                           log_tau, pos_mu, pos_alpha,
                                           wq, bq, wk, bk,
                                           MuS, sgs_g, ssum_g, ssq_g, wgt_g);
  k_vgemm<<<600, 256, 0, stream>>>(sgs_g, w1, ln1g, V_g);
  k_hbar_fbar<<<256, 512, 0, stream>>>(ids_a, ids_b, U, Abf, fsum, fsq,
                                       ssum_g, ssq_g, V_g, gw_g, c_g, wgt_g,
                                       hbar_g, Fbar_g);
  k_att<<<dim3(8, 10), 256, 0, stream>>>(hbar_g, Fbar_g, w2, b2, att_g);
  k_lnstats<<<256, 64, 0, stream>>>(att_g, ssum_g, ssq_g, m_g, rs_g);
  k_mlp1<<<dim3(8, 19), 256, 0, stream>>>(sgs_g, att_g, m_g, rs_g, ln2g, ln2b, aw1, ab1, g2_g);
  k_mlp2<<<dim3(8, 10), 256, 0, stream>>>(g2_g, sgs_g, aw2, ab2, final_g);
  k_cos<<<128, 64, 0, stream>>>(final_g, out);
}

// Round 7
// 419.041 us; speedup vs baseline: 1.1989x; 1.0494x over previous
//
#include <hip/hip_runtime.h>
#include <hip/hip_bf16.h>
#include <cstdint>
#include <cstddef>

#define DEV __device__ __forceinline__

// problem constants: B=128, S=512, V=30000, DS=64, DF=300, H=600, BB=256

typedef __attribute__((ext_vector_type(8))) short bf16x8;
typedef __attribute__((ext_vector_type(4))) float f32x4;

DEV float geluf(float x){ return 0.5f*x*(1.f + erff(x*0.7071067811865475f)); }
DEV float gelu_fast(float x){
  float y = 1.5957691216f*(x + 0.044715f*x*x*x);
  return x / (1.f + __expf(-y));
}

DEV float blk_sum512(float* red, int t, float v){
  red[t] = v; __syncthreads();
  for (int o = 256; o > 0; o >>= 1){ if (t < o) red[t] += red[t+o]; __syncthreads(); }
  float r = red[0]; __syncthreads(); return r;
}
DEV float blk_max512(float* red, int t, float v){
  red[t] = v; __syncthreads();
  for (int o = 256; o > 0; o >>= 1){ if (t < o) red[t] = fmaxf(red[t], red[t+o]); __syncthreads(); }
  float r = red[0]; __syncthreads(); return r;
}

DEV ushort f2bf(float v){ __hip_bfloat16 h = __float2bfloat16(v); return *(ushort*)&h; }
DEV float bf2f(ushort u){ __hip_bfloat16 h; *(ushort*)&h = u; return __bfloat162float(h); }

// ---- mask dtype classifier (bool may arrive as u8 / int32 / bf16) ----
DEV int mask_mode(const unsigned char* m){
  bool big = false, off123 = false, off0one = false;
  #pragma unroll
  for (int i = 0; i < 16; ++i){
    unsigned char c = m[i];
    if (c > 1) big = true;
    if ((i & 3) != 0 && c != 0) off123 = true;
    if ((i & 3) == 0 && c == 1) off0one = true;
  }
  if (big) return 2;
  if (!off123 && off0one) return 1;
  return 0;
}
DEV float mask_read(const void* m, int idx, int mode){
  if (mode == 1) return ((const int*)m)[idx] ? 1.f : 0.f;
  if (mode == 2) return ((const unsigned short*)m)[idx] ? 1.f : 0.f;
  return ((const unsigned char*)m)[idx] ? 1.f : 0.f;
}

// ---------------- fused: pack A (bf16 [30080][320]) + per-vocab stats ----------------
__global__ __launch_bounds__(256)
void k_pack_stats(const float* __restrict__ feat, ushort* __restrict__ A,
                  float* __restrict__ fsum, float* __restrict__ fsq){
  int v = blockIdx.x*4 + (threadIdx.x >> 6);
  int ln = threadIdx.x & 63;
  if (v >= 30080) return;
  float vals[8] = {0.f,0.f,0.f,0.f,0.f,0.f,0.f,0.f};
  if (v < 30000 && ln < 38){
    const float* fr = &feat[(size_t)v*300];
    if (ln < 37){
      float4 a = *(const float4*)&fr[ln*8];
      float4 b = *(const float4*)&fr[ln*8 + 4];
      vals[0]=a.x; vals[1]=a.y; vals[2]=a.z; vals[3]=a.w;
      vals[4]=b.x; vals[5]=b.y; vals[6]=b.z; vals[7]=b.w;
    } else {
      float4 a = *(const float4*)&fr[296];
      vals[0]=a.x; vals[1]=a.y; vals[2]=a.z; vals[3]=a.w;
    }
  }
  if (ln < 40){
    union { ushort u[8]; bf16x8 v8; } pk;
    #pragma unroll
    for (int i = 0; i < 8; ++i) pk.u[i] = f2bf(vals[i]);
    *(bf16x8*)&A[(size_t)v*320 + ln*8] = pk.v8;
  }
  float s = 0.f, q = 0.f;
  #pragma unroll
  for (int i = 0; i < 8; ++i){ s += vals[i]; q += vals[i]*vals[i]; }
  for (int o = 32; o > 0; o >>= 1){ s += __shfl_xor(s, o); q += __shfl_xor(q, o); }
  if (ln == 0 && v < 30000){ fsum[v] = s; fsq[v] = q; }
}

// ---------------- P0b: gw1/cv partials ----------------
__global__ __launch_bounds__(256)
void k_gw1_part(const float* __restrict__ w1, const float* __restrict__ g,
                const float* __restrict__ bln, float* __restrict__ pgw, float* __restrict__ pcv){
  int j = blockIdx.x*256 + threadIdx.x;
  int ic = blockIdx.y;
  if (j >= 600) return;
  float a = 0.f, c = 0.f;
  for (int i = ic*75; i < ic*75 + 75; ++i){
    float w = w1[i*600 + j];
    a += g[i]*w; c += bln[i]*w;
  }
  pgw[ic*600 + j] = a; pcv[ic*600 + j] = c;
}

__global__ __launch_bounds__(256)
void k_gw_reduce(const float* __restrict__ pgw, const float* __restrict__ pcv,
                 const float* __restrict__ b1, float* __restrict__ gw_g, float* __restrict__ c_g){
  int j = blockIdx.x*256 + threadIdx.x;
  if (j >= 600) return;
  float a = 0.f, c = 0.f;
  for (int k = 0; k < 8; ++k){ a += pgw[k*600 + j]; c += pcv[k*600 + j]; }
  gw_g[j] = a; c_g[j] = c + b1[j];
}

// ---------------- pack B^T: BT[n][k] = g[k]*w1[k*600+n], bf16 [640][320] ----------------
__global__ __launch_bounds__(256)
void k_pack_b(const float* __restrict__ w1, const float* __restrict__ g, ushort* __restrict__ BT){
  int id = blockIdx.x*256 + threadIdx.x;
  if (id >= 640*320) return;
  int n = id % 640, k = id / 640;
  float val = (k < 300 && n < 600) ? g[k]*w1[k*600 + n] : 0.f;
  BT[(size_t)n*320 + k] = f2bf(val);
}

// ---------------- P1: U = A @ B via MFMA 16x16x32 bf16, 128x128 tile ----------------
__global__ __launch_bounds__(256)
void k_ugemm_mfma(const ushort* __restrict__ A, const ushort* __restrict__ BT,
                  __hip_bfloat16* __restrict__ U){
  __shared__ ushort As[128][40];
  __shared__ ushort Bs[128][40];
  int tid = threadIdx.x;
  int bm = blockIdx.x * 128, bn = blockIdx.y * 128;
  int wid = tid >> 6, lane = tid & 63;
  int wr = wid >> 1, wc = wid & 1;
  int lr = lane & 15, lk = lane >> 4;
  f32x4 acc[4][4] = {};
  for (int k0 = 0; k0 < 320; k0 += 32){
    #pragma unroll
    for (int j = 0; j < 2; ++j){
      int idx = tid + 256*j;
      int row = idx >> 2, ko = (idx & 3)*8;
      *(bf16x8*)&As[row][ko] = *(const bf16x8*)&A[(size_t)(bm+row)*320 + k0 + ko];
      *(bf16x8*)&Bs[row][ko] = *(const bf16x8*)&BT[(size_t)(bn+row)*320 + k0 + ko];
    }
    __syncthreads();
    bf16x8 af[4], bfr[4];
    #pragma unroll
    for (int f = 0; f < 4; ++f){
      af[f]  = *(const bf16x8*)&As[wr*64 + f*16 + lr][lk*8];
      bfr[f] = *(const bf16x8*)&Bs[wc*64 + f*16 + lr][lk*8];
    }
    #pragma unroll
    for (int i = 0; i < 4; ++i)
      #pragma unroll
      for (int j = 0; j < 4; ++j)
        acc[i][j] = __builtin_amdgcn_mfma_f32_16x16x32_bf16(af[i], bfr[j], acc[i][j], 0, 0, 0);
    __syncthreads();
  }
  #pragma unroll
  for (int i = 0; i < 4; ++i){
    #pragma unroll
    for (int j = 0; j < 4; ++j){
      #pragma unroll
      for (int r = 0; r < 4; ++r){
        int row = bm + wr*64 + i*16 + lk*4 + r;
        int col = bn + wc*64 + j*16 + lr;
        if (row < 30000 && col < 600)
          U[(size_t)row*600 + col] = __float2bfloat16(acc[i][j][r]);
      }
    }
  }
}

// ---------------- K1: stage 1 (staged mu; fp32 float4 render — round-4 pattern) ----------------
__global__ __launch_bounds__(512)
void k_encode_stage1(const int* __restrict__ ids_a, const void* __restrict__ mask_a,
                     const int* __restrict__ ids_b, const void* __restrict__ mask_b,
                     const float* __restrict__ mu_tab, const float* __restrict__ logvar_tab,
                     const float* __restrict__ alpha_tab, const float* __restrict__ feat_tab,
                     const float* __restrict__ log_tau, const float* __restrict__ pos_mu,
                     const float* __restrict__ pos_alpha,
                     const float* __restrict__ wq, const float* __restrict__ bq,
                     const float* __restrict__ wk, const float* __restrict__ bk,
                     ushort* __restrict__ MuS,
                     float* __restrict__ sgs_g,
                     float* __restrict__ ssum_g, float* __restrict__ ssq_g,
                     float* __restrict__ wgt_g)
{
  int bb = blockIdx.x;
  const int* ids = (bb < 128) ? ids_a : ids_b;
  const void* msk = (bb < 128) ? mask_a : mask_b;
  int b = bb & 127;
  int t = threadIdx.x;

  __shared__ int   ids_l[512];
  __shared__ float mf_l[512], al_l[512], w_l[512], red[512];
  __shared__ float cent[64], q_l[64], qk_l[64];
  __shared__ float sgs_l[304];
  __shared__ float gpart[32][64];
  __shared__ float pacc[8][304];
  __shared__ float bkq_s;
  __shared__ int mmode;

  if (t == 0) mmode = mask_mode((const unsigned char*)msk);
  __syncthreads();

  {
    int id = ids[b*512 + t];
    float mf = mask_read(msk, b*512 + t, mmode);
    ids_l[t] = id; mf_l[t] = mf;
    float pa = pos_alpha[t];
    al_l[t] = alpha_tab[id] * (1.f/(1.f + expf(-pa))) * mf;
  }
  __syncthreads();
  float msum = blk_sum512(red, t, mf_l[t]);

  int grp = t >> 4, sub = t & 15;
  ushort* MuB = MuS + (size_t)bb*512*64;

  // phase 1: gather mu+pos once, stage bf16, centroid partials
  {
    float cp0=0.f, cp1=0.f, cp2=0.f, cp3=0.f;
    for (int k = 0; k < 16; ++k){
      int s = (grp << 4) | k;
      int id = ids_l[s];
      float4 m4 = *(const float4*)&mu_tab[(size_t)id*64 + sub*4];
      float4 p4 = *(const float4*)&pos_mu[s*64 + sub*4];
      float v0 = m4.x + p4.x, v1 = m4.y + p4.y, v2 = m4.z + p4.z, v3 = m4.w + p4.w;
      ushort4 st; st.x = f2bf(v0); st.y = f2bf(v1); st.z = f2bf(v2); st.w = f2bf(v3);
      *(ushort4*)&MuB[(size_t)s*64 + sub*4] = st;
      float mf = mf_l[s];
      cp0 += mf*v0; cp1 += mf*v1; cp2 += mf*v2; cp3 += mf*v3;
    }
    gpart[grp][sub*4+0] = cp0; gpart[grp][sub*4+1] = cp1;
    gpart[grp][sub*4+2] = cp2; gpart[grp][sub*4+3] = cp3;
  }
  __syncthreads();
  if (t < 64){
    float c = 0.f;
    for (int g = 0; g < 32; ++g) c += gpart[g][t];
    cent[t] = c / fmaxf(msum, 1.f);
  }
  __syncthreads();

  // phase 2: d2 -> w = alpha*K
  {
    float itau = expf(-log_tau[0]);
    float c0 = cent[sub*4+0], c1 = cent[sub*4+1], c2 = cent[sub*4+2], c3 = cent[sub*4+3];
    for (int k = 0; k < 16; ++k){
      int s = (grp << 4) | k;
      int id = ids_l[s];
      float4 lv = *(const float4*)&logvar_tab[(size_t)id*64 + sub*4];
      ushort4 mu = *(const ushort4*)&MuB[(size_t)s*64 + sub*4];
      float d0 = bf2f(mu.x) - c0, d1 = bf2f(mu.y) - c1, d2v = bf2f(mu.z) - c2, d3 = bf2f(mu.w) - c3;
      float val = d0*d0*expf(-lv.x) + d1*d1*expf(-lv.y) + d2v*d2v*expf(-lv.z) + d3*d3*expf(-lv.w);
      val += __shfl_xor(val, 1); val += __shfl_xor(val, 2);
      val += __shfl_xor(val, 4); val += __shfl_xor(val, 8);
      if (sub == 0){
        float K = expf(-0.5f * val * itau) * mf_l[s];
        w_l[s] = al_l[s] * K;
      }
    }
  }
  __syncthreads();
  float wsum = blk_sum512(red, t, w_l[t]);

  // phase 3: sgs render — wave-per-token, fp32 float4 gathers (round-4 pattern)
  {
    int wv = t >> 6, ln = t & 63;
    float a10=0.f,a11=0.f,a12=0.f,a13=0.f, a20=0.f,a21=0.f,a22=0.f,a23=0.f;
    for (int k = 0; k < 64; ++k){
      int s = (wv << 6) | k;
      float w = w_l[s];
      const float* fr = &feat_tab[(size_t)ids_l[s]*300];
      float4 v1 = *(const float4*)&fr[ln*4];
      a10 += w*v1.x; a11 += w*v1.y; a12 += w*v1.z; a13 += w*v1.w;
      if (ln < 11){
        float4 v2 = *(const float4*)&fr[256 + ln*4];
        a20 += w*v2.x; a21 += w*v2.y; a22 += w*v2.z; a23 += w*v2.w;
      }
    }
    pacc[wv][ln*4+0]=a10; pacc[wv][ln*4+1]=a11; pacc[wv][ln*4+2]=a12; pacc[wv][ln*4+3]=a13;
    if (ln < 11){
      pacc[wv][256+ln*4+0]=a20; pacc[wv][256+ln*4+1]=a21;
      pacc[wv][256+ln*4+2]=a22; pacc[wv][256+ln*4+3]=a23;
    }
  }
  __syncthreads();
  if (t < 300){
    float sacc = 0.f;
    #pragma unroll
    for (int w = 0; w < 8; ++w) sacc += pacc[w][t];
    float sv = sacc / fmaxf(wsum, 1e-8f);
    sgs_l[t] = sv;
    sgs_g[bb*300 + t] = sv;
  }
  __syncthreads();
  float ssum = blk_sum512(red, t, (t < 300) ? sgs_l[t] : 0.f);
  float ssq  = blk_sum512(red, t, (t < 300) ? sgs_l[t]*sgs_l[t] : 0.f);
  if (t == 0){ ssum_g[bb] = ssum; ssq_g[bb] = ssq; }

  // phase 4: query / qk / bkq
  if (t < 64){
    float q = bq[t];
    for (int i = 0; i < 300; ++i) q += sgs_l[i]*wq[i*64 + t];
    q_l[t] = q;
  }
  __syncthreads();
  if (t < 64){
    float a = 0.f;
    for (int j = 0; j < 64; ++j) a += wk[t*64 + j]*q_l[j];
    qk_l[t] = a;
  }
  if (t == 0){
    float s = 0.f;
    for (int j = 0; j < 64; ++j) s += bk[j]*q_l[j];
    bkq_s = s;
  }
  __syncthreads();

  // phase 5: scores from staged mu
  {
    float q0 = qk_l[sub*4+0], q1 = qk_l[sub*4+1], q2 = qk_l[sub*4+2], q3 = qk_l[sub*4+3];
    for (int k = 0; k < 16; ++k){
      int s = (grp << 4) | k;
      ushort4 mu = *(const ushort4*)&MuB[(size_t)s*64 + sub*4];
      float val = bf2f(mu.x)*q0 + bf2f(mu.y)*q1 + bf2f(mu.z)*q2 + bf2f(mu.w)*q3;
      val += __shfl_xor(val, 1); val += __shfl_xor(val, 2);
      val += __shfl_xor(val, 4); val += __shfl_xor(val, 8);
      if (sub == 0){
        float sv = (val + bkq_s) * 0.125f;
        w_l[s] = (mf_l[s] != 0.f) ? sv : -1e30f;
      }
    }
  }
  __syncthreads();

  // phase 6: softmax
  float mx = blk_max512(red, t, w_l[t]);
  float ex = expf(w_l[t] - mx);
  float Z  = blk_sum512(red, t, ex);
  wgt_g[bb*512 + t] = ex / Z;
}

// ---------------- k_vgemm: V[bb][j] ----------------
__global__ __launch_bounds__(256)
void k_vgemm(const float* __restrict__ sgs_g, const float* __restrict__ w1,
             const float* __restrict__ ln1g, float* __restrict__ V_g){
  int j = blockIdx.x;
  __shared__ float col[300];
  for (int i = threadIdx.x; i < 300; i += 256)
    col[i] = ln1g[300 + i]*w1[(size_t)(300 + i)*600 + j];
  __syncthreads();
  int bb = threadIdx.x;
  const float* sr = &sgs_g[bb*300];
  float acc = 0.f;
  #pragma unroll 4
  for (int i = 0; i < 300; ++i) acc += sr[i]*col[i];
  V_g[bb*600 + j] = acc;
}

// ---------------- K2: hbar + Fbar quarter-split (1024 blocks x 256 thr) ----------------
// partial outputs: hbar_p[4][256][608] (cols 600..607 zeroed), Fbar_p[4][256][300]
__global__ __launch_bounds__(256)
void k_hbar_fbar(const int* __restrict__ ids_a, const int* __restrict__ ids_b,
                 const __hip_bfloat16* __restrict__ U, const float* __restrict__ feat_tab,
                 const float* __restrict__ fsum, const float* __restrict__ fsq,
                 const float* __restrict__ ssum_g, const float* __restrict__ ssq_g,
                 const float* __restrict__ V_g, const float* __restrict__ gw_g,
                 const float* __restrict__ c_g, const float* __restrict__ wgt_g,
                 float* __restrict__ hbar_p, float* __restrict__ Fbar_p)
{
  int blk = blockIdx.x;            // bb*4 + quarter
  int bb = blk >> 2, qr = blk & 3;
  int b = bb & 127;
  const int* ids = (bb < 128) ? ids_a : ids_b;
  int t = threadIdx.x;
  __shared__ int id_l[128];
  __shared__ float m_l[128], rs_l[128], wg_l[128];
  __shared__ float hp[4][600];
  __shared__ float fp[4][304];
  float ss = ssum_g[bb], sq = ssq_g[bb];
  if (t < 128){
    int s = qr*128 + t;
    int id = ids[b*512 + s];
    id_l[t] = id;
    float m = (fsum[id] + ss) * (1.f/600.f);
    float var = (fsq[id] + sq) * (1.f/600.f) - m*m;
    m_l[t] = m;
    rs_l[t] = 1.f / sqrtf(var + 1e-5f);
    wg_l[t] = wgt_g[bb*512 + s];
  }
  __syncthreads();

  int wv = t >> 6, ln = t & 63;
  float Vp[8], gwp[8], cp[8], Vs[8], gws[8], cs[8];
  #pragma unroll
  for (int r = 0; r < 8; ++r){
    int j = ln*8 + r;
    Vp[r] = V_g[bb*600 + j]; gwp[r] = gw_g[j]; cp[r] = c_g[j];
    Vs[r] = 0.f; gws[r] = 0.f; cs[r] = 0.f;
  }
  if (ln < 11){
    #pragma unroll
    for (int r = 0; r < 8; ++r){
      int j = 512 + ln*8 + r;
      Vs[r] = V_g[bb*600 + j]; gws[r] = gw_g[j]; cs[r] = c_g[j];
    }
  }
  float h1[8] = {}, h2[8] = {};
  float f10=0.f,f11=0.f,f12=0.f,f13=0.f, f20=0.f,f21=0.f,f22=0.f,f23=0.f;

  for (int k = 0; k < 32; ++k){
    int s = (wv << 5) | k;           // token index within quarter (0..127)
    int id = id_l[s];
    float w = wg_l[s], m = m_l[s], rs = rs_l[s];
    const __hip_bfloat16* ur = &U[(size_t)id*600];
    const float* fr = &feat_tab[(size_t)id*300];
    bf16x8 u8 = *(const bf16x8*)&ur[ln*8];
    float4 fv = *(const float4*)&fr[ln*4];
    #pragma unroll
    for (int r = 0; r < 8; ++r){
      float u = bf2f((ushort)u8[r]);
      float a = (u + Vp[r] - m*gwp[r])*rs + cp[r];
      h1[r] += w*gelu_fast(a);
    }
    f10 += w*fv.x; f11 += w*fv.y; f12 += w*fv.z; f13 += w*fv.w;
    if (ln < 11){
      bf16x8 u8b = *(const bf16x8*)&ur[512 + ln*8];
      float4 fvb = *(const float4*)&fr[256 + ln*4];
      #pragma unroll
      for (int r = 0; r < 8; ++r){
        float u = bf2f((ushort)u8b[r]);
        float a = (u + Vs[r] - m*gws[r])*rs + cs[r];
        h2[r] += w*gelu_fast(a);
      }
      f20 += w*fvb.x; f21 += w*fvb.y; f22 += w*fvb.z; f23 += w*fvb.w;
    }
  }
  #pragma unroll
  for (int r = 0; r < 8; ++r) hp[wv][ln*8 + r] = h1[r];
  if (ln < 11){
    #pragma unroll
    for (int r = 0; r < 8; ++r) hp[wv][512 + ln*8 + r] = h2[r];
  }
  fp[wv][ln*4+0]=f10; fp[wv][ln*4+1]=f11; fp[wv][ln*4+2]=f12; fp[wv][ln*4+3]=f13;
  if (ln < 11){
    fp[wv][256+ln*4+0]=f20; fp[wv][256+ln*4+1]=f21;
    fp[wv][256+ln*4+2]=f22; fp[wv][256+ln*4+3]=f23;
  }
  __syncthreads();
  size_t hbase = ((size_t)qr*256 + bb)*608;
  for (int j = t; j < 600; j += 256){
    float s = hp[0][j] + hp[1][j] + hp[2][j] + hp[3][j];
    hbar_p[hbase + j] = s;
  }
  if (t < 8) hbar_p[hbase + 600 + t] = 0.f;
  size_t fbase = ((size_t)qr*256 + bb)*300;
  for (int j = t; j < 300; j += 256){
    float s = fp[0][j] + fp[1][j] + fp[2][j] + fp[3][j];
    Fbar_p[fbase + j] = s;
  }
}

// ============ final chain as small tiled fp32 GEMMs (32x32 tiles, 2x2/thread) ============

// GEMM1: att[256][300] = b2 + sum_q Fbar_p + (sum_q hbar_p) @ w2
__global__ __launch_bounds__(256)
void k_att(const float* __restrict__ hbar_p, const float* __restrict__ Fbar_p,
           const float* __restrict__ w2, const float* __restrict__ b2,
           float* __restrict__ att){
  __shared__ float As[32][33], Bs[32][33];
  int t = threadIdx.x;
  int bm = blockIdx.x*32, bn = blockIdx.y*32;
  int tx = t & 15, ty = t >> 4;
  const size_t Q = (size_t)256*608;
  float a00=0.f,a01=0.f,a10=0.f,a11=0.f;
  for (int k0 = 0; k0 < 608; k0 += 32){
    #pragma unroll
    for (int i = 0; i < 4; ++i){
      int idx = t + i*256;
      int kk = idx & 31, m = idx >> 5;
      size_t base = (size_t)(bm+m)*608 + k0 + kk;
      As[kk][m] = hbar_p[base] + hbar_p[Q + base] + hbar_p[2*Q + base] + hbar_p[3*Q + base];
    }
    #pragma unroll
    for (int i = 0; i < 4; ++i){
      int idx = t + i*256;
      int n = idx & 31, kk = idx >> 5;
      int kg = k0 + kk, cg = bn + n;
      Bs[kk][n] = (kg < 600 && cg < 300) ? w2[(size_t)kg*300 + cg] : 0.f;
    }
    __syncthreads();
    #pragma unroll
    for (int kk = 0; kk < 32; ++kk){
      float x0 = As[kk][ty*2], x1 = As[kk][ty*2+1];
      float y0 = Bs[kk][tx*2], y1 = Bs[kk][tx*2+1];
      a00 += x0*y0; a01 += x0*y1; a10 += x1*y0; a11 += x1*y1;
    }
    __syncthreads();
  }
  const size_t QF = (size_t)256*300;
  int r0 = bm + ty*2, c0 = bn + tx*2;
  #pragma unroll
  for (int i = 0; i < 2; ++i){
    #pragma unroll
    for (int j = 0; j < 2; ++j){
      int r = r0 + i, c = c0 + j;
      if (c < 300){
        float acc = (i==0 ? (j==0?a00:a01) : (j==0?a10:a11));
        size_t fb = (size_t)r*300 + c;
        acc += Fbar_p[fb] + Fbar_p[QF + fb] + Fbar_p[2*QF + fb] + Fbar_p[3*QF + fb];
        att[(size_t)r*300 + c] = acc + b2[c];
      }
    }
  }
}

// LN2 stats per row
__global__ __launch_bounds__(64)
void k_lnstats(const float* __restrict__ att, const float* __restrict__ ssum_g,
               const float* __restrict__ ssq_g, float* __restrict__ m_g, float* __restrict__ rs_g){
  int bb = blockIdx.x, lane = threadIdx.x;
  float s = 0.f, q = 0.f;
  for (int i = lane; i < 300; i += 64){
    float v = att[(size_t)bb*300 + i];
    s += v; q += v*v;
  }
  for (int o = 32; o > 0; o >>= 1){ s += __shfl_xor(s, o); q += __shfl_xor(q, o); }
  if (lane == 0){
    float m = (ssum_g[bb] + s) * (1.f/600.f);
    float var = (ssq_g[bb] + q) * (1.f/600.f) - m*m;
    m_g[bb] = m;
    rs_g[bb] = 1.f / sqrtf(var + 1e-5f);
  }
}

// GEMM2: g2[256][608] = gelu(LN2([sgs|att]) @ aw1[600][600] + ab1)
__global__ __launch_bounds__(256)
void k_mlp1(const float* __restrict__ sgs, const float* __restrict__ att,
            const float* __restrict__ m_g, const float* __restrict__ rs_g,
            const float* __restrict__ ln2g, const float* __restrict__ ln2b,
            const float* __restrict__ aw1, const float* __restrict__ ab1,
            float* __restrict__ g2){
  __shared__ float As[32][33], Bs[32][33];
  int t = threadIdx.x;
  int bm = blockIdx.x*32, bn = blockIdx.y*32;
  int tx = t & 15, ty = t >> 4;
  float a00=0.f,a01=0.f,a10=0.f,a11=0.f;
  for (int k0 = 0; k0 < 608; k0 += 32){
    #pragma unroll
    for (int i = 0; i < 4; ++i){
      int idx = t + i*256;
      int kk = idx & 31, m = idx >> 5;
      int kg = k0 + kk, row = bm + m;
      float t2 = 0.f;
      if (kg < 600){
        float x = (kg < 300) ? sgs[(size_t)row*300 + kg] : att[(size_t)row*300 + kg - 300];
        t2 = (x - m_g[row])*rs_g[row]*ln2g[kg] + ln2b[kg];
      }
      As[kk][m] = t2;
    }
    #pragma unroll
    for (int i = 0; i < 4; ++i){
      int idx = t + i*256;
      int n = idx & 31, kk = idx >> 5;
      int kg = k0 + kk, cg = bn + n;
      Bs[kk][n] = (kg < 600 && cg < 600) ? aw1[(size_t)kg*600 + cg] : 0.f;
    }
    __syncthreads();
    #pragma unroll
    for (int kk = 0; kk < 32; ++kk){
      float x0 = As[kk][ty*2], x1 = As[kk][ty*2+1];
      float y0 = Bs[kk][tx*2], y1 = Bs[kk][tx*2+1];
      a00 += x0*y0; a01 += x0*y1; a10 += x1*y0; a11 += x1*y1;
    }
    __syncthreads();
  }
  int r0 = bm + ty*2, c0 = bn + tx*2;
  #pragma unroll
  for (int i = 0; i < 2; ++i){
    #pragma unroll
    for (int j = 0; j < 2; ++j){
      int r = r0 + i, c = c0 + j;
      float acc = (i==0 ? (j==0?a00:a01) : (j==0?a10:a11));
      g2[(size_t)r*608 + c] = (c < 600) ? geluf(acc + ab1[c]) : 0.f;
    }
  }
}

// GEMM3: final[256][300] = sgs + ab2 + g2[256][608] @ aw2[600][300]
__global__ __launch_bounds__(256)
void k_mlp2(const float* __restrict__ g2, const float* __restrict__ sgs,
            const float* __restrict__ aw2, const float* __restrict__ ab2,
            float* __restrict__ final_g){
  __shared__ float As[32][33], Bs[32][33];
  int t = threadIdx.x;
  int bm = blockIdx.x*32, bn = blockIdx.y*32;
  int tx = t & 15, ty = t >> 4;
  float a00=0.f,a01=0.f,a10=0.f,a11=0.f;
  for (int k0 = 0; k0 < 608; k0 += 32){
    #pragma unroll
    for (int i = 0; i < 4; ++i){
      int idx = t + i*256;
      int kk = idx & 31, m = idx >> 5;
      As[kk][m] = g2[(size_t)(bm+m)*608 + k0 + kk];
    }
    #pragma unroll
    for (int i = 0; i < 4; ++i){
      int idx = t + i*256;
      int n = idx & 31, kk = idx >> 5;
      int kg = k0 + kk, cg = bn + n;
      Bs[kk][n] = (kg < 600 && cg < 300) ? aw2[(size_t)kg*300 + cg] : 0.f;
    }
    __syncthreads();
    #pragma unroll
    for (int kk = 0; kk < 32; ++kk){
      float x0 = As[kk][ty*2], x1 = As[kk][ty*2+1];
      float y0 = Bs[kk][tx*2], y1 = Bs[kk][tx*2+1];
      a00 += x0*y0; a01 += x0*y1; a10 += x1*y0; a11 += x1*y1;
    }
    __syncthreads();
  }
  int r0 = bm + ty*2, c0 = bn + tx*2;
  #pragma unroll
  for (int i = 0; i < 2; ++i){
    #pragma unroll
    for (int j = 0; j < 2; ++j){
      int r = r0 + i, c = c0 + j;
      if (c < 300){
        float acc = (i==0 ? (j==0?a00:a01) : (j==0?a10:a11));
        final_g[(size_t)r*300 + c] = acc + ab2[c] + sgs[(size_t)r*300 + c];
      }
    }
  }
}

// ---------------- K4: cosine ----------------
__global__ __launch_bounds__(64)
void k_cos(const float* __restrict__ final_g, float* __restrict__ out){
  int b = blockIdx.x; int lane = threadIdx.x;
  const float* A  = final_g + b*300;
  const float* Bv = final_g + (128 + b)*300;
  float dot = 0.f, na = 0.f, nb = 0.f;
  for (int i = lane; i < 300; i += 64){
    float x = A[i], y = Bv[i];
    dot += x*y; na += x*x; nb += y*y;
  }
  for (int o = 32; o > 0; o >>= 1){
    dot += __shfl_xor(dot, o); na += __shfl_xor(na, o); nb += __shfl_xor(nb, o);
  }
  if (lane == 0){
    float den = fmaxf(sqrtf(na), 1e-8f) * fmaxf(sqrtf(nb), 1e-8f);
    out[b] = 5.f * dot / den;
  }
}

extern "C" void kernel_launch(void* const* d_in, const int* in_sizes, int n_in,
                              void* d_out, int out_size, void* d_ws, size_t ws_size,
                              hipStream_t stream) {
  const int* ids_a = (const int*)d_in[0];
  const void* mask_a = d_in[1];
  const int* ids_b = (const int*)d_in[2];
  const void* mask_b = d_in[3];
  const float* mu_tab     = (const float*)d_in[4];
  const float* logvar_tab = (const float*)d_in[5];
  const float* alpha_tab  = (const float*)d_in[6];
  const float* feat_tab   = (const float*)d_in[7];
  const float* log_tau    = (const float*)d_in[8];
  const float* pos_mu     = (const float*)d_in[9];
  const float* pos_alpha  = (const float*)d_in[10];
  const float* ln1g = (const float*)d_in[11];
  const float* ln1b = (const float*)d_in[12];
  const float* w1   = (const float*)d_in[13];
  const float* b1   = (const float*)d_in[14];
  const float* w2   = (const float*)d_in[15];
  const float* b2   = (const float*)d_in[16];
  const float* wq   = (const float*)d_in[17];
  const float* bq   = (const float*)d_in[18];
  const float* wk   = (const float*)d_in[19];
  const float* bk   = (const float*)d_in[20];
  const float* ln2g = (const float*)d_in[21];
  const float* ln2b = (const float*)d_in[22];
  const float* aw1  = (const float*)d_in[23];
  const float* ab1  = (const float*)d_in[24];
  const float* aw2  = (const float*)d_in[25];
  const float* ab2  = (const float*)d_in[26];
  float* out = (float*)d_out;

  char* wsb = (char*)d_ws;
  size_t off = 0;
  auto take = [&](size_t bytes) -> void* {
    void* p = wsb + off;
    off += (bytes + 255) & ~(size_t)255;
    return p;
  };

  const size_t uBytes  = (size_t)30000 * 600 * 2;   // 36.0 MB
  const size_t aBytes  = (size_t)30080 * 320 * 2;   // 19.3 MB
  const size_t btBytes = (size_t)640 * 320 * 2;     // 0.41 MB
  const size_t muBytes = (size_t)256 * 512 * 64 * 2;// 16.8 MB (aliased post-stage1)
  const size_t need = uBytes + aBytes + btBytes + muBytes + ((size_t)4 << 20);
  if (ws_size < need) return;

  __hip_bfloat16* U = (__hip_bfloat16*)take(uBytes);
  ushort* Abf  = (ushort*)take(aBytes);
  ushort* BTbf = (ushort*)take(btBytes);
  char* muRegion = (char*)take(muBytes);
  ushort* MuS = (ushort*)muRegion;
  // alias post-stage1 buffers onto the (dead-after-stage1) MuS region:
  float* hbar_p = (float*)(muRegion + 0);                 // 4*256*608*4 = 2490368
  float* Fbar_p = (float*)(muRegion + 2490368);           // 4*256*300*4 = 1228800
  float* att_g  = (float*)(muRegion + 2490368 + 1228800); // 256*300*4   = 307200
  float* g2_g   = (float*)(muRegion + 4026368);           // 256*608*4   = 622592
  float* final_g= (float*)(muRegion + 4648960);           // 256*300*4   = 307200

  float* fsum   = (float*)take(30000*4);
  float* fsq    = (float*)take(30000*4);
  float* pgw    = (float*)take(8*600*4);
  float* pcv    = (float*)take(8*600*4);
  float* gw_g   = (float*)take(600*4);
  float* c_g    = (float*)take(600*4);
  float* sgs_g  = (float*)take(256*300*4);
  float* ssum_g = (float*)take(256*4);
  float* ssq_g  = (float*)take(256*4);
  float* V_g    = (float*)take(256*600*4);
  float* wgt_g  = (float*)take(256*512*4);
  float* m_g    = (float*)take(256*4);
  float* rs_g   = (float*)take(256*4);

  k_pack_stats<<<7520, 256, 0, stream>>>(feat_tab, Abf, fsum, fsq);
  k_pack_b<<<(640*320 + 255)/256, 256, 0, stream>>>(w1, ln1g, BTbf);
  k_gw1_part<<<dim3(3, 8), 256, 0, stream>>>(w1, ln1g, ln1b, pgw, pcv);
  k_gw_reduce<<<3, 256, 0, stream>>>(pgw, pcv, b1, gw_g, c_g);
  k_ugemm_mfma<<<dim3(235, 5), 256, 0, stream>>>(Abf, BTbf, U);
  k_encode_stage1<<<256, 512, 0, stream>>>(ids_a, mask_a, ids_b, mask_b,
                                           mu_tab, logvar_tab, alpha_tab, feat_tab,
                                           log_tau, pos_mu, pos_alpha,
                                           wq, bq, wk, bk,
                                           MuS, sgs_g, ssum_g, ssq_g, wgt_g);
  k_vgemm<<<600, 256, 0, stream>>>(sgs_g, w1, ln1g, V_g);
  k_hbar_fbar<<<1024, 256, 0, stream>>>(ids_a, ids_b, U, feat_tab, fsum, fsq,
                                        ssum_g, ssq_g, V_g, gw_g, c_g, wgt_g,
                                        hbar_p, Fbar_p);
  k_att<<<dim3(8, 10), 256, 0, stream>>>(hbar_p, Fbar_p, w2, b2, att_g);
  k_lnstats<<<256, 64, 0, stream>>>(att_g, ssum_g, ssq_g, m_g, rs_g);
  k_mlp1<<<dim3(8, 19), 256, 0, stream>>>(sgs_g, att_g, m_g, rs_g, ln2g, ln2b, aw1, ab1, g2_g);
  k_mlp2<<<dim3(8, 10), 256, 0, stream>>>(g2_g, sgs_g, aw2, ab2, final_g);
  k_cos<<<128, 64, 0, stream>>>(final_g, out);
}

// Round 8
// 412.909 us; speedup vs baseline: 1.2167x; 1.0148x over previous
//
#include <hip/hip_runtime.h>
#include <hip/hip_bf16.h>
#include <cstdint>
#include <cstddef>

#define DEV __device__ __forceinline__

// problem constants: B=128, S=512, V=30000, DS=64, DF=300, H=600, BB=256

typedef __attribute__((ext_vector_type(8))) short bf16x8;
typedef __attribute__((ext_vector_type(4))) float f32x4;

DEV float geluf(float x){ return 0.5f*x*(1.f + erff(x*0.7071067811865475f)); }
DEV float gelu_fast(float x){
  float y = 1.5957691216f*(x + 0.044715f*x*x*x);
  return x / (1.f + __expf(-y));
}

DEV float blk_sum512(float* red, int t, float v){
  red[t] = v; __syncthreads();
  for (int o = 256; o > 0; o >>= 1){ if (t < o) red[t] += red[t+o]; __syncthreads(); }
  float r = red[0]; __syncthreads(); return r;
}
DEV float blk_max512(float* red, int t, float v){
  red[t] = v; __syncthreads();
  for (int o = 256; o > 0; o >>= 1){ if (t < o) red[t] = fmaxf(red[t], red[t+o]); __syncthreads(); }
  float r = red[0]; __syncthreads(); return r;
}

DEV ushort f2bf(float v){ __hip_bfloat16 h = __float2bfloat16(v); return *(ushort*)&h; }
DEV float bf2f(ushort u){ __hip_bfloat16 h; *(ushort*)&h = u; return __bfloat162float(h); }

// ---- mask dtype classifier (bool may arrive as u8 / int32 / bf16) ----
DEV int mask_mode(const unsigned char* m){
  bool big = false, off123 = false, off0one = false;
  #pragma unroll
  for (int i = 0; i < 16; ++i){
    unsigned char c = m[i];
    if (c > 1) big = true;
    if ((i & 3) != 0 && c != 0) off123 = true;
    if ((i & 3) == 0 && c == 1) off0one = true;
  }
  if (big) return 2;
  if (!off123 && off0one) return 1;
  return 0;
}
DEV float mask_read(const void* m, int idx, int mode){
  if (mode == 1) return ((const int*)m)[idx] ? 1.f : 0.f;
  if (mode == 2) return ((const unsigned short*)m)[idx] ? 1.f : 0.f;
  return ((const unsigned char*)m)[idx] ? 1.f : 0.f;
}

// ---------------- fused: pack A (bf16 [30080][320]) + per-vocab stats ----------------
__global__ __launch_bounds__(256)
void k_pack_stats(const float* __restrict__ feat, ushort* __restrict__ A,
                  float* __restrict__ fsum, float* __restrict__ fsq){
  int v = blockIdx.x*4 + (threadIdx.x >> 6);
  int ln = threadIdx.x & 63;
  if (v >= 30080) return;
  float vals[8] = {0.f,0.f,0.f,0.f,0.f,0.f,0.f,0.f};
  if (v < 30000 && ln < 38){
    const float* fr = &feat[(size_t)v*300];
    if (ln < 37){
      float4 a = *(const float4*)&fr[ln*8];
      float4 b = *(const float4*)&fr[ln*8 + 4];
      vals[0]=a.x; vals[1]=a.y; vals[2]=a.z; vals[3]=a.w;
      vals[4]=b.x; vals[5]=b.y; vals[6]=b.z; vals[7]=b.w;
    } else {
      float4 a = *(const float4*)&fr[296];
      vals[0]=a.x; vals[1]=a.y; vals[2]=a.z; vals[3]=a.w;
    }
  }
  if (ln < 40){
    union { ushort u[8]; bf16x8 v8; } pk;
    #pragma unroll
    for (int i = 0; i < 8; ++i) pk.u[i] = f2bf(vals[i]);
    *(bf16x8*)&A[(size_t)v*320 + ln*8] = pk.v8;
  }
  float s = 0.f, q = 0.f;
  #pragma unroll
  for (int i = 0; i < 8; ++i){ s += vals[i]; q += vals[i]*vals[i]; }
  for (int o = 32; o > 0; o >>= 1){ s += __shfl_xor(s, o); q += __shfl_xor(q, o); }
  if (ln == 0 && v < 30000){ fsum[v] = s; fsq[v] = q; }
}

// ---------------- P0b: gw1/cv partials ----------------
__global__ __launch_bounds__(256)
void k_gw1_part(const float* __restrict__ w1, const float* __restrict__ g,
                const float* __restrict__ bln, float* __restrict__ pgw, float* __restrict__ pcv){
  int j = blockIdx.x*256 + threadIdx.x;
  int ic = blockIdx.y;
  if (j >= 600) return;
  float a = 0.f, c = 0.f;
  for (int i = ic*75; i < ic*75 + 75; ++i){
    float w = w1[i*600 + j];
    a += g[i]*w; c += bln[i]*w;
  }
  pgw[ic*600 + j] = a; pcv[ic*600 + j] = c;
}

__global__ __launch_bounds__(256)
void k_gw_reduce(const float* __restrict__ pgw, const float* __restrict__ pcv,
                 const float* __restrict__ b1, float* __restrict__ gw_g, float* __restrict__ c_g){
  int j = blockIdx.x*256 + threadIdx.x;
  if (j >= 600) return;
  float a = 0.f, c = 0.f;
  for (int k = 0; k < 8; ++k){ a += pgw[k*600 + j]; c += pcv[k*600 + j]; }
  gw_g[j] = a; c_g[j] = c + b1[j];
}

// ---------------- pack B^T: BT[n][k] = g[k]*w1[k*600+n], bf16 [640][320] ----------------
__global__ __launch_bounds__(256)
void k_pack_b(const float* __restrict__ w1, const float* __restrict__ g, ushort* __restrict__ BT){
  int id = blockIdx.x*256 + threadIdx.x;
  if (id >= 640*320) return;
  int n = id % 640, k = id / 640;
  float val = (k < 300 && n < 600) ? g[k]*w1[k*600 + n] : 0.f;
  BT[(size_t)n*320 + k] = f2bf(val);
}

// ---------------- P1: U = A @ B via MFMA 16x16x32 bf16, 128x128 tile ----------------
__global__ __launch_bounds__(256)
void k_ugemm_mfma(const ushort* __restrict__ A, const ushort* __restrict__ BT,
                  __hip_bfloat16* __restrict__ U){
  __shared__ ushort As[128][40];
  __shared__ ushort Bs[128][40];
  int tid = threadIdx.x;
  int bm = blockIdx.x * 128, bn = blockIdx.y * 128;
  int wid = tid >> 6, lane = tid & 63;
  int wr = wid >> 1, wc = wid & 1;
  int lr = lane & 15, lk = lane >> 4;
  f32x4 acc[4][4] = {};
  for (int k0 = 0; k0 < 320; k0 += 32){
    #pragma unroll
    for (int j = 0; j < 2; ++j){
      int idx = tid + 256*j;
      int row = idx >> 2, ko = (idx & 3)*8;
      *(bf16x8*)&As[row][ko] = *(const bf16x8*)&A[(size_t)(bm+row)*320 + k0 + ko];
      *(bf16x8*)&Bs[row][ko] = *(const bf16x8*)&BT[(size_t)(bn+row)*320 + k0 + ko];
    }
    __syncthreads();
    bf16x8 af[4], bfr[4];
    #pragma unroll
    for (int f = 0; f < 4; ++f){
      af[f]  = *(const bf16x8*)&As[wr*64 + f*16 + lr][lk*8];
      bfr[f] = *(const bf16x8*)&Bs[wc*64 + f*16 + lr][lk*8];
    }
    #pragma unroll
    for (int i = 0; i < 4; ++i)
      #pragma unroll
      for (int j = 0; j < 4; ++j)
        acc[i][j] = __builtin_amdgcn_mfma_f32_16x16x32_bf16(af[i], bfr[j], acc[i][j], 0, 0, 0);
    __syncthreads();
  }
  #pragma unroll
  for (int i = 0; i < 4; ++i){
    #pragma unroll
    for (int j = 0; j < 4; ++j){
      #pragma unroll
      for (int r = 0; r < 4; ++r){
        int row = bm + wr*64 + i*16 + lk*4 + r;
        int col = bn + wc*64 + j*16 + lr;
        if (row < 30000 && col < 600)
          U[(size_t)row*600 + col] = __float2bfloat16(acc[i][j][r]);
      }
    }
  }
}

// ---------------- ivar precompute: ivar = exp(-logvar), [30000*64] fp32 ----------------
__global__ __launch_bounds__(256)
void k_ivar(const float* __restrict__ logvar, float* __restrict__ ivar){
  int i = blockIdx.x*256 + threadIdx.x;
  if (i < 30000*64) ivar[i] = __expf(-logvar[i]);
}

// ---------------- K1: stage 1 ----------------
__global__ __launch_bounds__(512)
void k_encode_stage1(const int* __restrict__ ids_a, const void* __restrict__ mask_a,
                     const int* __restrict__ ids_b, const void* __restrict__ mask_b,
                     const float* __restrict__ mu_tab, const float* __restrict__ ivar_tab,
                     const float* __restrict__ alpha_tab, const float* __restrict__ feat_tab,
                     const float* __restrict__ log_tau, const float* __restrict__ pos_mu,
                     const float* __restrict__ pos_alpha,
                     const float* __restrict__ wq, const float* __restrict__ bq,
                     const float* __restrict__ wk, const float* __restrict__ bk,
                     ushort* __restrict__ MuS,
                     float* __restrict__ sgs_g,
                     float* __restrict__ ssum_g, float* __restrict__ ssq_g,
                     float* __restrict__ wgt_g)
{
  int bb = blockIdx.x;
  const int* ids = (bb < 128) ? ids_a : ids_b;
  const void* msk = (bb < 128) ? mask_a : mask_b;
  int b = bb & 127;
  int t = threadIdx.x;

  __shared__ int   ids_l[512];
  __shared__ float mf_l[512], al_l[512], w_l[512], red[512];
  __shared__ float cent[64], q_l[64], qk_l[64];
  __shared__ float sgs_l[304];
  __shared__ float gpart[32][64];
  __shared__ float pacc[8][304];
  __shared__ float bkq_s;
  __shared__ int mmode;

  if (t == 0) mmode = mask_mode((const unsigned char*)msk);
  __syncthreads();

  {
    int id = ids[b*512 + t];
    float mf = mask_read(msk, b*512 + t, mmode);
    ids_l[t] = id; mf_l[t] = mf;
    float pa = pos_alpha[t];
    al_l[t] = alpha_tab[id] * (1.f/(1.f + __expf(-pa))) * mf;
  }
  __syncthreads();
  float msum = blk_sum512(red, t, mf_l[t]);

  int grp = t >> 4, sub = t & 15;
  ushort* MuB = MuS + (size_t)bb*512*64;

  // phase 1: gather mu+pos once, stage bf16, centroid partials
  {
    float cp0=0.f, cp1=0.f, cp2=0.f, cp3=0.f;
    for (int k = 0; k < 16; ++k){
      int s = (grp << 4) | k;
      int id = ids_l[s];
      float4 m4 = *(const float4*)&mu_tab[(size_t)id*64 + sub*4];
      float4 p4 = *(const float4*)&pos_mu[s*64 + sub*4];
      float v0 = m4.x + p4.x, v1 = m4.y + p4.y, v2 = m4.z + p4.z, v3 = m4.w + p4.w;
      ushort4 st; st.x = f2bf(v0); st.y = f2bf(v1); st.z = f2bf(v2); st.w = f2bf(v3);
      *(ushort4*)&MuB[(size_t)s*64 + sub*4] = st;
      float mf = mf_l[s];
      cp0 += mf*v0; cp1 += mf*v1; cp2 += mf*v2; cp3 += mf*v3;
    }
    gpart[grp][sub*4+0] = cp0; gpart[grp][sub*4+1] = cp1;
    gpart[grp][sub*4+2] = cp2; gpart[grp][sub*4+3] = cp3;
  }
  __syncthreads();
  if (t < 64){
    float c = 0.f;
    for (int g = 0; g < 32; ++g) c += gpart[g][t];
    cent[t] = c / fmaxf(msum, 1.f);
  }
  __syncthreads();

  // phase 2: d2 -> w = alpha*K  (ivar table, no per-element exp)
  {
    float itau = __expf(-log_tau[0]);
    float c0 = cent[sub*4+0], c1 = cent[sub*4+1], c2 = cent[sub*4+2], c3 = cent[sub*4+3];
    for (int k = 0; k < 16; ++k){
      int s = (grp << 4) | k;
      int id = ids_l[s];
      float4 iv = *(const float4*)&ivar_tab[(size_t)id*64 + sub*4];
      ushort4 mu = *(const ushort4*)&MuB[(size_t)s*64 + sub*4];
      float d0 = bf2f(mu.x) - c0, d1 = bf2f(mu.y) - c1, d2v = bf2f(mu.z) - c2, d3 = bf2f(mu.w) - c3;
      float val = d0*d0*iv.x + d1*d1*iv.y + d2v*d2v*iv.z + d3*d3*iv.w;
      val += __shfl_xor(val, 1); val += __shfl_xor(val, 2);
      val += __shfl_xor(val, 4); val += __shfl_xor(val, 8);
      if (sub == 0){
        float K = __expf(-0.5f * val * itau) * mf_l[s];
        w_l[s] = al_l[s] * K;
      }
    }
  }
  __syncthreads();
  float wsum = blk_sum512(red, t, w_l[t]);

  // phase 3: sgs render — wave-per-token, fp32 float4 gathers
  {
    int wv = t >> 6, ln = t & 63;
    float a10=0.f,a11=0.f,a12=0.f,a13=0.f, a20=0.f,a21=0.f,a22=0.f,a23=0.f;
    for (int k = 0; k < 64; ++k){
      int s = (wv << 6) | k;
      float w = w_l[s];
      const float* fr = &feat_tab[(size_t)ids_l[s]*300];
      float4 v1 = *(const float4*)&fr[ln*4];
      a10 += w*v1.x; a11 += w*v1.y; a12 += w*v1.z; a13 += w*v1.w;
      if (ln < 11){
        float4 v2 = *(const float4*)&fr[256 + ln*4];
        a20 += w*v2.x; a21 += w*v2.y; a22 += w*v2.z; a23 += w*v2.w;
      }
    }
    pacc[wv][ln*4+0]=a10; pacc[wv][ln*4+1]=a11; pacc[wv][ln*4+2]=a12; pacc[wv][ln*4+3]=a13;
    if (ln < 11){
      pacc[wv][256+ln*4+0]=a20; pacc[wv][256+ln*4+1]=a21;
      pacc[wv][256+ln*4+2]=a22; pacc[wv][256+ln*4+3]=a23;
    }
  }
  __syncthreads();
  if (t < 300){
    float sacc = 0.f;
    #pragma unroll
    for (int w = 0; w < 8; ++w) sacc += pacc[w][t];
    float sv = sacc / fmaxf(wsum, 1e-8f);
    sgs_l[t] = sv;
    sgs_g[bb*300 + t] = sv;
  }
  __syncthreads();
  float ssum = blk_sum512(red, t, (t < 300) ? sgs_l[t] : 0.f);
  float ssq  = blk_sum512(red, t, (t < 300) ? sgs_l[t]*sgs_l[t] : 0.f);
  if (t == 0){ ssum_g[bb] = ssum; ssq_g[bb] = ssq; }

  // phase 4: query / qk / bkq
  if (t < 64){
    float q = bq[t];
    for (int i = 0; i < 300; ++i) q += sgs_l[i]*wq[i*64 + t];
    q_l[t] = q;
  }
  __syncthreads();
  if (t < 64){
    float a = 0.f;
    for (int j = 0; j < 64; ++j) a += wk[t*64 + j]*q_l[j];
    qk_l[t] = a;
  }
  if (t == 0){
    float s = 0.f;
    for (int j = 0; j < 64; ++j) s += bk[j]*q_l[j];
    bkq_s = s;
  }
  __syncthreads();

  // phase 5: scores from staged mu
  {
    float q0 = qk_l[sub*4+0], q1 = qk_l[sub*4+1], q2 = qk_l[sub*4+2], q3 = qk_l[sub*4+3];
    for (int k = 0; k < 16; ++k){
      int s = (grp << 4) | k;
      ushort4 mu = *(const ushort4*)&MuB[(size_t)s*64 + sub*4];
      float val = bf2f(mu.x)*q0 + bf2f(mu.y)*q1 + bf2f(mu.z)*q2 + bf2f(mu.w)*q3;
      val += __shfl_xor(val, 1); val += __shfl_xor(val, 2);
      val += __shfl_xor(val, 4); val += __shfl_xor(val, 8);
      if (sub == 0){
        float sv = (val + bkq_s) * 0.125f;
        w_l[s] = (mf_l[s] != 0.f) ? sv : -1e30f;
      }
    }
  }
  __syncthreads();

  // phase 6: softmax
  float mx = blk_max512(red, t, w_l[t]);
  float ex = __expf(w_l[t] - mx);
  float Z  = blk_sum512(red, t, ex);
  wgt_g[bb*512 + t] = ex / Z;
}

// ---------------- k_vgemm2: V[256][600] = sgs[256][300] @ (g*w1_bot)[300][600], tiled ----------------
__global__ __launch_bounds__(256)
void k_vgemm2(const float* __restrict__ sgs, const float* __restrict__ w1,
              const float* __restrict__ ln1g, float* __restrict__ V_g){
  __shared__ float As[32][33], Bs[32][33];
  int t = threadIdx.x;
  int bm = blockIdx.x*32, bn = blockIdx.y*32;
  int tx = t & 15, ty = t >> 4;
  float a00=0.f,a01=0.f,a10=0.f,a11=0.f;
  for (int k0 = 0; k0 < 300; k0 += 32){
    #pragma unroll
    for (int i = 0; i < 4; ++i){
      int idx = t + i*256;
      int kk = idx & 31, m = idx >> 5;
      int kg = k0 + kk;
      As[kk][m] = (kg < 300) ? sgs[(size_t)(bm+m)*300 + kg] : 0.f;
    }
    #pragma unroll
    for (int i = 0; i < 4; ++i){
      int idx = t + i*256;
      int n = idx & 31, kk = idx >> 5;
      int kg = k0 + kk, cg = bn + n;
      Bs[kk][n] = (kg < 300 && cg < 600) ? ln1g[300 + kg]*w1[(size_t)(300 + kg)*600 + cg] : 0.f;
    }
    __syncthreads();
    #pragma unroll
    for (int kk = 0; kk < 32; ++kk){
      float x0 = As[kk][ty*2], x1 = As[kk][ty*2+1];
      float y0 = Bs[kk][tx*2], y1 = Bs[kk][tx*2+1];
      a00 += x0*y0; a01 += x0*y1; a10 += x1*y0; a11 += x1*y1;
    }
    __syncthreads();
  }
  int r0 = bm + ty*2, c0 = bn + tx*2;
  #pragma unroll
  for (int i = 0; i < 2; ++i){
    #pragma unroll
    for (int j = 0; j < 2; ++j){
      int r = r0 + i, c = c0 + j;
      if (c < 600){
        float acc = (i==0 ? (j==0?a00:a01) : (j==0?a10:a11));
        V_g[(size_t)r*600 + c] = acc;
      }
    }
  }
}

// ---------------- K2: hbar + Fbar eighth-split (2048 blocks x 256 thr) ----------------
// partial outputs: hbar_p[8][256][608] (cols 600..607 zeroed), Fbar_p[8][256][300]
__global__ __launch_bounds__(256)
void k_hbar_fbar(const int* __restrict__ ids_a, const int* __restrict__ ids_b,
                 const __hip_bfloat16* __restrict__ U, const float* __restrict__ feat_tab,
                 const float* __restrict__ fsum, const float* __restrict__ fsq,
                 const float* __restrict__ ssum_g, const float* __restrict__ ssq_g,
                 const float* __restrict__ V_g, const float* __restrict__ gw_g,
                 const float* __restrict__ c_g, const float* __restrict__ wgt_g,
                 float* __restrict__ hbar_p, float* __restrict__ Fbar_p)
{
  int blk = blockIdx.x;            // bb*8 + eighth
  int bb = blk >> 3, qr = blk & 7;
  int b = bb & 127;
  const int* ids = (bb < 128) ? ids_a : ids_b;
  int t = threadIdx.x;
  __shared__ int id_l[64];
  __shared__ float m_l[64], rs_l[64], wg_l[64];
  __shared__ float hp[4][600];
  __shared__ float fp[4][304];
  float ss = ssum_g[bb], sq = ssq_g[bb];
  if (t < 64){
    int s = qr*64 + t;
    int id = ids[b*512 + s];
    id_l[t] = id;
    float m = (fsum[id] + ss) * (1.f/600.f);
    float var = (fsq[id] + sq) * (1.f/600.f) - m*m;
    m_l[t] = m;
    rs_l[t] = 1.f / sqrtf(var + 1e-5f);
    wg_l[t] = wgt_g[bb*512 + s];
  }
  __syncthreads();

  int wv = t >> 6, ln = t & 63;
  float Vp[8], gwp[8], cp[8], Vs[8], gws[8], cs[8];
  #pragma unroll
  for (int r = 0; r < 8; ++r){
    int j = ln*8 + r;
    Vp[r] = V_g[bb*600 + j]; gwp[r] = gw_g[j]; cp[r] = c_g[j];
    Vs[r] = 0.f; gws[r] = 0.f; cs[r] = 0.f;
  }
  if (ln < 11){
    #pragma unroll
    for (int r = 0; r < 8; ++r){
      int j = 512 + ln*8 + r;
      Vs[r] = V_g[bb*600 + j]; gws[r] = gw_g[j]; cs[r] = c_g[j];
    }
  }
  float h1[8] = {}, h2[8] = {};
  float f10=0.f,f11=0.f,f12=0.f,f13=0.f, f20=0.f,f21=0.f,f22=0.f,f23=0.f;

  for (int k = 0; k < 16; ++k){
    int s = (wv << 4) | k;           // token index within eighth (0..63)
    int id = id_l[s];
    float w = wg_l[s], m = m_l[s], rs = rs_l[s];
    const __hip_bfloat16* ur = &U[(size_t)id*600];
    const float* fr = &feat_tab[(size_t)id*300];
    bf16x8 u8 = *(const bf16x8*)&ur[ln*8];
    float4 fv = *(const float4*)&fr[ln*4];
    #pragma unroll
    for (int r = 0; r < 8; ++r){
      float u = bf2f((ushort)u8[r]);
      float a = (u + Vp[r] - m*gwp[r])*rs + cp[r];
      h1[r] += w*gelu_fast(a);
    }
    f10 += w*fv.x; f11 += w*fv.y; f12 += w*fv.z; f13 += w*fv.w;
    if (ln < 11){
      bf16x8 u8b = *(const bf16x8*)&ur[512 + ln*8];
      float4 fvb = *(const float4*)&fr[256 + ln*4];
      #pragma unroll
      for (int r = 0; r < 8; ++r){
        float u = bf2f((ushort)u8b[r]);
        float a = (u + Vs[r] - m*gws[r])*rs + cs[r];
        h2[r] += w*gelu_fast(a);
      }
      f20 += w*fvb.x; f21 += w*fvb.y; f22 += w*fvb.z; f23 += w*fvb.w;
    }
  }
  #pragma unroll
  for (int r = 0; r < 8; ++r) hp[wv][ln*8 + r] = h1[r];
  if (ln < 11){
    #pragma unroll
    for (int r = 0; r < 8; ++r) hp[wv][512 + ln*8 + r] = h2[r];
  }
  fp[wv][ln*4+0]=f10; fp[wv][ln*4+1]=f11; fp[wv][ln*4+2]=f12; fp[wv][ln*4+3]=f13;
  if (ln < 11){
    fp[wv][256+ln*4+0]=f20; fp[wv][256+ln*4+1]=f21;
    fp[wv][256+ln*4+2]=f22; fp[wv][256+ln*4+3]=f23;
  }
  __syncthreads();
  size_t hbase = ((size_t)qr*256 + bb)*608;
  for (int j = t; j < 600; j += 256){
    float s = hp[0][j] + hp[1][j] + hp[2][j] + hp[3][j];
    hbar_p[hbase + j] = s;
  }
  if (t < 8) hbar_p[hbase + 600 + t] = 0.f;
  size_t fbase = ((size_t)qr*256 + bb)*300;
  for (int j = t; j < 300; j += 256){
    float s = fp[0][j] + fp[1][j] + fp[2][j] + fp[3][j];
    Fbar_p[fbase + j] = s;
  }
}

// ============ final chain as small tiled fp32 GEMMs (32x32 tiles, 2x2/thread) ============

// GEMM1: att[256][300] = b2 + sum_q Fbar_p + (sum_q hbar_p) @ w2
__global__ __launch_bounds__(256)
void k_att(const float* __restrict__ hbar_p, const float* __restrict__ Fbar_p,
           const float* __restrict__ w2, const float* __restrict__ b2,
           float* __restrict__ att){
  __shared__ float As[32][33], Bs[32][33];
  int t = threadIdx.x;
  int bm = blockIdx.x*32, bn = blockIdx.y*32;
  int tx = t & 15, ty = t >> 4;
  const size_t Q = (size_t)256*608;
  float a00=0.f,a01=0.f,a10=0.f,a11=0.f;
  for (int k0 = 0; k0 < 608; k0 += 32){
    #pragma unroll
    for (int i = 0; i < 4; ++i){
      int idx = t + i*256;
      int kk = idx & 31, m = idx >> 5;
      size_t base = (size_t)(bm+m)*608 + k0 + kk;
      float s = 0.f;
      #pragma unroll
      for (int q = 0; q < 8; ++q) s += hbar_p[q*Q + base];
      As[kk][m] = s;
    }
    #pragma unroll
    for (int i = 0; i < 4; ++i){
      int idx = t + i*256;
      int n = idx & 31, kk = idx >> 5;
      int kg = k0 + kk, cg = bn + n;
      Bs[kk][n] = (kg < 600 && cg < 300) ? w2[(size_t)kg*300 + cg] : 0.f;
    }
    __syncthreads();
    #pragma unroll
    for (int kk = 0; kk < 32; ++kk){
      float x0 = As[kk][ty*2], x1 = As[kk][ty*2+1];
      float y0 = Bs[kk][tx*2], y1 = Bs[kk][tx*2+1];
      a00 += x0*y0; a01 += x0*y1; a10 += x1*y0; a11 += x1*y1;
    }
    __syncthreads();
  }
  const size_t QF = (size_t)256*300;
  int r0 = bm + ty*2, c0 = bn + tx*2;
  #pragma unroll
  for (int i = 0; i < 2; ++i){
    #pragma unroll
    for (int j = 0; j < 2; ++j){
      int r = r0 + i, c = c0 + j;
      if (c < 300){
        float acc = (i==0 ? (j==0?a00:a01) : (j==0?a10:a11));
        size_t fb = (size_t)r*300 + c;
        #pragma unroll
        for (int q = 0; q < 8; ++q) acc += Fbar_p[q*QF + fb];
        att[(size_t)r*300 + c] = acc + b2[c];
      }
    }
  }
}

// LN2 stats per row
__global__ __launch_bounds__(64)
void k_lnstats(const float* __restrict__ att, const float* __restrict__ ssum_g,
               const float* __restrict__ ssq_g, float* __restrict__ m_g, float* __restrict__ rs_g){
  int bb = blockIdx.x, lane = threadIdx.x;
  float s = 0.f, q = 0.f;
  for (int i = lane; i < 300; i += 64){
    float v = att[(size_t)bb*300 + i];
    s += v; q += v*v;
  }
  for (int o = 32; o > 0; o >>= 1){ s += __shfl_xor(s, o); q += __shfl_xor(q, o); }
  if (lane == 0){
    float m = (ssum_g[bb] + s) * (1.f/600.f);
    float var = (ssq_g[bb] + q) * (1.f/600.f) - m*m;
    m_g[bb] = m;
    rs_g[bb] = 1.f / sqrtf(var + 1e-5f);
  }
}

// GEMM2: g2[256][608] = gelu(LN2([sgs|att]) @ aw1[600][600] + ab1)
__global__ __launch_bounds__(256)
void k_mlp1(const float* __restrict__ sgs, const float* __restrict__ att,
            const float* __restrict__ m_g, const float* __restrict__ rs_g,
            const float* __restrict__ ln2g, const float* __restrict__ ln2b,
            const float* __restrict__ aw1, const float* __restrict__ ab1,
            float* __restrict__ g2){
  __shared__ float As[32][33], Bs[32][33];
  int t = threadIdx.x;
  int bm = blockIdx.x*32, bn = blockIdx.y*32;
  int tx = t & 15, ty = t >> 4;
  float a00=0.f,a01=0.f,a10=0.f,a11=0.f;
  for (int k0 = 0; k0 < 608; k0 += 32){
    #pragma unroll
    for (int i = 0; i < 4; ++i){
      int idx = t + i*256;
      int kk = idx & 31, m = idx >> 5;
      int kg = k0 + kk, row = bm + m;
      float t2 = 0.f;
      if (kg < 600){
        float x = (kg < 300) ? sgs[(size_t)row*300 + kg] : att[(size_t)row*300 + kg - 300];
        t2 = (x - m_g[row])*rs_g[row]*ln2g[kg] + ln2b[kg];
      }
      As[kk][m] = t2;
    }
    #pragma unroll
    for (int i = 0; i < 4; ++i){
      int idx = t + i*256;
      int n = idx & 31, kk = idx >> 5;
      int kg = k0 + kk, cg = bn + n;
      Bs[kk][n] = (kg < 600 && cg < 600) ? aw1[(size_t)kg*600 + cg] : 0.f;
    }
    __syncthreads();
    #pragma unroll
    for (int kk = 0; kk < 32; ++kk){
      float x0 = As[kk][ty*2], x1 = As[kk][ty*2+1];
      float y0 = Bs[kk][tx*2], y1 = Bs[kk][tx*2+1];
      a00 += x0*y0; a01 += x0*y1; a10 += x1*y0; a11 += x1*y1;
    }
    __syncthreads();
  }
  int r0 = bm + ty*2, c0 = bn + tx*2;
  #pragma unroll
  for (int i = 0; i < 2; ++i){
    #pragma unroll
    for (int j = 0; j < 2; ++j){
      int r = r0 + i, c = c0 + j;
      float acc = (i==0 ? (j==0?a00:a01) : (j==0?a10:a11));
      g2[(size_t)r*608 + c] = (c < 600) ? geluf(acc + ab1[c]) : 0.f;
    }
  }
}

// GEMM3: final[256][300] = sgs + ab2 + g2[256][608] @ aw2[600][300]
__global__ __launch_bounds__(256)
void k_mlp2(const float* __restrict__ g2, const float* __restrict__ sgs,
            const float* __restrict__ aw2, const float* __restrict__ ab2,
            float* __restrict__ final_g){
  __shared__ float As[32][33], Bs[32][33];
  int t = threadIdx.x;
  int bm = blockIdx.x*32, bn = blockIdx.y*32;
  int tx = t & 15, ty = t >> 4;
  float a00=0.f,a01=0.f,a10=0.f,a11=0.f;
  for (int k0 = 0; k0 < 608; k0 += 32){
    #pragma unroll
    for (int i = 0; i < 4; ++i){
      int idx = t + i*256;
      int kk = idx & 31, m = idx >> 5;
      As[kk][m] = g2[(size_t)(bm+m)*608 + k0 + kk];
    }
    #pragma unroll
    for (int i = 0; i < 4; ++i){
      int idx = t + i*256;
      int n = idx & 31, kk = idx >> 5;
      int kg = k0 + kk, cg = bn + n;
      Bs[kk][n] = (kg < 600 && cg < 300) ? aw2[(size_t)kg*300 + cg] : 0.f;
    }
    __syncthreads();
    #pragma unroll
    for (int kk = 0; kk < 32; ++kk){
      float x0 = As[kk][ty*2], x1 = As[kk][ty*2+1];
      float y0 = Bs[kk][tx*2], y1 = Bs[kk][tx*2+1];
      a00 += x0*y0; a01 += x0*y1; a10 += x1*y0; a11 += x1*y1;
    }
    __syncthreads();
  }
  int r0 = bm + ty*2, c0 = bn + tx*2;
  #pragma unroll
  for (int i = 0; i < 2; ++i){
    #pragma unroll
    for (int j = 0; j < 2; ++j){
      int r = r0 + i, c = c0 + j;
      if (c < 300){
        float acc = (i==0 ? (j==0?a00:a01) : (j==0?a10:a11));
        final_g[(size_t)r*300 + c] = acc + ab2[c] + sgs[(size_t)r*300 + c];
      }
    }
  }
}

// ---------------- K4: cosine ----------------
__global__ __launch_bounds__(64)
void k_cos(const float* __restrict__ final_g, float* __restrict__ out){
  int b = blockIdx.x; int lane = threadIdx.x;
  const float* A  = final_g + b*300;
  const float* Bv = final_g + (128 + b)*300;
  float dot = 0.f, na = 0.f, nb = 0.f;
  for (int i = lane; i < 300; i += 64){
    float x = A[i], y = Bv[i];
    dot += x*y; na += x*x; nb += y*y;
  }
  for (int o = 32; o > 0; o >>= 1){
    dot += __shfl_xor(dot, o); na += __shfl_xor(na, o); nb += __shfl_xor(nb, o);
  }
  if (lane == 0){
    float den = fmaxf(sqrtf(na), 1e-8f) * fmaxf(sqrtf(nb), 1e-8f);
    out[b] = 5.f * dot / den;
  }
}

extern "C" void kernel_launch(void* const* d_in, const int* in_sizes, int n_in,
                              void* d_out, int out_size, void* d_ws, size_t ws_size,
                              hipStream_t stream) {
  const int* ids_a = (const int*)d_in[0];
  const void* mask_a = d_in[1];
  const int* ids_b = (const int*)d_in[2];
  const void* mask_b = d_in[3];
  const float* mu_tab     = (const float*)d_in[4];
  const float* logvar_tab = (const float*)d_in[5];
  const float* alpha_tab  = (const float*)d_in[6];
  const float* feat_tab   = (const float*)d_in[7];
  const float* log_tau    = (const float*)d_in[8];
  const float* pos_mu     = (const float*)d_in[9];
  const float* pos_alpha  = (const float*)d_in[10];
  const float* ln1g = (const float*)d_in[11];
  const float* ln1b = (const float*)d_in[12];
  const float* w1   = (const float*)d_in[13];
  const float* b1   = (const float*)d_in[14];
  const float* w2   = (const float*)d_in[15];
  const float* b2   = (const float*)d_in[16];
  const float* wq   = (const float*)d_in[17];
  const float* bq   = (const float*)d_in[18];
  const float* wk   = (const float*)d_in[19];
  const float* bk   = (const float*)d_in[20];
  const float* ln2g = (const float*)d_in[21];
  const float* ln2b = (const float*)d_in[22];
  const float* aw1  = (const float*)d_in[23];
  const float* ab1  = (const float*)d_in[24];
  const float* aw2  = (const float*)d_in[25];
  const float* ab2  = (const float*)d_in[26];
  float* out = (float*)d_out;

  char* wsb = (char*)d_ws;
  size_t off = 0;
  auto take = [&](size_t bytes) -> void* {
    void* p = wsb + off;
    off += (bytes + 255) & ~(size_t)255;
    return p;
  };

  const size_t uBytes  = (size_t)30000 * 600 * 2;   // 36.0 MB
  const size_t aBytes  = (size_t)30080 * 320 * 2;   // 19.3 MB (ivar aliases after ugemm)
  const size_t btBytes = (size_t)640 * 320 * 2;     // 0.41 MB
  const size_t muBytes = (size_t)256 * 512 * 64 * 2;// 16.8 MB (aliased post-stage1)
  const size_t need = uBytes + aBytes + btBytes + muBytes + ((size_t)4 << 20);
  if (ws_size < need) return;

  __hip_bfloat16* U = (__hip_bfloat16*)take(uBytes);
  char* abfRegion = (char*)take(aBytes);
  ushort* Abf = (ushort*)abfRegion;
  float* ivar_tab = (float*)abfRegion;               // 30000*64*4 = 7.68 MB, alias (dead Abf)
  ushort* BTbf = (ushort*)take(btBytes);
  char* muRegion = (char*)take(muBytes);
  ushort* MuS = (ushort*)muRegion;
  // alias post-stage1 buffers onto the (dead-after-stage1) MuS region:
  float* hbar_p = (float*)(muRegion + 0);                 // 8*256*608*4 = 4,980,736
  float* Fbar_p = (float*)(muRegion + 4980736);           // 8*256*300*4 = 2,457,600
  float* att_g  = (float*)(muRegion + 4980736 + 2457600); // 256*300*4   = 307,200
  float* g2_g   = (float*)(muRegion + 7745536);           // 256*608*4   = 622,592
  float* final_g= (float*)(muRegion + 8368128);           // 256*300*4   = 307,200

  float* fsum   = (float*)take(30000*4);
  float* fsq    = (float*)take(30000*4);
  float* pgw    = (float*)take(8*600*4);
  float* pcv    = (float*)take(8*600*4);
  float* gw_g   = (float*)take(600*4);
  float* c_g    = (float*)take(600*4);
  float* sgs_g  = (float*)take(256*300*4);
  float* ssum_g = (float*)take(256*4);
  float* ssq_g  = (float*)take(256*4);
  float* V_g    = (float*)take(256*600*4);
  float* wgt_g  = (float*)take(256*512*4);
  float* m_g    = (float*)take(256*4);
  float* rs_g   = (float*)take(256*4);

  k_pack_stats<<<7520, 256, 0, stream>>>(feat_tab, Abf, fsum, fsq);
  k_pack_b<<<(640*320 + 255)/256, 256, 0, stream>>>(w1, ln1g, BTbf);
  k_gw1_part<<<dim3(3, 8), 256, 0, stream>>>(w1, ln1g, ln1b, pgw, pcv);
  k_gw_reduce<<<3, 256, 0, stream>>>(pgw, pcv, b1, gw_g, c_g);
  k_ugemm_mfma<<<dim3(235, 5), 256, 0, stream>>>(Abf, BTbf, U);
  k_ivar<<<7500, 256, 0, stream>>>(logvar_tab, ivar_tab);   // after ugemm: reuses Abf region
  k_encode_stage1<<<256, 512, 0, stream>>>(ids_a, mask_a, ids_b, mask_b,
                                           mu_tab, ivar_tab, alpha_tab, feat_tab,
                                           log_tau, pos_mu, pos_alpha,
                                           wq, bq, wk, bk,
                                           MuS, sgs_g, ssum_g, ssq_g, wgt_g);
  k_vgemm2<<<dim3(8, 19), 256, 0, stream>>>(sgs_g, w1, ln1g, V_g);
  k_hbar_fbar<<<2048, 256, 0, stream>>>(ids_a, ids_b, U, feat_tab, fsum, fsq,
                                        ssum_g, ssq_g, V_g, gw_g, c_g, wgt_g,
                                        hbar_p, Fbar_p);
  k_att<<<dim3(8, 10), 256, 0, stream>>>(hbar_p, Fbar_p, w2, b2, att_g);
  k_lnstats<<<256, 64, 0, stream>>>(att_g, ssum_g, ssq_g, m_g, rs_g);
  k_mlp1<<<dim3(8, 19), 256, 0, stream>>>(sgs_g, att_g, m_g, rs_g, ln2g, ln2b, aw1, ab1, g2_g);
  k_mlp2<<<dim3(8, 10), 256, 0, stream>>>(g2_g, sgs_g, aw2, ab2, final_g);
  k_cos<<<128, 64, 0, stream>>>(final_g, out);
}

// Round 9
// 381.650 us; speedup vs baseline: 1.3164x; 1.0819x over previous
//
#include <hip/hip_runtime.h>
#include <hip/hip_bf16.h>
#include <cstdint>
#include <cstddef>

#define DEV __device__ __forceinline__

// problem constants: B=128, S=512, V=30000, DS=64, DF=300, H=600, BB=256

typedef __attribute__((ext_vector_type(8))) short bf16x8;
typedef __attribute__((ext_vector_type(4))) float f32x4;

DEV float geluf(float x){ return 0.5f*x*(1.f + erff(x*0.7071067811865475f)); }
// tanh-form gelu, log2e folded: x * sigmoid(1.5958(x+0.0447x^3))
//  = x * rcp(1 + exp2(x*(c1 + c2*x^2))),  c1=-1.5957691*log2e, c2=c1*0.044715
DEV float gelu_fast(float x){
  float x2 = x*x;
  float e = __builtin_amdgcn_exp2f(x * __builtin_fmaf(x2, -0.102953f, -2.302218f));
  return x * __builtin_amdgcn_rcpf(1.f + e);
}

DEV float blk_sum512(float* red, int t, float v){
  red[t] = v; __syncthreads();
  for (int o = 256; o > 0; o >>= 1){ if (t < o) red[t] += red[t+o]; __syncthreads(); }
  float r = red[0]; __syncthreads(); return r;
}
DEV float blk_max512(float* red, int t, float v){
  red[t] = v; __syncthreads();
  for (int o = 256; o > 0; o >>= 1){ if (t < o) red[t] = fmaxf(red[t], red[t+o]); __syncthreads(); }
  float r = red[0]; __syncthreads(); return r;
}
DEV float blk_sum256(float* red, int t, float v){
  red[t] = v; __syncthreads();
  for (int o = 128; o > 0; o >>= 1){ if (t < o) red[t] += red[t+o]; __syncthreads(); }
  float r = red[0]; __syncthreads(); return r;
}

DEV ushort f2bf(float v){ __hip_bfloat16 h = __float2bfloat16(v); return *(ushort*)&h; }
DEV float bf2f(ushort u){ __hip_bfloat16 h; *(ushort*)&h = u; return __bfloat162float(h); }

// ---- mask dtype classifier (bool may arrive as u8 / int32 / bf16) ----
DEV int mask_mode(const unsigned char* m){
  bool big = false, off123 = false, off0one = false;
  #pragma unroll
  for (int i = 0; i < 16; ++i){
    unsigned char c = m[i];
    if (c > 1) big = true;
    if ((i & 3) != 0 && c != 0) off123 = true;
    if ((i & 3) == 0 && c == 1) off0one = true;
  }
  if (big) return 2;
  if (!off123 && off0one) return 1;
  return 0;
}
DEV float mask_read(const void* m, int idx, int mode){
  if (mode == 1) return ((const int*)m)[idx] ? 1.f : 0.f;
  if (mode == 2) return ((const unsigned short*)m)[idx] ? 1.f : 0.f;
  return ((const unsigned char*)m)[idx] ? 1.f : 0.f;
}

// ---------------- fused: pack A (bf16 [30080][320]) + per-vocab stats ----------------
__global__ __launch_bounds__(256)
void k_pack_stats(const float* __restrict__ feat, ushort* __restrict__ A,
                  float* __restrict__ fsum, float* __restrict__ fsq){
  int v = blockIdx.x*4 + (threadIdx.x >> 6);
  int ln = threadIdx.x & 63;
  if (v >= 30080) return;
  float vals[8] = {0.f,0.f,0.f,0.f,0.f,0.f,0.f,0.f};
  if (v < 30000 && ln < 38){
    const float* fr = &feat[(size_t)v*300];
    if (ln < 37){
      float4 a = *(const float4*)&fr[ln*8];
      float4 b = *(const float4*)&fr[ln*8 + 4];
      vals[0]=a.x; vals[1]=a.y; vals[2]=a.z; vals[3]=a.w;
      vals[4]=b.x; vals[5]=b.y; vals[6]=b.z; vals[7]=b.w;
    } else {
      float4 a = *(const float4*)&fr[296];
      vals[0]=a.x; vals[1]=a.y; vals[2]=a.z; vals[3]=a.w;
    }
  }
  if (ln < 40){
    union { ushort u[8]; bf16x8 v8; } pk;
    #pragma unroll
    for (int i = 0; i < 8; ++i) pk.u[i] = f2bf(vals[i]);
    *(bf16x8*)&A[(size_t)v*320 + ln*8] = pk.v8;
  }
  float s = 0.f, q = 0.f;
  #pragma unroll
  for (int i = 0; i < 8; ++i){ s += vals[i]; q += vals[i]*vals[i]; }
  for (int o = 32; o > 0; o >>= 1){ s += __shfl_xor(s, o); q += __shfl_xor(q, o); }
  if (ln == 0 && v < 30000){ fsum[v] = s; fsq[v] = q; }
}

// ---------------- P0b: gw1/cv partials ----------------
__global__ __launch_bounds__(256)
void k_gw1_part(const float* __restrict__ w1, const float* __restrict__ g,
                const float* __restrict__ bln, float* __restrict__ pgw, float* __restrict__ pcv){
  int j = blockIdx.x*256 + threadIdx.x;
  int ic = blockIdx.y;
  if (j >= 600) return;
  float a = 0.f, c = 0.f;
  for (int i = ic*75; i < ic*75 + 75; ++i){
    float w = w1[i*600 + j];
    a += g[i]*w; c += bln[i]*w;
  }
  pgw[ic*600 + j] = a; pcv[ic*600 + j] = c;
}

__global__ __launch_bounds__(256)
void k_gw_reduce(const float* __restrict__ pgw, const float* __restrict__ pcv,
                 const float* __restrict__ b1, float* __restrict__ gw_g, float* __restrict__ c_g){
  int j = blockIdx.x*256 + threadIdx.x;
  if (j >= 600) return;
  float a = 0.f, c = 0.f;
  for (int k = 0; k < 8; ++k){ a += pgw[k*600 + j]; c += pcv[k*600 + j]; }
  gw_g[j] = a; c_g[j] = c + b1[j];
}

// ---------------- pack B^T: BT[n][k] = g[k]*w1[k*600+n], bf16 [640][320] ----------------
__global__ __launch_bounds__(256)
void k_pack_b(const float* __restrict__ w1, const float* __restrict__ g, ushort* __restrict__ BT){
  int id = blockIdx.x*256 + threadIdx.x;
  if (id >= 640*320) return;
  int n = id % 640, k = id / 640;
  float val = (k < 300 && n < 600) ? g[k]*w1[k*600 + n] : 0.f;
  BT[(size_t)n*320 + k] = f2bf(val);
}

// ---------------- P1: U = A @ B via MFMA 16x16x32 bf16, 128x128 tile ----------------
__global__ __launch_bounds__(256)
void k_ugemm_mfma(const ushort* __restrict__ A, const ushort* __restrict__ BT,
                  __hip_bfloat16* __restrict__ U){
  __shared__ ushort As[128][40];
  __shared__ ushort Bs[128][40];
  int tid = threadIdx.x;
  int bm = blockIdx.x * 128, bn = blockIdx.y * 128;
  int wid = tid >> 6, lane = tid & 63;
  int wr = wid >> 1, wc = wid & 1;
  int lr = lane & 15, lk = lane >> 4;
  f32x4 acc[4][4] = {};
  for (int k0 = 0; k0 < 320; k0 += 32){
    #pragma unroll
    for (int j = 0; j < 2; ++j){
      int idx = tid + 256*j;
      int row = idx >> 2, ko = (idx & 3)*8;
      *(bf16x8*)&As[row][ko] = *(const bf16x8*)&A[(size_t)(bm+row)*320 + k0 + ko];
      *(bf16x8*)&Bs[row][ko] = *(const bf16x8*)&BT[(size_t)(bn+row)*320 + k0 + ko];
    }
    __syncthreads();
    bf16x8 af[4], bfr[4];
    #pragma unroll
    for (int f = 0; f < 4; ++f){
      af[f]  = *(const bf16x8*)&As[wr*64 + f*16 + lr][lk*8];
      bfr[f] = *(const bf16x8*)&Bs[wc*64 + f*16 + lr][lk*8];
    }
    #pragma unroll
    for (int i = 0; i < 4; ++i)
      #pragma unroll
      for (int j = 0; j < 4; ++j)
        acc[i][j] = __builtin_amdgcn_mfma_f32_16x16x32_bf16(af[i], bfr[j], acc[i][j], 0, 0, 0);
    __syncthreads();
  }
  #pragma unroll
  for (int i = 0; i < 4; ++i){
    #pragma unroll
    for (int j = 0; j < 4; ++j){
      #pragma unroll
      for (int r = 0; r < 4; ++r){
        int row = bm + wr*64 + i*16 + lk*4 + r;
        int col = bn + wc*64 + j*16 + lr;
        if (row < 30000 && col < 600)
          U[(size_t)row*600 + col] = __float2bfloat16(acc[i][j][r]);
      }
    }
  }
}

// ---------------- ivar precompute: ivar = exp(-logvar) ----------------
__global__ __launch_bounds__(256)
void k_ivar(const float* __restrict__ logvar, float* __restrict__ ivar){
  int i = blockIdx.x*256 + threadIdx.x;
  if (i < 30000*64) ivar[i] = __builtin_amdgcn_exp2f(-1.44269504f*logvar[i]);
}

// ---------------- S1a: mu gather+stage (8-way split), centroid partials, alpha ----------------
__global__ __launch_bounds__(256)
void k_mu_stage(const int* __restrict__ ids_a, const void* __restrict__ mask_a,
                const int* __restrict__ ids_b, const void* __restrict__ mask_b,
                const float* __restrict__ mu_tab, const float* __restrict__ pos_mu,
                const float* __restrict__ alpha_tab, const float* __restrict__ pos_alpha,
                ushort* __restrict__ MuS, float* __restrict__ cent_p,
                float* __restrict__ msum_p, float* __restrict__ al_g){
  int blk = blockIdx.x;                 // bb*8 + qr
  int bb = blk >> 3, qr = blk & 7;
  int b = bb & 127;
  const int* ids = (bb < 128) ? ids_a : ids_b;
  const void* msk = (bb < 128) ? mask_a : mask_b;
  int t = threadIdx.x;
  int grp = t >> 4, sub = t & 15;       // 16 groups x 16 lanes
  __shared__ int mmode_s;
  __shared__ float gpart[16][64];
  __shared__ float mf_s[64];
  __shared__ float red[256];
  if (t == 0) mmode_s = mask_mode((const unsigned char*)msk);
  __syncthreads();
  int mmode = mmode_s;
  float cp0=0.f, cp1=0.f, cp2=0.f, cp3=0.f;
  #pragma unroll
  for (int k = 0; k < 4; ++k){
    int sl = grp*4 + k;                 // 0..63
    int s  = qr*64 + sl;                // 0..511
    int id = ids[b*512 + s];
    float mf = mask_read(msk, b*512 + s, mmode);
    float4 m4 = *(const float4*)&mu_tab[(size_t)id*64 + sub*4];
    float4 p4 = *(const float4*)&pos_mu[s*64 + sub*4];
    float v0 = m4.x+p4.x, v1 = m4.y+p4.y, v2 = m4.z+p4.z, v3 = m4.w+p4.w;
    ushort4 st; st.x = f2bf(v0); st.y = f2bf(v1); st.z = f2bf(v2); st.w = f2bf(v3);
    *(ushort4*)&MuS[((size_t)bb*512 + s)*64 + sub*4] = st;
    cp0 += mf*v0; cp1 += mf*v1; cp2 += mf*v2; cp3 += mf*v3;
    if (sub == 0){
      mf_s[sl] = mf;
      float pa = pos_alpha[s];
      float sg = __builtin_amdgcn_rcpf(1.f + __builtin_amdgcn_exp2f(-1.44269504f*pa));
      al_g[bb*512 + s] = alpha_tab[id] * sg * mf;
    }
  }
  gpart[grp][sub*4+0] = cp0; gpart[grp][sub*4+1] = cp1;
  gpart[grp][sub*4+2] = cp2; gpart[grp][sub*4+3] = cp3;
  __syncthreads();
  if (t < 64){
    float c = 0.f;
    #pragma unroll
    for (int g = 0; g < 16; ++g) c += gpart[g][t];
    cent_p[(size_t)blk*64 + t] = c;
  }
  float ms = blk_sum256(red, t, (t < 64) ? mf_s[t] : 0.f);
  if (t == 0) msum_p[blk] = ms;
}

// ---------------- S1b: centroid reduce ----------------
__global__ __launch_bounds__(64)
void k_cent_reduce(const float* __restrict__ cent_p, const float* __restrict__ msum_p,
                   float* __restrict__ cent){
  int bb = blockIdx.x, d = threadIdx.x;
  float c = 0.f, ms = 0.f;
  #pragma unroll
  for (int q = 0; q < 8; ++q){
    c  += cent_p[(size_t)(bb*8+q)*64 + d];
    ms += msum_p[bb*8+q];
  }
  cent[bb*64 + d] = c / fmaxf(ms, 1.f);
}

// ---------------- S1c: w = alpha*K (d2 from staged mu + ivar), render partials ----------------
__global__ __launch_bounds__(256)
void k_wrender(const int* __restrict__ ids_a, const int* __restrict__ ids_b,
               const float* __restrict__ ivar_tab, const ushort* __restrict__ MuS,
               const float* __restrict__ cent, const float* __restrict__ al_g,
               const float* __restrict__ log_tau, const float* __restrict__ feat_tab,
               float* __restrict__ wsum_p, float* __restrict__ sgs_p){
  int blk = blockIdx.x;                 // bb*8 + qr
  int bb = blk >> 3, qr = blk & 7;
  int b = bb & 127;
  const int* ids = (bb < 128) ? ids_a : ids_b;
  int t = threadIdx.x;
  int grp = t >> 4, sub = t & 15;
  __shared__ float wl[64];
  __shared__ int   idl[64];
  __shared__ float pacc[4][304];
  __shared__ float red[256];
  float itau = __builtin_amdgcn_exp2f(-1.44269504f*log_tau[0]);
  float c0 = cent[bb*64 + sub*4+0], c1 = cent[bb*64 + sub*4+1];
  float c2 = cent[bb*64 + sub*4+2], c3 = cent[bb*64 + sub*4+3];
  #pragma unroll
  for (int k = 0; k < 4; ++k){
    int sl = grp*4 + k, s = qr*64 + sl;
    int id = ids[b*512 + s];
    float4 iv = *(const float4*)&ivar_tab[(size_t)id*64 + sub*4];
    ushort4 mu = *(const ushort4*)&MuS[((size_t)bb*512 + s)*64 + sub*4];
    float d0 = bf2f(mu.x)-c0, d1 = bf2f(mu.y)-c1, d2v = bf2f(mu.z)-c2, d3 = bf2f(mu.w)-c3;
    float val = d0*d0*iv.x + d1*d1*iv.y + d2v*d2v*iv.z + d3*d3*iv.w;
    val += __shfl_xor(val, 1); val += __shfl_xor(val, 2);
    val += __shfl_xor(val, 4); val += __shfl_xor(val, 8);
    if (sub == 0){
      idl[sl] = id;
      float K = __builtin_amdgcn_exp2f(-0.72134752f * val * itau);  // exp(-0.5*val*itau)
      wl[sl] = al_g[bb*512 + s] * K;
    }
  }
  __syncthreads();
  float ws = blk_sum256(red, t, (t < 64) ? wl[t] : 0.f);
  if (t == 0) wsum_p[blk] = ws;
  // render partials: wave-per-token
  int wv = t >> 6, ln = t & 63;
  float a10=0.f,a11=0.f,a12=0.f,a13=0.f, a20=0.f,a21=0.f,a22=0.f,a23=0.f;
  for (int k = 0; k < 16; ++k){
    int sl = (wv << 4) | k;
    float w = wl[sl];
    const float* fr = &feat_tab[(size_t)idl[sl]*300];
    float4 v1 = *(const float4*)&fr[ln*4];
    a10 += w*v1.x; a11 += w*v1.y; a12 += w*v1.z; a13 += w*v1.w;
    if (ln < 11){
      float4 v2 = *(const float4*)&fr[256 + ln*4];
      a20 += w*v2.x; a21 += w*v2.y; a22 += w*v2.z; a23 += w*v2.w;
    }
  }
  pacc[wv][ln*4+0]=a10; pacc[wv][ln*4+1]=a11; pacc[wv][ln*4+2]=a12; pacc[wv][ln*4+3]=a13;
  if (ln < 11){
    pacc[wv][256+ln*4+0]=a20; pacc[wv][256+ln*4+1]=a21;
    pacc[wv][256+ln*4+2]=a22; pacc[wv][256+ln*4+3]=a23;
  }
  __syncthreads();
  for (int j = t; j < 300; j += 256)
    sgs_p[(size_t)blk*304 + j] = pacc[0][j] + pacc[1][j] + pacc[2][j] + pacc[3][j];
}

// ---------------- S1d: sgs reduce, query, scores, softmax ----------------
__global__ __launch_bounds__(512)
void k_stage1c(const int* __restrict__ ids_a, const void* __restrict__ mask_a,
               const int* __restrict__ ids_b, const void* __restrict__ mask_b,
               const ushort* __restrict__ MuS, const float* __restrict__ sgs_p,
               const float* __restrict__ wsum_p,
               const float* __restrict__ wq, const float* __restrict__ bq,
               const float* __restrict__ wk, const float* __restrict__ bk,
               float* __restrict__ sgs_g, float* __restrict__ ssum_g, float* __restrict__ ssq_g,
               float* __restrict__ wgt_g)
{
  int bb = blockIdx.x;
  const int* ids = (bb < 128) ? ids_a : ids_b;   // (ids unused; masks needed)
  const void* msk = (bb < 128) ? mask_a : mask_b;
  int b = bb & 127;
  int t = threadIdx.x;
  __shared__ float mf_l[512], w_l[512], red[512];
  __shared__ float q_l[64], qk_l[64];
  __shared__ float sgs_l[304];
  __shared__ float bkq_s;
  __shared__ int mmode;
  (void)ids;
  if (t == 0) mmode = mask_mode((const unsigned char*)msk);
  __syncthreads();
  mf_l[t] = mask_read(msk, b*512 + t, mmode);

  float wsum = 0.f;
  #pragma unroll
  for (int q = 0; q < 8; ++q) wsum += wsum_p[bb*8 + q];
  wsum = fmaxf(wsum, 1e-8f);
  if (t < 300){
    float sa = 0.f;
    #pragma unroll
    for (int q = 0; q < 8; ++q) sa += sgs_p[(size_t)(bb*8+q)*304 + t];
    float sv = sa / wsum;
    sgs_l[t] = sv;
    sgs_g[bb*300 + t] = sv;
  }
  __syncthreads();
  float ssum = blk_sum512(red, t, (t < 300) ? sgs_l[t] : 0.f);
  float ssq  = blk_sum512(red, t, (t < 300) ? sgs_l[t]*sgs_l[t] : 0.f);
  if (t == 0){ ssum_g[bb] = ssum; ssq_g[bb] = ssq; }

  if (t < 64){
    float q = bq[t];
    for (int i = 0; i < 300; ++i) q += sgs_l[i]*wq[i*64 + t];
    q_l[t] = q;
  }
  __syncthreads();
  if (t < 64){
    float a = 0.f;
    for (int j = 0; j < 64; ++j) a += wk[t*64 + j]*q_l[j];
    qk_l[t] = a;
  }
  if (t == 0){
    float s = 0.f;
    for (int j = 0; j < 64; ++j) s += bk[j]*q_l[j];
    bkq_s = s;
  }
  __syncthreads();

  int grp = t >> 4, sub = t & 15;
  {
    float q0 = qk_l[sub*4+0], q1 = qk_l[sub*4+1], q2 = qk_l[sub*4+2], q3 = qk_l[sub*4+3];
    for (int k = 0; k < 16; ++k){
      int s = (grp << 4) | k;
      ushort4 mu = *(const ushort4*)&MuS[((size_t)bb*512 + s)*64 + sub*4];
      float val = bf2f(mu.x)*q0 + bf2f(mu.y)*q1 + bf2f(mu.z)*q2 + bf2f(mu.w)*q3;
      val += __shfl_xor(val, 1); val += __shfl_xor(val, 2);
      val += __shfl_xor(val, 4); val += __shfl_xor(val, 8);
      if (sub == 0){
        float sv = (val + bkq_s) * 0.125f;
        w_l[s] = (mf_l[s] != 0.f) ? sv : -1e30f;
      }
    }
  }
  __syncthreads();

  float mx = blk_max512(red, t, w_l[t]);
  float ex = __expf(w_l[t] - mx);
  float Z  = blk_sum512(red, t, ex);
  wgt_g[bb*512 + t] = ex / Z;
}

// ---------------- k_vgemm2: V[256][600] tiled ----------------
__global__ __launch_bounds__(256)
void k_vgemm2(const float* __restrict__ sgs, const float* __restrict__ w1,
              const float* __restrict__ ln1g, float* __restrict__ V_g){
  __shared__ float As[32][33], Bs[32][33];
  int t = threadIdx.x;
  int bm = blockIdx.x*32, bn = blockIdx.y*32;
  int tx = t & 15, ty = t >> 4;
  float a00=0.f,a01=0.f,a10=0.f,a11=0.f;
  for (int k0 = 0; k0 < 300; k0 += 32){
    #pragma unroll
    for (int i = 0; i < 4; ++i){
      int idx = t + i*256;
      int kk = idx & 31, m = idx >> 5;
      int kg = k0 + kk;
      As[kk][m] = (kg < 300) ? sgs[(size_t)(bm+m)*300 + kg] : 0.f;
    }
    #pragma unroll
    for (int i = 0; i < 4; ++i){
      int idx = t + i*256;
      int n = idx & 31, kk = idx >> 5;
      int kg = k0 + kk, cg = bn + n;
      Bs[kk][n] = (kg < 300 && cg < 600) ? ln1g[300 + kg]*w1[(size_t)(300 + kg)*600 + cg] : 0.f;
    }
    __syncthreads();
    #pragma unroll
    for (int kk = 0; kk < 32; ++kk){
      float x0 = As[kk][ty*2], x1 = As[kk][ty*2+1];
      float y0 = Bs[kk][tx*2], y1 = Bs[kk][tx*2+1];
      a00 += x0*y0; a01 += x0*y1; a10 += x1*y0; a11 += x1*y1;
    }
    __syncthreads();
  }
  int r0 = bm + ty*2, c0 = bn + tx*2;
  #pragma unroll
  for (int i = 0; i < 2; ++i){
    #pragma unroll
    for (int j = 0; j < 2; ++j){
      int r = r0 + i, c = c0 + j;
      if (c < 600) V_g[(size_t)r*600 + c] = (i==0 ? (j==0?a00:a01) : (j==0?a10:a11));
    }
  }
}

// ---------------- K2: hbar + Fbar eighth-split (2048 blocks x 256 thr) ----------------
__global__ __launch_bounds__(256)
void k_hbar_fbar(const int* __restrict__ ids_a, const int* __restrict__ ids_b,
                 const __hip_bfloat16* __restrict__ U, const float* __restrict__ feat_tab,
                 const float* __restrict__ fsum, const float* __restrict__ fsq,
                 const float* __restrict__ ssum_g, const float* __restrict__ ssq_g,
                 const float* __restrict__ V_g, const float* __restrict__ gw_g,
                 const float* __restrict__ c_g, const float* __restrict__ wgt_g,
                 float* __restrict__ hbar_p, float* __restrict__ Fbar_p)
{
  int blk = blockIdx.x;            // bb*8 + eighth
  int bb = blk >> 3, qr = blk & 7;
  int b = bb & 127;
  const int* ids = (bb < 128) ? ids_a : ids_b;
  int t = threadIdx.x;
  __shared__ int id_l[64];
  __shared__ float m_l[64], rs_l[64], wg_l[64];
  __shared__ float hp[4][600];
  __shared__ float fp[4][304];
  float ss = ssum_g[bb], sq = ssq_g[bb];
  if (t < 64){
    int s = qr*64 + t;
    int id = ids[b*512 + s];
    id_l[t] = id;
    float m = (fsum[id] + ss) * (1.f/600.f);
    float var = (fsq[id] + sq) * (1.f/600.f) - m*m;
    m_l[t] = m;
    rs_l[t] = 1.f / sqrtf(var + 1e-5f);
    wg_l[t] = wgt_g[bb*512 + s];
  }
  __syncthreads();

  int wv = t >> 6, ln = t & 63;
  float Vp[8], gwp[8], cp[8], Vs[8], gws[8], cs[8];
  #pragma unroll
  for (int r = 0; r < 8; ++r){
    int j = ln*8 + r;
    Vp[r] = V_g[bb*600 + j]; gwp[r] = gw_g[j]; cp[r] = c_g[j];
    Vs[r] = 0.f; gws[r] = 0.f; cs[r] = 0.f;
  }
  if (ln < 11){
    #pragma unroll
    for (int r = 0; r < 8; ++r){
      int j = 512 + ln*8 + r;
      Vs[r] = V_g[bb*600 + j]; gws[r] = gw_g[j]; cs[r] = c_g[j];
    }
  }
  float h1[8] = {}, h2[8] = {};
  float f10=0.f,f11=0.f,f12=0.f,f13=0.f, f20=0.f,f21=0.f,f22=0.f,f23=0.f;

  for (int k = 0; k < 16; ++k){
    int s = (wv << 4) | k;
    int id = id_l[s];
    float w = wg_l[s], m = m_l[s], rs = rs_l[s];
    const __hip_bfloat16* ur = &U[(size_t)id*600];
    const float* fr = &feat_tab[(size_t)id*300];
    bf16x8 u8 = *(const bf16x8*)&ur[ln*8];
    float4 fv = *(const float4*)&fr[ln*4];
    #pragma unroll
    for (int r = 0; r < 8; ++r){
      float u = bf2f((ushort)u8[r]);
      float a = (u + Vp[r] - m*gwp[r])*rs + cp[r];
      h1[r] += w*gelu_fast(a);
    }
    f10 += w*fv.x; f11 += w*fv.y; f12 += w*fv.z; f13 += w*fv.w;
    if (ln < 11){
      bf16x8 u8b = *(const bf16x8*)&ur[512 + ln*8];
      float4 fvb = *(const float4*)&fr[256 + ln*4];
      #pragma unroll
      for (int r = 0; r < 8; ++r){
        float u = bf2f((ushort)u8b[r]);
        float a = (u + Vs[r] - m*gws[r])*rs + cs[r];
        h2[r] += w*gelu_fast(a);
      }
      f20 += w*fvb.x; f21 += w*fvb.y; f22 += w*fvb.z; f23 += w*fvb.w;
    }
  }
  #pragma unroll
  for (int r = 0; r < 8; ++r) hp[wv][ln*8 + r] = h1[r];
  if (ln < 11){
    #pragma unroll
    for (int r = 0; r < 8; ++r) hp[wv][512 + ln*8 + r] = h2[r];
  }
  fp[wv][ln*4+0]=f10; fp[wv][ln*4+1]=f11; fp[wv][ln*4+2]=f12; fp[wv][ln*4+3]=f13;
  if (ln < 11){
    fp[wv][256+ln*4+0]=f20; fp[wv][256+ln*4+1]=f21;
    fp[wv][256+ln*4+2]=f22; fp[wv][256+ln*4+3]=f23;
  }
  __syncthreads();
  size_t hbase = ((size_t)qr*256 + bb)*608;
  for (int j = t; j < 600; j += 256){
    hbar_p[hbase + j] = hp[0][j] + hp[1][j] + hp[2][j] + hp[3][j];
  }
  if (t < 8) hbar_p[hbase + 600 + t] = 0.f;
  size_t fbase = ((size_t)qr*256 + bb)*300;
  for (int j = t; j < 300; j += 256){
    Fbar_p[fbase + j] = fp[0][j] + fp[1][j] + fp[2][j] + fp[3][j];
  }
}

// ============ final chain: small tiled fp32 GEMMs ============

__global__ __launch_bounds__(256)
void k_att(const float* __restrict__ hbar_p, const float* __restrict__ Fbar_p,
           const float* __restrict__ w2, const float* __restrict__ b2,
           float* __restrict__ att){
  __shared__ float As[32][33], Bs[32][33];
  int t = threadIdx.x;
  int bm = blockIdx.x*32, bn = blockIdx.y*32;
  int tx = t & 15, ty = t >> 4;
  const size_t Q = (size_t)256*608;
  float a00=0.f,a01=0.f,a10=0.f,a11=0.f;
  for (int k0 = 0; k0 < 608; k0 += 32){
    #pragma unroll
    for (int i = 0; i < 4; ++i){
      int idx = t + i*256;
      int kk = idx & 31, m = idx >> 5;
      size_t base = (size_t)(bm+m)*608 + k0 + kk;
      float s = 0.f;
      #pragma unroll
      for (int q = 0; q < 8; ++q) s += hbar_p[q*Q + base];
      As[kk][m] = s;
    }
    #pragma unroll
    for (int i = 0; i < 4; ++i){
      int idx = t + i*256;
      int n = idx & 31, kk = idx >> 5;
      int kg = k0 + kk, cg = bn + n;
      Bs[kk][n] = (kg < 600 && cg < 300) ? w2[(size_t)kg*300 + cg] : 0.f;
    }
    __syncthreads();
    #pragma unroll
    for (int kk = 0; kk < 32; ++kk){
      float x0 = As[kk][ty*2], x1 = As[kk][ty*2+1];
      float y0 = Bs[kk][tx*2], y1 = Bs[kk][tx*2+1];
      a00 += x0*y0; a01 += x0*y1; a10 += x1*y0; a11 += x1*y1;
    }
    __syncthreads();
  }
  const size_t QF = (size_t)256*300;
  int r0 = bm + ty*2, c0 = bn + tx*2;
  #pragma unroll
  for (int i = 0; i < 2; ++i){
    #pragma unroll
    for (int j = 0; j < 2; ++j){
      int r = r0 + i, c = c0 + j;
      if (c < 300){
        float acc = (i==0 ? (j==0?a00:a01) : (j==0?a10:a11));
        size_t fb = (size_t)r*300 + c;
        #pragma unroll
        for (int q = 0; q < 8; ++q) acc += Fbar_p[q*QF + fb];
        att[(size_t)r*300 + c] = acc + b2[c];
      }
    }
  }
}

__global__ __launch_bounds__(64)
void k_lnstats(const float* __restrict__ att, const float* __restrict__ ssum_g,
               const float* __restrict__ ssq_g, float* __restrict__ m_g, float* __restrict__ rs_g){
  int bb = blockIdx.x, lane = threadIdx.x;
  float s = 0.f, q = 0.f;
  for (int i = lane; i < 300; i += 64){
    float v = att[(size_t)bb*300 + i];
    s += v; q += v*v;
  }
  for (int o = 32; o > 0; o >>= 1){ s += __shfl_xor(s, o); q += __shfl_xor(q, o); }
  if (lane == 0){
    float m = (ssum_g[bb] + s) * (1.f/600.f);
    float var = (ssq_g[bb] + q) * (1.f/600.f) - m*m;
    m_g[bb] = m;
    rs_g[bb] = 1.f / sqrtf(var + 1e-5f);
  }
}

__global__ __launch_bounds__(256)
void k_mlp1(const float* __restrict__ sgs, const float* __restrict__ att,
            const float* __restrict__ m_g, const float* __restrict__ rs_g,
            const float* __restrict__ ln2g, const float* __restrict__ ln2b,
            const float* __restrict__ aw1, const float* __restrict__ ab1,
            float* __restrict__ g2){
  __shared__ float As[32][33], Bs[32][33];
  int t = threadIdx.x;
  int bm = blockIdx.x*32, bn = blockIdx.y*32;
  int tx = t & 15, ty = t >> 4;
  float a00=0.f,a01=0.f,a10=0.f,a11=0.f;
  for (int k0 = 0; k0 < 608; k0 += 32){
    #pragma unroll
    for (int i = 0; i < 4; ++i){
      int idx = t + i*256;
      int kk = idx & 31, m = idx >> 5;
      int kg = k0 + kk, row = bm + m;
      float t2 = 0.f;
      if (kg < 600){
        float x = (kg < 300) ? sgs[(size_t)row*300 + kg] : att[(size_t)row*300 + kg - 300];
        t2 = (x - m_g[row])*rs_g[row]*ln2g[kg] + ln2b[kg];
      }
      As[kk][m] = t2;
    }
    #pragma unroll
    for (int i = 0; i < 4; ++i){
      int idx = t + i*256;
      int n = idx & 31, kk = idx >> 5;
      int kg = k0 + kk, cg = bn + n;
      Bs[kk][n] = (kg < 600 && cg < 600) ? aw1[(size_t)kg*600 + cg] : 0.f;
    }
    __syncthreads();
    #pragma unroll
    for (int kk = 0; kk < 32; ++kk){
      float x0 = As[kk][ty*2], x1 = As[kk][ty*2+1];
      float y0 = Bs[kk][tx*2], y1 = Bs[kk][tx*2+1];
      a00 += x0*y0; a01 += x0*y1; a10 += x1*y0; a11 += x1*y1;
    }
    __syncthreads();
  }
  int r0 = bm + ty*2, c0 = bn + tx*2;
  #pragma unroll
  for (int i = 0; i < 2; ++i){
    #pragma unroll
    for (int j = 0; j < 2; ++j){
      int r = r0 + i, c = c0 + j;
      float acc = (i==0 ? (j==0?a00:a01) : (j==0?a10:a11));
      g2[(size_t)r*608 + c] = (c < 600) ? geluf(acc + ab1[c]) : 0.f;
    }
  }
}

__global__ __launch_bounds__(256)
void k_mlp2(const float* __restrict__ g2, const float* __restrict__ sgs,
            const float* __restrict__ aw2, const float* __restrict__ ab2,
            float* __restrict__ final_g){
  __shared__ float As[32][33], Bs[32][33];
  int t = threadIdx.x;
  int bm = blockIdx.x*32, bn = blockIdx.y*32;
  int tx = t & 15, ty = t >> 4;
  float a00=0.f,a01=0.f,a10=0.f,a11=0.f;
  for (int k0 = 0; k0 < 608; k0 += 32){
    #pragma unroll
    for (int i = 0; i < 4; ++i){
      int idx = t + i*256;
      int kk = idx & 31, m = idx >> 5;
      As[kk][m] = g2[(size_t)(bm+m)*608 + k0 + kk];
    }
    #pragma unroll
    for (int i = 0; i < 4; ++i){
      int idx = t + i*256;
      int n = idx & 31, kk = idx >> 5;
      int kg = k0 + kk, cg = bn + n;
      Bs[kk][n] = (kg < 600 && cg < 300) ? aw2[(size_t)kg*300 + cg] : 0.f;
    }
    __syncthreads();
    #pragma unroll
    for (int kk = 0; kk < 32; ++kk){
      float x0 = As[kk][ty*2], x1 = As[kk][ty*2+1];
      float y0 = Bs[kk][tx*2], y1 = Bs[kk][tx*2+1];
      a00 += x0*y0; a01 += x0*y1; a10 += x1*y0; a11 += x1*y1;
    }
    __syncthreads();
  }
  int r0 = bm + ty*2, c0 = bn + tx*2;
  #pragma unroll
  for (int i = 0; i < 2; ++i){
    #pragma unroll
    for (int j = 0; j < 2; ++j){
      int r = r0 + i, c = c0 + j;
      if (c < 300){
        float acc = (i==0 ? (j==0?a00:a01) : (j==0?a10:a11));
        final_g[(size_t)r*300 + c] = acc + ab2[c] + sgs[(size_t)r*300 + c];
      }
    }
  }
}

__global__ __launch_bounds__(64)
void k_cos(const float* __restrict__ final_g, float* __restrict__ out){
  int b = blockIdx.x; int lane = threadIdx.x;
  const float* A  = final_g + b*300;
  const float* Bv = final_g + (128 + b)*300;
  float dot = 0.f, na = 0.f, nb = 0.f;
  for (int i = lane; i < 300; i += 64){
    float x = A[i], y = Bv[i];
    dot += x*y; na += x*x; nb += y*y;
  }
  for (int o = 32; o > 0; o >>= 1){
    dot += __shfl_xor(dot, o); na += __shfl_xor(na, o); nb += __shfl_xor(nb, o);
  }
  if (lane == 0){
    float den = fmaxf(sqrtf(na), 1e-8f) * fmaxf(sqrtf(nb), 1e-8f);
    out[b] = 5.f * dot / den;
  }
}

extern "C" void kernel_launch(void* const* d_in, const int* in_sizes, int n_in,
                              void* d_out, int out_size, void* d_ws, size_t ws_size,
                              hipStream_t stream) {
  const int* ids_a = (const int*)d_in[0];
  const void* mask_a = d_in[1];
  const int* ids_b = (const int*)d_in[2];
  const void* mask_b = d_in[3];
  const float* mu_tab     = (const float*)d_in[4];
  const float* logvar_tab = (const float*)d_in[5];
  const float* alpha_tab  = (const float*)d_in[6];
  const float* feat_tab   = (const float*)d_in[7];
  const float* log_tau    = (const float*)d_in[8];
  const float* pos_mu     = (const float*)d_in[9];
  const float* pos_alpha  = (const float*)d_in[10];
  const float* ln1g = (const float*)d_in[11];
  const float* ln1b = (const float*)d_in[12];
  const float* w1   = (const float*)d_in[13];
  const float* b1   = (const float*)d_in[14];
  const float* w2   = (const float*)d_in[15];
  const float* b2   = (const float*)d_in[16];
  const float* wq   = (const float*)d_in[17];
  const float* bq   = (const float*)d_in[18];
  const float* wk   = (const float*)d_in[19];
  const float* bk   = (const float*)d_in[20];
  const float* ln2g = (const float*)d_in[21];
  const float* ln2b = (const float*)d_in[22];
  const float* aw1  = (const float*)d_in[23];
  const float* ab1  = (const float*)d_in[24];
  const float* aw2  = (const float*)d_in[25];
  const float* ab2  = (const float*)d_in[26];
  float* out = (float*)d_out;

  char* wsb = (char*)d_ws;
  size_t off = 0;
  auto take = [&](size_t bytes) -> void* {
    void* p = wsb + off;
    off += (bytes + 255) & ~(size_t)255;
    return p;
  };

  const size_t uBytes  = (size_t)30000 * 600 * 2;   // 36.0 MB
  const size_t aBytes  = (size_t)30080 * 320 * 2;   // 19.3 MB (ivar aliases after ugemm)
  const size_t btBytes = (size_t)640 * 320 * 2;     // 0.41 MB
  const size_t muBytes = (size_t)256 * 512 * 64 * 2;// 16.8 MB (aliased post-stage1)
  const size_t need = uBytes + aBytes + btBytes + muBytes + ((size_t)8 << 20);
  if (ws_size < need) return;   // ws >= 80.5MB proven (rounds 2-3 identical check passed)

  __hip_bfloat16* U = (__hip_bfloat16*)take(uBytes);
  char* abfRegion = (char*)take(aBytes);
  ushort* Abf = (ushort*)abfRegion;
  float* ivar_tab = (float*)abfRegion;               // 7.68 MB, alias (Abf dead after ugemm)
  ushort* BTbf = (ushort*)take(btBytes);
  char* muRegion = (char*)take(muBytes);
  ushort* MuS = (ushort*)muRegion;
  // alias post-stage1 buffers onto the (dead-after-stage1c) MuS region:
  float* hbar_p = (float*)(muRegion + 0);                 // 8*256*608*4 = 4,980,736
  float* Fbar_p = (float*)(muRegion + 4980736);           // 8*256*300*4 = 2,457,600
  float* att_g  = (float*)(muRegion + 4980736 + 2457600); // 307,200
  float* g2_g   = (float*)(muRegion + 7745536);           // 622,592
  float* final_g= (float*)(muRegion + 8368128);           // 307,200

  float* fsum   = (float*)take(30000*4);
  float* fsq    = (float*)take(30000*4);
  float* pgw    = (float*)take(8*600*4);
  float* pcv    = (float*)take(8*600*4);
  float* gw_g   = (float*)take(600*4);
  float* c_g    = (float*)take(600*4);
  float* sgs_g  = (float*)take(256*300*4);
  float* ssum_g = (float*)take(256*4);
  float* ssq_g  = (float*)take(256*4);
  float* V_g    = (float*)take(256*600*4);
  float* wgt_g  = (float*)take(256*512*4);
  float* m_g    = (float*)take(256*4);
  float* rs_g   = (float*)take(256*4);
  // stage1-split scratch (coexists with MuS):
  float* cent_p = (float*)take((size_t)2048*64*4);   // 512 KB
  float* msum_p = (float*)take(2048*4);
  float* cent   = (float*)take(256*64*4);
  float* al_g   = (float*)take((size_t)256*512*4);   // 512 KB
  float* wsum_p = (float*)take(2048*4);
  float* sgs_p  = (float*)take((size_t)2048*304*4);  // 2.49 MB

  k_pack_stats<<<7520, 256, 0, stream>>>(feat_tab, Abf, fsum, fsq);
  k_pack_b<<<(640*320 + 255)/256, 256, 0, stream>>>(w1, ln1g, BTbf);
  k_gw1_part<<<dim3(3, 8), 256, 0, stream>>>(w1, ln1g, ln1b, pgw, pcv);
  k_gw_reduce<<<3, 256, 0, stream>>>(pgw, pcv, b1, gw_g, c_g);
  k_ugemm_mfma<<<dim3(235, 5), 256, 0, stream>>>(Abf, BTbf, U);
  k_ivar<<<7500, 256, 0, stream>>>(logvar_tab, ivar_tab);   // after ugemm: reuses Abf region
  k_mu_stage<<<2048, 256, 0, stream>>>(ids_a, mask_a, ids_b, mask_b,
                                       mu_tab, pos_mu, alpha_tab, pos_alpha,
                                       MuS, cent_p, msum_p, al_g);
  k_cent_reduce<<<256, 64, 0, stream>>>(cent_p, msum_p, cent);
  k_wrender<<<2048, 256, 0, stream>>>(ids_a, ids_b, ivar_tab, MuS, cent, al_g,
                                      log_tau, feat_tab, wsum_p, sgs_p);
  k_stage1c<<<256, 512, 0, stream>>>(ids_a, mask_a, ids_b, mask_b,
                                     MuS, sgs_p, wsum_p,
                                     wq, bq, wk, bk,
                                     sgs_g, ssum_g, ssq_g, wgt_g);
  k_vgemm2<<<dim3(8, 19), 256, 0, stream>>>(sgs_g, w1, ln1g, V_g);
  k_hbar_fbar<<<2048, 256, 0, stream>>>(ids_a, ids_b, U, feat_tab, fsum, fsq,
                                        ssum_g, ssq_g, V_g, gw_g, c_g, wgt_g,
                                        hbar_p, Fbar_p);
  k_att<<<dim3(8, 10), 256, 0, stream>>>(hbar_p, Fbar_p, w2, b2, att_g);
  k_lnstats<<<256, 64, 0, stream>>>(att_g, ssum_g, ssq_g, m_g, rs_g);
  k_mlp1<<<dim3(8, 19), 256, 0, stream>>>(sgs_g, att_g, m_g, rs_g, ln2g, ln2b, aw1, ab1, g2_g);
  k_mlp2<<<dim3(8, 10), 256, 0, stream>>>(g2_g, sgs_g, aw2, ab2, final_g);
  k_cos<<<128, 64, 0, stream>>>(final_g, out);
}

// Round 10
// 371.970 us; speedup vs baseline: 1.3507x; 1.0260x over previous
//
#include <hip/hip_runtime.h>
#include <hip/hip_bf16.h>
#include <cstdint>
#include <cstddef>

#define DEV __device__ __forceinline__

// problem constants: B=128, S=512, V=30000, DS=64, DF=300, H=600, BB=256

typedef __attribute__((ext_vector_type(8))) short bf16x8;
typedef __attribute__((ext_vector_type(4))) float f32x4;

DEV float geluf(float x){ return 0.5f*x*(1.f + erff(x*0.7071067811865475f)); }
// tanh-form gelu, log2e folded: x * rcp(1 + exp2(x*(c1 + c2*x^2)))
DEV float gelu_fast(float x){
  float x2 = x*x;
  float e = __builtin_amdgcn_exp2f(x * __builtin_fmaf(x2, -0.102953f, -2.302218f));
  return x * __builtin_amdgcn_rcpf(1.f + e);
}

DEV float blk_sum512(float* red, int t, float v){
  red[t] = v; __syncthreads();
  for (int o = 256; o > 0; o >>= 1){ if (t < o) red[t] += red[t+o]; __syncthreads(); }
  float r = red[0]; __syncthreads(); return r;
}
DEV float blk_max512(float* red, int t, float v){
  red[t] = v; __syncthreads();
  for (int o = 256; o > 0; o >>= 1){ if (t < o) red[t] = fmaxf(red[t], red[t+o]); __syncthreads(); }
  float r = red[0]; __syncthreads(); return r;
}
DEV float blk_sum256(float* red, int t, float v){
  red[t] = v; __syncthreads();
  for (int o = 128; o > 0; o >>= 1){ if (t < o) red[t] += red[t+o]; __syncthreads(); }
  float r = red[0]; __syncthreads(); return r;
}

DEV ushort f2bf(float v){ __hip_bfloat16 h = __float2bfloat16(v); return *(ushort*)&h; }
DEV float bf2f(ushort u){ __hip_bfloat16 h; *(ushort*)&h = u; return __bfloat162float(h); }

// ---- mask dtype classifier (bool may arrive as u8 / int32 / bf16) ----
DEV int mask_mode(const unsigned char* m){
  bool big = false, off123 = false, off0one = false;
  #pragma unroll
  for (int i = 0; i < 16; ++i){
    unsigned char c = m[i];
    if (c > 1) big = true;
    if ((i & 3) != 0 && c != 0) off123 = true;
    if ((i & 3) == 0 && c == 1) off0one = true;
  }
  if (big) return 2;
  if (!off123 && off0one) return 1;
  return 0;
}
DEV float mask_read(const void* m, int idx, int mode){
  if (mode == 1) return ((const int*)m)[idx] ? 1.f : 0.f;
  if (mode == 2) return ((const unsigned short*)m)[idx] ? 1.f : 0.f;
  return ((const unsigned char*)m)[idx] ? 1.f : 0.f;
}

// ---------------- fused: pack A (bf16 [30080][320]) + per-vocab stats ----------------
__global__ __launch_bounds__(256)
void k_pack_stats(const float* __restrict__ feat, ushort* __restrict__ A,
                  float* __restrict__ fsum, float* __restrict__ fsq){
  int v = blockIdx.x*4 + (threadIdx.x >> 6);
  int ln = threadIdx.x & 63;
  if (v >= 30080) return;
  float vals[8] = {0.f,0.f,0.f,0.f,0.f,0.f,0.f,0.f};
  if (v < 30000 && ln < 38){
    const float* fr = &feat[(size_t)v*300];
    if (ln < 37){
      float4 a = *(const float4*)&fr[ln*8];
      float4 b = *(const float4*)&fr[ln*8 + 4];
      vals[0]=a.x; vals[1]=a.y; vals[2]=a.z; vals[3]=a.w;
      vals[4]=b.x; vals[5]=b.y; vals[6]=b.z; vals[7]=b.w;
    } else {
      float4 a = *(const float4*)&fr[296];
      vals[0]=a.x; vals[1]=a.y; vals[2]=a.z; vals[3]=a.w;
    }
  }
  if (ln < 40){
    union { ushort u[8]; bf16x8 v8; } pk;
    #pragma unroll
    for (int i = 0; i < 8; ++i) pk.u[i] = f2bf(vals[i]);
    *(bf16x8*)&A[(size_t)v*320 + ln*8] = pk.v8;
  }
  float s = 0.f, q = 0.f;
  #pragma unroll
  for (int i = 0; i < 8; ++i){ s += vals[i]; q += vals[i]*vals[i]; }
  for (int o = 32; o > 0; o >>= 1){ s += __shfl_xor(s, o); q += __shfl_xor(q, o); }
  if (ln == 0 && v < 30000){ fsum[v] = s; fsq[v] = q; }
}

// ---------------- P0b: gw1/cv partials ----------------
__global__ __launch_bounds__(256)
void k_gw1_part(const float* __restrict__ w1, const float* __restrict__ g,
                const float* __restrict__ bln, float* __restrict__ pgw, float* __restrict__ pcv){
  int j = blockIdx.x*256 + threadIdx.x;
  int ic = blockIdx.y;
  if (j >= 600) return;
  float a = 0.f, c = 0.f;
  for (int i = ic*75; i < ic*75 + 75; ++i){
    float w = w1[i*600 + j];
    a += g[i]*w; c += bln[i]*w;
  }
  pgw[ic*600 + j] = a; pcv[ic*600 + j] = c;
}

__global__ __launch_bounds__(256)
void k_gw_reduce(const float* __restrict__ pgw, const float* __restrict__ pcv,
                 const float* __restrict__ b1, float* __restrict__ gw_g, float* __restrict__ c_g){
  int j = blockIdx.x*256 + threadIdx.x;
  if (j >= 600) return;
  float a = 0.f, c = 0.f;
  for (int k = 0; k < 8; ++k){ a += pgw[k*600 + j]; c += pcv[k*600 + j]; }
  gw_g[j] = a; c_g[j] = c + b1[j];
}

// ---------------- pack B^T ----------------
__global__ __launch_bounds__(256)
void k_pack_b(const float* __restrict__ w1, const float* __restrict__ g, ushort* __restrict__ BT){
  int id = blockIdx.x*256 + threadIdx.x;
  if (id >= 640*320) return;
  int n = id % 640, k = id / 640;
  float val = (k < 300 && n < 600) ? g[k]*w1[k*600 + n] : 0.f;
  BT[(size_t)n*320 + k] = f2bf(val);
}

// ---------------- P1: U = A @ B via MFMA 16x16x32 bf16, 128x128 tile ----------------
__global__ __launch_bounds__(256)
void k_ugemm_mfma(const ushort* __restrict__ A, const ushort* __restrict__ BT,
                  __hip_bfloat16* __restrict__ U){
  __shared__ ushort As[128][40];
  __shared__ ushort Bs[128][40];
  int tid = threadIdx.x;
  int bm = blockIdx.x * 128, bn = blockIdx.y * 128;
  int wid = tid >> 6, lane = tid & 63;
  int wr = wid >> 1, wc = wid & 1;
  int lr = lane & 15, lk = lane >> 4;
  f32x4 acc[4][4] = {};
  for (int k0 = 0; k0 < 320; k0 += 32){
    #pragma unroll
    for (int j = 0; j < 2; ++j){
      int idx = tid + 256*j;
      int row = idx >> 2, ko = (idx & 3)*8;
      *(bf16x8*)&As[row][ko] = *(const bf16x8*)&A[(size_t)(bm+row)*320 + k0 + ko];
      *(bf16x8*)&Bs[row][ko] = *(const bf16x8*)&BT[(size_t)(bn+row)*320 + k0 + ko];
    }
    __syncthreads();
    bf16x8 af[4], bfr[4];
    #pragma unroll
    for (int f = 0; f < 4; ++f){
      af[f]  = *(const bf16x8*)&As[wr*64 + f*16 + lr][lk*8];
      bfr[f] = *(const bf16x8*)&Bs[wc*64 + f*16 + lr][lk*8];
    }
    #pragma unroll
    for (int i = 0; i < 4; ++i)
      #pragma unroll
      for (int j = 0; j < 4; ++j)
        acc[i][j] = __builtin_amdgcn_mfma_f32_16x16x32_bf16(af[i], bfr[j], acc[i][j], 0, 0, 0);
    __syncthreads();
  }
  #pragma unroll
  for (int i = 0; i < 4; ++i){
    #pragma unroll
    for (int j = 0; j < 4; ++j){
      #pragma unroll
      for (int r = 0; r < 4; ++r){
        int row = bm + wr*64 + i*16 + lk*4 + r;
        int col = bn + wc*64 + j*16 + lr;
        if (row < 30000 && col < 600)
          U[(size_t)row*600 + col] = __float2bfloat16(acc[i][j][r]);
      }
    }
  }
}

// ---------------- ivar precompute ----------------
__global__ __launch_bounds__(256)
void k_ivar(const float* __restrict__ logvar, float* __restrict__ ivar){
  int i = blockIdx.x*256 + threadIdx.x;
  if (i < 30000*64) ivar[i] = __builtin_amdgcn_exp2f(-1.44269504f*logvar[i]);
}

// ---------------- S1a: mu gather+stage (8-way split) ----------------
__global__ __launch_bounds__(256)
void k_mu_stage(const int* __restrict__ ids_a, const void* __restrict__ mask_a,
                const int* __restrict__ ids_b, const void* __restrict__ mask_b,
                const float* __restrict__ mu_tab, const float* __restrict__ pos_mu,
                const float* __restrict__ alpha_tab, const float* __restrict__ pos_alpha,
                ushort* __restrict__ MuS, float* __restrict__ cent_p,
                float* __restrict__ msum_p, float* __restrict__ al_g){
  int blk = blockIdx.x;                 // bb*8 + qr
  int bb = blk >> 3, qr = blk & 7;
  int b = bb & 127;
  const int* ids = (bb < 128) ? ids_a : ids_b;
  const void* msk = (bb < 128) ? mask_a : mask_b;
  int t = threadIdx.x;
  int grp = t >> 4, sub = t & 15;
  __shared__ int mmode_s;
  __shared__ float gpart[16][64];
  __shared__ float mf_s[64];
  __shared__ float red[256];
  if (t == 0) mmode_s = mask_mode((const unsigned char*)msk);
  __syncthreads();
  int mmode = mmode_s;
  float cp0=0.f, cp1=0.f, cp2=0.f, cp3=0.f;
  #pragma unroll
  for (int k = 0; k < 4; ++k){
    int sl = grp*4 + k;
    int s  = qr*64 + sl;
    int id = ids[b*512 + s];
    float mf = mask_read(msk, b*512 + s, mmode);
    float4 m4 = *(const float4*)&mu_tab[(size_t)id*64 + sub*4];
    float4 p4 = *(const float4*)&pos_mu[s*64 + sub*4];
    float v0 = m4.x+p4.x, v1 = m4.y+p4.y, v2 = m4.z+p4.z, v3 = m4.w+p4.w;
    ushort4 st; st.x = f2bf(v0); st.y = f2bf(v1); st.z = f2bf(v2); st.w = f2bf(v3);
    *(ushort4*)&MuS[((size_t)bb*512 + s)*64 + sub*4] = st;
    cp0 += mf*v0; cp1 += mf*v1; cp2 += mf*v2; cp3 += mf*v3;
    if (sub == 0){
      mf_s[sl] = mf;
      float pa = pos_alpha[s];
      float sg = __builtin_amdgcn_rcpf(1.f + __builtin_amdgcn_exp2f(-1.44269504f*pa));
      al_g[bb*512 + s] = alpha_tab[id] * sg * mf;
    }
  }
  gpart[grp][sub*4+0] = cp0; gpart[grp][sub*4+1] = cp1;
  gpart[grp][sub*4+2] = cp2; gpart[grp][sub*4+3] = cp3;
  __syncthreads();
  if (t < 64){
    float c = 0.f;
    #pragma unroll
    for (int g = 0; g < 16; ++g) c += gpart[g][t];
    cent_p[(size_t)blk*64 + t] = c;
  }
  float ms = blk_sum256(red, t, (t < 64) ? mf_s[t] : 0.f);
  if (t == 0) msum_p[blk] = ms;
}

// ---------------- S1b: centroid reduce ----------------
__global__ __launch_bounds__(64)
void k_cent_reduce(const float* __restrict__ cent_p, const float* __restrict__ msum_p,
                   float* __restrict__ cent){
  int bb = blockIdx.x, d = threadIdx.x;
  float c = 0.f, ms = 0.f;
  #pragma unroll
  for (int q = 0; q < 8; ++q){
    c  += cent_p[(size_t)(bb*8+q)*64 + d];
    ms += msum_p[bb*8+q];
  }
  cent[bb*64 + d] = c / fmaxf(ms, 1.f);
}

// ---------------- S1c: w = alpha*K, render partials ----------------
__global__ __launch_bounds__(256)
void k_wrender(const int* __restrict__ ids_a, const int* __restrict__ ids_b,
               const float* __restrict__ ivar_tab, const ushort* __restrict__ MuS,
               const float* __restrict__ cent, const float* __restrict__ al_g,
               const float* __restrict__ log_tau, const float* __restrict__ feat_tab,
               float* __restrict__ wsum_p, float* __restrict__ sgs_p){
  int blk = blockIdx.x;
  int bb = blk >> 3, qr = blk & 7;
  int b = bb & 127;
  const int* ids = (bb < 128) ? ids_a : ids_b;
  int t = threadIdx.x;
  int grp = t >> 4, sub = t & 15;
  __shared__ float wl[64];
  __shared__ int   idl[64];
  __shared__ float pacc[4][304];
  __shared__ float red[256];
  float itau = __builtin_amdgcn_exp2f(-1.44269504f*log_tau[0]);
  float c0 = cent[bb*64 + sub*4+0], c1 = cent[bb*64 + sub*4+1];
  float c2 = cent[bb*64 + sub*4+2], c3 = cent[bb*64 + sub*4+3];
  #pragma unroll
  for (int k = 0; k < 4; ++k){
    int sl = grp*4 + k, s = qr*64 + sl;
    int id = ids[b*512 + s];
    float4 iv = *(const float4*)&ivar_tab[(size_t)id*64 + sub*4];
    ushort4 mu = *(const ushort4*)&MuS[((size_t)bb*512 + s)*64 + sub*4];
    float d0 = bf2f(mu.x)-c0, d1 = bf2f(mu.y)-c1, d2v = bf2f(mu.z)-c2, d3 = bf2f(mu.w)-c3;
    float val = d0*d0*iv.x + d1*d1*iv.y + d2v*d2v*iv.z + d3*d3*iv.w;
    val += __shfl_xor(val, 1); val += __shfl_xor(val, 2);
    val += __shfl_xor(val, 4); val += __shfl_xor(val, 8);
    if (sub == 0){
      idl[sl] = id;
      float K = __builtin_amdgcn_exp2f(-0.72134752f * val * itau);
      wl[sl] = al_g[bb*512 + s] * K;
    }
  }
  __syncthreads();
  float ws = blk_sum256(red, t, (t < 64) ? wl[t] : 0.f);
  if (t == 0) wsum_p[blk] = ws;
  int wv = t >> 6, ln = t & 63;
  float a10=0.f,a11=0.f,a12=0.f,a13=0.f, a20=0.f,a21=0.f,a22=0.f,a23=0.f;
  for (int k = 0; k < 16; ++k){
    int sl = (wv << 4) | k;
    float w = wl[sl];
    const float* fr = &feat_tab[(size_t)idl[sl]*300];
    float4 v1 = *(const float4*)&fr[ln*4];
    a10 += w*v1.x; a11 += w*v1.y; a12 += w*v1.z; a13 += w*v1.w;
    if (ln < 11){
      float4 v2 = *(const float4*)&fr[256 + ln*4];
      a20 += w*v2.x; a21 += w*v2.y; a22 += w*v2.z; a23 += w*v2.w;
    }
  }
  pacc[wv][ln*4+0]=a10; pacc[wv][ln*4+1]=a11; pacc[wv][ln*4+2]=a12; pacc[wv][ln*4+3]=a13;
  if (ln < 11){
    pacc[wv][256+ln*4+0]=a20; pacc[wv][256+ln*4+1]=a21;
    pacc[wv][256+ln*4+2]=a22; pacc[wv][256+ln*4+3]=a23;
  }
  __syncthreads();
  for (int j = t; j < 300; j += 256)
    sgs_p[(size_t)blk*304 + j] = pacc[0][j] + pacc[1][j] + pacc[2][j] + pacc[3][j];
}

// ---------------- S1d: sgs reduce, query, scores, softmax ----------------
__global__ __launch_bounds__(512)
void k_stage1c(const int* __restrict__ ids_a, const void* __restrict__ mask_a,
               const int* __restrict__ ids_b, const void* __restrict__ mask_b,
               const ushort* __restrict__ MuS, const float* __restrict__ sgs_p,
               const float* __restrict__ wsum_p,
               const float* __restrict__ wq, const float* __restrict__ bq,
               const float* __restrict__ wk, const float* __restrict__ bk,
               float* __restrict__ sgs_g, float* __restrict__ ssum_g, float* __restrict__ ssq_g,
               float* __restrict__ wgt_g)
{
  int bb = blockIdx.x;
  const void* msk = (bb < 128) ? mask_a : mask_b;
  int b = bb & 127;
  int t = threadIdx.x;
  __shared__ float mf_l[512], w_l[512], red[512];
  __shared__ float q_l[64], qk_l[64];
  __shared__ float sgs_l[304];
  __shared__ float bkq_s;
  __shared__ int mmode;
  if (t == 0) mmode = mask_mode((const unsigned char*)msk);
  __syncthreads();
  mf_l[t] = mask_read(msk, b*512 + t, mmode);

  float wsum = 0.f;
  #pragma unroll
  for (int q = 0; q < 8; ++q) wsum += wsum_p[bb*8 + q];
  wsum = fmaxf(wsum, 1e-8f);
  if (t < 300){
    float sa = 0.f;
    #pragma unroll
    for (int q = 0; q < 8; ++q) sa += sgs_p[(size_t)(bb*8+q)*304 + t];
    float sv = sa / wsum;
    sgs_l[t] = sv;
    sgs_g[bb*300 + t] = sv;
  }
  __syncthreads();
  float ssum = blk_sum512(red, t, (t < 300) ? sgs_l[t] : 0.f);
  float ssq  = blk_sum512(red, t, (t < 300) ? sgs_l[t]*sgs_l[t] : 0.f);
  if (t == 0){ ssum_g[bb] = ssum; ssq_g[bb] = ssq; }

  if (t < 64){
    float q = bq[t];
    for (int i = 0; i < 300; ++i) q += sgs_l[i]*wq[i*64 + t];
    q_l[t] = q;
  }
  __syncthreads();
  if (t < 64){
    float a = 0.f;
    for (int j = 0; j < 64; ++j) a += wk[t*64 + j]*q_l[j];
    qk_l[t] = a;
  }
  if (t == 0){
    float s = 0.f;
    for (int j = 0; j < 64; ++j) s += bk[j]*q_l[j];
    bkq_s = s;
  }
  __syncthreads();

  int grp = t >> 4, sub = t & 15;
  {
    float q0 = qk_l[sub*4+0], q1 = qk_l[sub*4+1], q2 = qk_l[sub*4+2], q3 = qk_l[sub*4+3];
    for (int k = 0; k < 16; ++k){
      int s = (grp << 4) | k;
      ushort4 mu = *(const ushort4*)&MuS[((size_t)bb*512 + s)*64 + sub*4];
      float val = bf2f(mu.x)*q0 + bf2f(mu.y)*q1 + bf2f(mu.z)*q2 + bf2f(mu.w)*q3;
      val += __shfl_xor(val, 1); val += __shfl_xor(val, 2);
      val += __shfl_xor(val, 4); val += __shfl_xor(val, 8);
      if (sub == 0){
        float sv = (val + bkq_s) * 0.125f;
        w_l[s] = (mf_l[s] != 0.f) ? sv : -1e30f;
      }
    }
  }
  __syncthreads();

  float mx = blk_max512(red, t, w_l[t]);
  float ex = __expf(w_l[t] - mx);
  float Z  = blk_sum512(red, t, ex);
  wgt_g[bb*512 + t] = ex / Z;
}

// ---------------- k_vgemm2 ----------------
__global__ __launch_bounds__(256)
void k_vgemm2(const float* __restrict__ sgs, const float* __restrict__ w1,
              const float* __restrict__ ln1g, float* __restrict__ V_g){
  __shared__ float As[32][33], Bs[32][33];
  int t = threadIdx.x;
  int bm = blockIdx.x*32, bn = blockIdx.y*32;
  int tx = t & 15, ty = t >> 4;
  float a00=0.f,a01=0.f,a10=0.f,a11=0.f;
  for (int k0 = 0; k0 < 300; k0 += 32){
    #pragma unroll
    for (int i = 0; i < 4; ++i){
      int idx = t + i*256;
      int kk = idx & 31, m = idx >> 5;
      int kg = k0 + kk;
      As[kk][m] = (kg < 300) ? sgs[(size_t)(bm+m)*300 + kg] : 0.f;
    }
    #pragma unroll
    for (int i = 0; i < 4; ++i){
      int idx = t + i*256;
      int n = idx & 31, kk = idx >> 5;
      int kg = k0 + kk, cg = bn + n;
      Bs[kk][n] = (kg < 300 && cg < 600) ? ln1g[300 + kg]*w1[(size_t)(300 + kg)*600 + cg] : 0.f;
    }
    __syncthreads();
    #pragma unroll
    for (int kk = 0; kk < 32; ++kk){
      float x0 = As[kk][ty*2], x1 = As[kk][ty*2+1];
      float y0 = Bs[kk][tx*2], y1 = Bs[kk][tx*2+1];
      a00 += x0*y0; a01 += x0*y1; a10 += x1*y0; a11 += x1*y1;
    }
    __syncthreads();
  }
  int r0 = bm + ty*2, c0 = bn + tx*2;
  #pragma unroll
  for (int i = 0; i < 2; ++i){
    #pragma unroll
    for (int j = 0; j < 2; ++j){
      int r = r0 + i, c = c0 + j;
      if (c < 600) V_g[(size_t)r*600 + c] = (i==0 ? (j==0?a00:a01) : (j==0?a10:a11));
    }
  }
}

// ---------------- K2: hbar + Fbar eighth-split ----------------
__global__ __launch_bounds__(256)
void k_hbar_fbar(const int* __restrict__ ids_a, const int* __restrict__ ids_b,
                 const __hip_bfloat16* __restrict__ U, const float* __restrict__ feat_tab,
                 const float* __restrict__ fsum, const float* __restrict__ fsq,
                 const float* __restrict__ ssum_g, const float* __restrict__ ssq_g,
                 const float* __restrict__ V_g, const float* __restrict__ gw_g,
                 const float* __restrict__ c_g, const float* __restrict__ wgt_g,
                 float* __restrict__ hbar_p, float* __restrict__ Fbar_p)
{
  int blk = blockIdx.x;
  int bb = blk >> 3, qr = blk & 7;
  int b = bb & 127;
  const int* ids = (bb < 128) ? ids_a : ids_b;
  int t = threadIdx.x;
  __shared__ int id_l[64];
  __shared__ float m_l[64], rs_l[64], wg_l[64];
  __shared__ float hp[4][600];
  __shared__ float fp[4][304];
  float ss = ssum_g[bb], sq = ssq_g[bb];
  if (t < 64){
    int s = qr*64 + t;
    int id = ids[b*512 + s];
    id_l[t] = id;
    float m = (fsum[id] + ss) * (1.f/600.f);
    float var = (fsq[id] + sq) * (1.f/600.f) - m*m;
    m_l[t] = m;
    rs_l[t] = 1.f / sqrtf(var + 1e-5f);
    wg_l[t] = wgt_g[bb*512 + s];
  }
  __syncthreads();

  int wv = t >> 6, ln = t & 63;
  float Vp[8], gwp[8], cp[8], Vs[8], gws[8], cs[8];
  #pragma unroll
  for (int r = 0; r < 8; ++r){
    int j = ln*8 + r;
    Vp[r] = V_g[bb*600 + j]; gwp[r] = gw_g[j]; cp[r] = c_g[j];
    Vs[r] = 0.f; gws[r] = 0.f; cs[r] = 0.f;
  }
  if (ln < 11){
    #pragma unroll
    for (int r = 0; r < 8; ++r){
      int j = 512 + ln*8 + r;
      Vs[r] = V_g[bb*600 + j]; gws[r] = gw_g[j]; cs[r] = c_g[j];
    }
  }
  float h1[8] = {}, h2[8] = {};
  float f10=0.f,f11=0.f,f12=0.f,f13=0.f, f20=0.f,f21=0.f,f22=0.f,f23=0.f;

  for (int k = 0; k < 16; ++k){
    int s = (wv << 4) | k;
    int id = id_l[s];
    float w = wg_l[s], m = m_l[s], rs = rs_l[s];
    const __hip_bfloat16* ur = &U[(size_t)id*600];
    const float* fr = &feat_tab[(size_t)id*300];
    bf16x8 u8 = *(const bf16x8*)&ur[ln*8];
    float4 fv = *(const float4*)&fr[ln*4];
    #pragma unroll
    for (int r = 0; r < 8; ++r){
      float u = bf2f((ushort)u8[r]);
      float a = (u + Vp[r] - m*gwp[r])*rs + cp[r];
      h1[r] += w*gelu_fast(a);
    }
    f10 += w*fv.x; f11 += w*fv.y; f12 += w*fv.z; f13 += w*fv.w;
    if (ln < 11){
      bf16x8 u8b = *(const bf16x8*)&ur[512 + ln*8];
      float4 fvb = *(const float4*)&fr[256 + ln*4];
      #pragma unroll
      for (int r = 0; r < 8; ++r){
        float u = bf2f((ushort)u8b[r]);
        float a = (u + Vs[r] - m*gws[r])*rs + cs[r];
        h2[r] += w*gelu_fast(a);
      }
      f20 += w*fvb.x; f21 += w*fvb.y; f22 += w*fvb.z; f23 += w*fvb.w;
    }
  }
  #pragma unroll
  for (int r = 0; r < 8; ++r) hp[wv][ln*8 + r] = h1[r];
  if (ln < 11){
    #pragma unroll
    for (int r = 0; r < 8; ++r) hp[wv][512 + ln*8 + r] = h2[r];
  }
  fp[wv][ln*4+0]=f10; fp[wv][ln*4+1]=f11; fp[wv][ln*4+2]=f12; fp[wv][ln*4+3]=f13;
  if (ln < 11){
    fp[wv][256+ln*4+0]=f20; fp[wv][256+ln*4+1]=f21;
    fp[wv][256+ln*4+2]=f22; fp[wv][256+ln*4+3]=f23;
  }
  __syncthreads();
  size_t hbase = ((size_t)qr*256 + bb)*608;
  for (int j = t; j < 600; j += 256){
    hbar_p[hbase + j] = hp[0][j] + hp[1][j] + hp[2][j] + hp[3][j];
  }
  if (t < 8) hbar_p[hbase + 600 + t] = 0.f;
  size_t fbase = ((size_t)qr*256 + bb)*300;
  for (int j = t; j < 300; j += 256){
    Fbar_p[fbase + j] = fp[0][j] + fp[1][j] + fp[2][j] + fp[3][j];
  }
}

// ---------------- k_hreduce: sum the 8 partials (coalesced, massively parallel) ----------------
__global__ __launch_bounds__(256)
void k_hreduce(const float* __restrict__ hbar_p, const float* __restrict__ Fbar_p,
               float* __restrict__ hbar_s, float* __restrict__ Fbar_s){
  int i = blockIdx.x*256 + threadIdx.x;
  const size_t Q  = (size_t)256*608;
  const size_t QF = (size_t)256*300;
  if (i < 256*608){
    float s0 = hbar_p[i]       + hbar_p[Q + i];
    float s1 = hbar_p[2*Q + i] + hbar_p[3*Q + i];
    float s2 = hbar_p[4*Q + i] + hbar_p[5*Q + i];
    float s3 = hbar_p[6*Q + i] + hbar_p[7*Q + i];
    hbar_s[i] = (s0 + s1) + (s2 + s3);
  }
  if (i < 256*300){
    float s0 = Fbar_p[i]        + Fbar_p[QF + i];
    float s1 = Fbar_p[2*QF + i] + Fbar_p[3*QF + i];
    float s2 = Fbar_p[4*QF + i] + Fbar_p[5*QF + i];
    float s3 = Fbar_p[6*QF + i] + Fbar_p[7*QF + i];
    Fbar_s[i] = (s0 + s1) + (s2 + s3);
  }
}

// ============ final chain: small tiled fp32 GEMMs ============

__global__ __launch_bounds__(256)
void k_att(const float* __restrict__ hbar_s, const float* __restrict__ Fbar_s,
           const float* __restrict__ w2, const float* __restrict__ b2,
           float* __restrict__ att){
  __shared__ float As[32][33], Bs[32][33];
  int t = threadIdx.x;
  int bm = blockIdx.x*32, bn = blockIdx.y*32;
  int tx = t & 15, ty = t >> 4;
  float a00=0.f,a01=0.f,a10=0.f,a11=0.f;
  for (int k0 = 0; k0 < 608; k0 += 32){
    #pragma unroll
    for (int i = 0; i < 4; ++i){
      int idx = t + i*256;
      int kk = idx & 31, m = idx >> 5;
      As[kk][m] = hbar_s[(size_t)(bm+m)*608 + k0 + kk];
    }
    #pragma unroll
    for (int i = 0; i < 4; ++i){
      int idx = t + i*256;
      int n = idx & 31, kk = idx >> 5;
      int kg = k0 + kk, cg = bn + n;
      Bs[kk][n] = (kg < 600 && cg < 300) ? w2[(size_t)kg*300 + cg] : 0.f;
    }
    __syncthreads();
    #pragma unroll
    for (int kk = 0; kk < 32; ++kk){
      float x0 = As[kk][ty*2], x1 = As[kk][ty*2+1];
      float y0 = Bs[kk][tx*2], y1 = Bs[kk][tx*2+1];
      a00 += x0*y0; a01 += x0*y1; a10 += x1*y0; a11 += x1*y1;
    }
    __syncthreads();
  }
  int r0 = bm + ty*2, c0 = bn + tx*2;
  #pragma unroll
  for (int i = 0; i < 2; ++i){
    #pragma unroll
    for (int j = 0; j < 2; ++j){
      int r = r0 + i, c = c0 + j;
      if (c < 300){
        float acc = (i==0 ? (j==0?a00:a01) : (j==0?a10:a11));
        att[(size_t)r*300 + c] = acc + b2[c] + Fbar_s[(size_t)r*300 + c];
      }
    }
  }
}

__global__ __launch_bounds__(64)
void k_lnstats(const float* __restrict__ att, const float* __restrict__ ssum_g,
               const float* __restrict__ ssq_g, float* __restrict__ m_g, float* __restrict__ rs_g){
  int bb = blockIdx.x, lane = threadIdx.x;
  float s = 0.f, q = 0.f;
  for (int i = lane; i < 300; i += 64){
    float v = att[(size_t)bb*300 + i];
    s += v; q += v*v;
  }
  for (int o = 32; o > 0; o >>= 1){ s += __shfl_xor(s, o); q += __shfl_xor(q, o); }
  if (lane == 0){
    float m = (ssum_g[bb] + s) * (1.f/600.f);
    float var = (ssq_g[bb] + q) * (1.f/600.f) - m*m;
    m_g[bb] = m;
    rs_g[bb] = 1.f / sqrtf(var + 1e-5f);
  }
}

__global__ __launch_bounds__(256)
void k_mlp1(const float* __restrict__ sgs, const float* __restrict__ att,
            const float* __restrict__ m_g, const float* __restrict__ rs_g,
            const float* __restrict__ ln2g, const float* __restrict__ ln2b,
            const float* __restrict__ aw1, const float* __restrict__ ab1,
            float* __restrict__ g2){
  __shared__ float As[32][33], Bs[32][33];
  int t = threadIdx.x;
  int bm = blockIdx.x*32, bn = blockIdx.y*32;
  int tx = t & 15, ty = t >> 4;
  float a00=0.f,a01=0.f,a10=0.f,a11=0.f;
  for (int k0 = 0; k0 < 608; k0 += 32){
    #pragma unroll
    for (int i = 0; i < 4; ++i){
      int idx = t + i*256;
      int kk = idx & 31, m = idx >> 5;
      int kg = k0 + kk, row = bm + m;
      float t2 = 0.f;
      if (kg < 600){
        float x = (kg < 300) ? sgs[(size_t)row*300 + kg] : att[(size_t)row*300 + kg - 300];
        t2 = (x - m_g[row])*rs_g[row]*ln2g[kg] + ln2b[kg];
      }
      As[kk][m] = t2;
    }
    #pragma unroll
    for (int i = 0; i < 4; ++i){
      int idx = t + i*256;
      int n = idx & 31, kk = idx >> 5;
      int kg = k0 + kk, cg = bn + n;
      Bs[kk][n] = (kg < 600 && cg < 600) ? aw1[(size_t)kg*600 + cg] : 0.f;
    }
    __syncthreads();
    #pragma unroll
    for (int kk = 0; kk < 32; ++kk){
      float x0 = As[kk][ty*2], x1 = As[kk][ty*2+1];
      float y0 = Bs[kk][tx*2], y1 = Bs[kk][tx*2+1];
      a00 += x0*y0; a01 += x0*y1; a10 += x1*y0; a11 += x1*y1;
    }
    __syncthreads();
  }
  int r0 = bm + ty*2, c0 = bn + tx*2;
  #pragma unroll
  for (int i = 0; i < 2; ++i){
    #pragma unroll
    for (int j = 0; j < 2; ++j){
      int r = r0 + i, c = c0 + j;
      float acc = (i==0 ? (j==0?a00:a01) : (j==0?a10:a11));
      g2[(size_t)r*608 + c] = (c < 600) ? geluf(acc + ab1[c]) : 0.f;
    }
  }
}

__global__ __launch_bounds__(256)
void k_mlp2(const float* __restrict__ g2, const float* __restrict__ sgs,
            const float* __restrict__ aw2, const float* __restrict__ ab2,
            float* __restrict__ final_g){
  __shared__ float As[32][33], Bs[32][33];
  int t = threadIdx.x;
  int bm = blockIdx.x*32, bn = blockIdx.y*32;
  int tx = t & 15, ty = t >> 4;
  float a00=0.f,a01=0.f,a10=0.f,a11=0.f;
  for (int k0 = 0; k0 < 608; k0 += 32){
    #pragma unroll
    for (int i = 0; i < 4; ++i){
      int idx = t + i*256;
      int kk = idx & 31, m = idx >> 5;
      As[kk][m] = g2[(size_t)(bm+m)*608 + k0 + kk];
    }
    #pragma unroll
    for (int i = 0; i < 4; ++i){
      int idx = t + i*256;
      int n = idx & 31, kk = idx >> 5;
      int kg = k0 + kk, cg = bn + n;
      Bs[kk][n] = (kg < 600 && cg < 300) ? aw2[(size_t)kg*300 + cg] : 0.f;
    }
    __syncthreads();
    #pragma unroll
    for (int kk = 0; kk < 32; ++kk){
      float x0 = As[kk][ty*2], x1 = As[kk][ty*2+1];
      float y0 = Bs[kk][tx*2], y1 = Bs[kk][tx*2+1];
      a00 += x0*y0; a01 += x0*y1; a10 += x1*y0; a11 += x1*y1;
    }
    __syncthreads();
  }
  int r0 = bm + ty*2, c0 = bn + tx*2;
  #pragma unroll
  for (int i = 0; i < 2; ++i){
    #pragma unroll
    for (int j = 0; j < 2; ++j){
      int r = r0 + i, c = c0 + j;
      if (c < 300){
        float acc = (i==0 ? (j==0?a00:a01) : (j==0?a10:a11));
        final_g[(size_t)r*300 + c] = acc + ab2[c] + sgs[(size_t)r*300 + c];
      }
    }
  }
}

__global__ __launch_bounds__(64)
void k_cos(const float* __restrict__ final_g, float* __restrict__ out){
  int b = blockIdx.x; int lane = threadIdx.x;
  const float* A  = final_g + b*300;
  const float* Bv = final_g + (128 + b)*300;
  float dot = 0.f, na = 0.f, nb = 0.f;
  for (int i = lane; i < 300; i += 64){
    float x = A[i], y = Bv[i];
    dot += x*y; na += x*x; nb += y*y;
  }
  for (int o = 32; o > 0; o >>= 1){
    dot += __shfl_xor(dot, o); na += __shfl_xor(na, o); nb += __shfl_xor(nb, o);
  }
  if (lane == 0){
    float den = fmaxf(sqrtf(na), 1e-8f) * fmaxf(sqrtf(nb), 1e-8f);
    out[b] = 5.f * dot / den;
  }
}

extern "C" void kernel_launch(void* const* d_in, const int* in_sizes, int n_in,
                              void* d_out, int out_size, void* d_ws, size_t ws_size,
                              hipStream_t stream) {
  const int* ids_a = (const int*)d_in[0];
  const void* mask_a = d_in[1];
  const int* ids_b = (const int*)d_in[2];
  const void* mask_b = d_in[3];
  const float* mu_tab     = (const float*)d_in[4];
  const float* logvar_tab = (const float*)d_in[5];
  const float* alpha_tab  = (const float*)d_in[6];
  const float* feat_tab   = (const float*)d_in[7];
  const float* log_tau    = (const float*)d_in[8];
  const float* pos_mu     = (const float*)d_in[9];
  const float* pos_alpha  = (const float*)d_in[10];
  const float* ln1g = (const float*)d_in[11];
  const float* ln1b = (const float*)d_in[12];
  const float* w1   = (const float*)d_in[13];
  const float* b1   = (const float*)d_in[14];
  const float* w2   = (const float*)d_in[15];
  const float* b2   = (const float*)d_in[16];
  const float* wq   = (const float*)d_in[17];
  const float* bq   = (const float*)d_in[18];
  const float* wk   = (const float*)d_in[19];
  const float* bk   = (const float*)d_in[20];
  const float* ln2g = (const float*)d_in[21];
  const float* ln2b = (const float*)d_in[22];
  const float* aw1  = (const float*)d_in[23];
  const float* ab1  = (const float*)d_in[24];
  const float* aw2  = (const float*)d_in[25];
  const float* ab2  = (const float*)d_in[26];
  float* out = (float*)d_out;

  char* wsb = (char*)d_ws;
  size_t off = 0;
  auto take = [&](size_t bytes) -> void* {
    void* p = wsb + off;
    off += (bytes + 255) & ~(size_t)255;
    return p;
  };

  const size_t uBytes  = (size_t)30000 * 600 * 2;   // 36.0 MB
  const size_t aBytes  = (size_t)30080 * 320 * 2;   // 19.3 MB (ivar aliases after ugemm)
  const size_t btBytes = (size_t)640 * 320 * 2;     // 0.41 MB
  const size_t muBytes = (size_t)256 * 512 * 64 * 2;// 16.8 MB (aliased post-stage1)
  const size_t need = uBytes + aBytes + btBytes + muBytes + ((size_t)8 << 20);
  if (ws_size < need) return;

  __hip_bfloat16* U = (__hip_bfloat16*)take(uBytes);
  char* abfRegion = (char*)take(aBytes);
  ushort* Abf = (ushort*)abfRegion;
  float* ivar_tab = (float*)abfRegion;               // alias (Abf dead after ugemm)
  ushort* BTbf = (ushort*)take(btBytes);
  char* muRegion = (char*)take(muBytes);
  ushort* MuS = (ushort*)muRegion;
  // alias post-stage1 buffers onto the (dead-after-stage1c) MuS region:
  float* hbar_p = (float*)(muRegion + 0);                 // 8*256*608*4 = 4,980,736
  float* Fbar_p = (float*)(muRegion + 4980736);           // 8*256*300*4 = 2,457,600
  float* att_g  = (float*)(muRegion + 7438336);           // 307,200
  float* g2_g   = (float*)(muRegion + 7745536);           // 622,592
  float* final_g= (float*)(muRegion + 8368128);           // 307,200
  float* hbar_s = (float*)(muRegion + 8675328);           // 256*608*4 = 622,592
  float* Fbar_s = (float*)(muRegion + 9297920);           // 256*300*4 = 307,200  (ends 9.6MB < 16.8MB)

  float* fsum   = (float*)take(30000*4);
  float* fsq    = (float*)take(30000*4);
  float* pgw    = (float*)take(8*600*4);
  float* pcv    = (float*)take(8*600*4);
  float* gw_g   = (float*)take(600*4);
  float* c_g    = (float*)take(600*4);
  float* sgs_g  = (float*)take(256*300*4);
  float* ssum_g = (float*)take(256*4);
  float* ssq_g  = (float*)take(256*4);
  float* V_g    = (float*)take(256*600*4);
  float* wgt_g  = (float*)take(256*512*4);
  float* m_g    = (float*)take(256*4);
  float* rs_g   = (float*)take(256*4);
  float* cent_p = (float*)take((size_t)2048*64*4);
  float* msum_p = (float*)take(2048*4);
  float* cent   = (float*)take(256*64*4);
  float* al_g   = (float*)take((size_t)256*512*4);
  float* wsum_p = (float*)take(2048*4);
  float* sgs_p  = (float*)take((size_t)2048*304*4);

  k_pack_stats<<<7520, 256, 0, stream>>>(feat_tab, Abf, fsum, fsq);
  k_pack_b<<<(640*320 + 255)/256, 256, 0, stream>>>(w1, ln1g, BTbf);
  k_gw1_part<<<dim3(3, 8), 256, 0, stream>>>(w1, ln1g, ln1b, pgw, pcv);
  k_gw_reduce<<<3, 256, 0, stream>>>(pgw, pcv, b1, gw_g, c_g);
  k_ugemm_mfma<<<dim3(235, 5), 256, 0, stream>>>(Abf, BTbf, U);
  k_ivar<<<7500, 256, 0, stream>>>(logvar_tab, ivar_tab);
  k_mu_stage<<<2048, 256, 0, stream>>>(ids_a, mask_a, ids_b, mask_b,
                                       mu_tab, pos_mu, alpha_tab, pos_alpha,
                                       MuS, cent_p, msum_p, al_g);
  k_cent_reduce<<<256, 64, 0, stream>>>(cent_p, msum_p, cent);
  k_wrender<<<2048, 256, 0, stream>>>(ids_a, ids_b, ivar_tab, MuS, cent, al_g,
                                      log_tau, feat_tab, wsum_p, sgs_p);
  k_stage1c<<<256, 512, 0, stream>>>(ids_a, mask_a, ids_b, mask_b,
                                     MuS, sgs_p, wsum_p,
                                     wq, bq, wk, bk,
                                     sgs_g, ssum_g, ssq_g, wgt_g);
  k_vgemm2<<<dim3(8, 19), 256, 0, stream>>>(sgs_g, w1, ln1g, V_g);
  k_hbar_fbar<<<2048, 256, 0, stream>>>(ids_a, ids_b, U, feat_tab, fsum, fsq,
                                        ssum_g, ssq_g, V_g, gw_g, c_g, wgt_g,
                                        hbar_p, Fbar_p);
  k_hreduce<<<608, 256, 0, stream>>>(hbar_p, Fbar_p, hbar_s, Fbar_s);
  k_att<<<dim3(8, 10), 256, 0, stream>>>(hbar_s, Fbar_s, w2, b2, att_g);
  k_lnstats<<<256, 64, 0, stream>>>(att_g, ssum_g, ssq_g, m_g, rs_g);
  k_mlp1<<<dim3(8, 19), 256, 0, stream>>>(sgs_g, att_g, m_g, rs_g, ln2g, ln2b, aw1, ab1, g2_g);
  k_mlp2<<<dim3(8, 10), 256, 0, stream>>>(g2_g, sgs_g, aw2, ab2, final_g);
  k_cos<<<128, 64, 0, stream>>>(final_g, out);
}

// Round 11
// 280.985 us; speedup vs baseline: 1.7880x; 1.3238x over previous
//
#include <hip/hip_runtime.h>
#include <hip/hip_bf16.h>
#include <cstdint>
#include <cstddef>

#define DEV __device__ __forceinline__

// problem constants: B=128, S=512, V=30000, DS=64, DF=300, H=600, BB=256

typedef __attribute__((ext_vector_type(8))) short bf16x8;
typedef __attribute__((ext_vector_type(4))) float f32x4;

DEV float geluf(float x){ return 0.5f*x*(1.f + erff(x*0.7071067811865475f)); }
DEV float gelu_fast(float x){
  float x2 = x*x;
  float e = __builtin_amdgcn_exp2f(x * __builtin_fmaf(x2, -0.102953f, -2.302218f));
  return x * __builtin_amdgcn_rcpf(1.f + e);
}

DEV float blk_sum512(float* red, int t, float v){
  red[t] = v; __syncthreads();
  for (int o = 256; o > 0; o >>= 1){ if (t < o) red[t] += red[t+o]; __syncthreads(); }
  float r = red[0]; __syncthreads(); return r;
}
DEV float blk_max512(float* red, int t, float v){
  red[t] = v; __syncthreads();
  for (int o = 256; o > 0; o >>= 1){ if (t < o) red[t] = fmaxf(red[t], red[t+o]); __syncthreads(); }
  float r = red[0]; __syncthreads(); return r;
}
DEV float blk_sum256(float* red, int t, float v){
  red[t] = v; __syncthreads();
  for (int o = 128; o > 0; o >>= 1){ if (t < o) red[t] += red[t+o]; __syncthreads(); }
  float r = red[0]; __syncthreads(); return r;
}

DEV ushort f2bf(float v){ __hip_bfloat16 h = __float2bfloat16(v); return *(ushort*)&h; }
DEV float bf2f(ushort u){ __hip_bfloat16 h; *(ushort*)&h = u; return __bfloat162float(h); }

// ---- mask dtype classifier ----
DEV int mask_mode(const unsigned char* m){
  bool big = false, off123 = false, off0one = false;
  #pragma unroll
  for (int i = 0; i < 16; ++i){
    unsigned char c = m[i];
    if (c > 1) big = true;
    if ((i & 3) != 0 && c != 0) off123 = true;
    if ((i & 3) == 0 && c == 1) off0one = true;
  }
  if (big) return 2;
  if (!off123 && off0one) return 1;
  return 0;
}
DEV float mask_read(const void* m, int idx, int mode){
  if (mode == 1) return ((const int*)m)[idx] ? 1.f : 0.f;
  if (mode == 2) return ((const unsigned short*)m)[idx] ? 1.f : 0.f;
  return ((const unsigned char*)m)[idx] ? 1.f : 0.f;
}

// ---------------- fused: pack A + per-vocab stats ----------------
__global__ __launch_bounds__(256)
void k_pack_stats(const float* __restrict__ feat, ushort* __restrict__ A,
                  float* __restrict__ fsum, float* __restrict__ fsq){
  int v = blockIdx.x*4 + (threadIdx.x >> 6);
  int ln = threadIdx.x & 63;
  if (v >= 30080) return;
  float vals[8] = {0.f,0.f,0.f,0.f,0.f,0.f,0.f,0.f};
  if (v < 30000 && ln < 38){
    const float* fr = &feat[(size_t)v*300];
    if (ln < 37){
      float4 a = *(const float4*)&fr[ln*8];
      float4 b = *(const float4*)&fr[ln*8 + 4];
      vals[0]=a.x; vals[1]=a.y; vals[2]=a.z; vals[3]=a.w;
      vals[4]=b.x; vals[5]=b.y; vals[6]=b.z; vals[7]=b.w;
    } else {
      float4 a = *(const float4*)&fr[296];
      vals[0]=a.x; vals[1]=a.y; vals[2]=a.z; vals[3]=a.w;
    }
  }
  if (ln < 40){
    union { ushort u[8]; bf16x8 v8; } pk;
    #pragma unroll
    for (int i = 0; i < 8; ++i) pk.u[i] = f2bf(vals[i]);
    *(bf16x8*)&A[(size_t)v*320 + ln*8] = pk.v8;
  }
  float s = 0.f, q = 0.f;
  #pragma unroll
  for (int i = 0; i < 8; ++i){ s += vals[i]; q += vals[i]*vals[i]; }
  for (int o = 32; o > 0; o >>= 1){ s += __shfl_xor(s, o); q += __shfl_xor(q, o); }
  if (ln == 0 && v < 30000){ fsum[v] = s; fsq[v] = q; }
}

// ---------------- P0b ----------------
__global__ __launch_bounds__(256)
void k_gw1_part(const float* __restrict__ w1, const float* __restrict__ g,
                const float* __restrict__ bln, float* __restrict__ pgw, float* __restrict__ pcv){
  int j = blockIdx.x*256 + threadIdx.x;
  int ic = blockIdx.y;
  if (j >= 600) return;
  float a = 0.f, c = 0.f;
  for (int i = ic*75; i < ic*75 + 75; ++i){
    float w = w1[i*600 + j];
    a += g[i]*w; c += bln[i]*w;
  }
  pgw[ic*600 + j] = a; pcv[ic*600 + j] = c;
}

__global__ __launch_bounds__(256)
void k_gw_reduce(const float* __restrict__ pgw, const float* __restrict__ pcv,
                 const float* __restrict__ b1, float* __restrict__ gw_g, float* __restrict__ c_g){
  int j = blockIdx.x*256 + threadIdx.x;
  if (j >= 600) return;
  float a = 0.f, c = 0.f;
  for (int k = 0; k < 8; ++k){ a += pgw[k*600 + j]; c += pcv[k*600 + j]; }
  gw_g[j] = a; c_g[j] = c + b1[j];
}

// ---------------- pack B^T ----------------
__global__ __launch_bounds__(256)
void k_pack_b(const float* __restrict__ w1, const float* __restrict__ g, ushort* __restrict__ BT){
  int id = blockIdx.x*256 + threadIdx.x;
  if (id >= 640*320) return;
  int n = id % 640, k = id / 640;
  float val = (k < 300 && n < 600) ? g[k]*w1[k*600 + n] : 0.f;
  BT[(size_t)n*320 + k] = f2bf(val);
}

// ---------------- P1: U GEMM (MFMA) ----------------
__global__ __launch_bounds__(256)
void k_ugemm_mfma(const ushort* __restrict__ A, const ushort* __restrict__ BT,
                  __hip_bfloat16* __restrict__ U){
  __shared__ ushort As[128][40];
  __shared__ ushort Bs[128][40];
  int tid = threadIdx.x;
  int bm = blockIdx.x * 128, bn = blockIdx.y * 128;
  int wid = tid >> 6, lane = tid & 63;
  int wr = wid >> 1, wc = wid & 1;
  int lr = lane & 15, lk = lane >> 4;
  f32x4 acc[4][4] = {};
  for (int k0 = 0; k0 < 320; k0 += 32){
    #pragma unroll
    for (int j = 0; j < 2; ++j){
      int idx = tid + 256*j;
      int row = idx >> 2, ko = (idx & 3)*8;
      *(bf16x8*)&As[row][ko] = *(const bf16x8*)&A[(size_t)(bm+row)*320 + k0 + ko];
      *(bf16x8*)&Bs[row][ko] = *(const bf16x8*)&BT[(size_t)(bn+row)*320 + k0 + ko];
    }
    __syncthreads();
    bf16x8 af[4], bfr[4];
    #pragma unroll
    for (int f = 0; f < 4; ++f){
      af[f]  = *(const bf16x8*)&As[wr*64 + f*16 + lr][lk*8];
      bfr[f] = *(const bf16x8*)&Bs[wc*64 + f*16 + lr][lk*8];
    }
    #pragma unroll
    for (int i = 0; i < 4; ++i)
      #pragma unroll
      for (int j = 0; j < 4; ++j)
        acc[i][j] = __builtin_amdgcn_mfma_f32_16x16x32_bf16(af[i], bfr[j], acc[i][j], 0, 0, 0);
    __syncthreads();
  }
  #pragma unroll
  for (int i = 0; i < 4; ++i){
    #pragma unroll
    for (int j = 0; j < 4; ++j){
      #pragma unroll
      for (int r = 0; r < 4; ++r){
        int row = bm + wr*64 + i*16 + lk*4 + r;
        int col = bn + wc*64 + j*16 + lr;
        if (row < 30000 && col < 600)
          U[(size_t)row*600 + col] = __float2bfloat16(acc[i][j][r]);
      }
    }
  }
}

// ---------------- ivar precompute ----------------
__global__ __launch_bounds__(256)
void k_ivar(const float* __restrict__ logvar, float* __restrict__ ivar){
  int i = blockIdx.x*256 + threadIdx.x;
  if (i < 30000*64) ivar[i] = __builtin_amdgcn_exp2f(-1.44269504f*logvar[i]);
}

// ---------------- S1a: mu gather+stage ----------------
__global__ __launch_bounds__(256)
void k_mu_stage(const int* __restrict__ ids_a, const void* __restrict__ mask_a,
                const int* __restrict__ ids_b, const void* __restrict__ mask_b,
                const float* __restrict__ mu_tab, const float* __restrict__ pos_mu,
                const float* __restrict__ alpha_tab, const float* __restrict__ pos_alpha,
                ushort* __restrict__ MuS, float* __restrict__ cent_p,
                float* __restrict__ msum_p, float* __restrict__ al_g){
  int blk = blockIdx.x;
  int bb = blk >> 3, qr = blk & 7;
  int b = bb & 127;
  const int* ids = (bb < 128) ? ids_a : ids_b;
  const void* msk = (bb < 128) ? mask_a : mask_b;
  int t = threadIdx.x;
  int grp = t >> 4, sub = t & 15;
  __shared__ int mmode_s;
  __shared__ float gpart[16][64];
  __shared__ float mf_s[64];
  __shared__ float red[256];
  if (t == 0) mmode_s = mask_mode((const unsigned char*)msk);
  __syncthreads();
  int mmode = mmode_s;
  float cp0=0.f, cp1=0.f, cp2=0.f, cp3=0.f;
  #pragma unroll
  for (int k = 0; k < 4; ++k){
    int sl = grp*4 + k;
    int s  = qr*64 + sl;
    int id = ids[b*512 + s];
    float mf = mask_read(msk, b*512 + s, mmode);
    float4 m4 = *(const float4*)&mu_tab[(size_t)id*64 + sub*4];
    float4 p4 = *(const float4*)&pos_mu[s*64 + sub*4];
    float v0 = m4.x+p4.x, v1 = m4.y+p4.y, v2 = m4.z+p4.z, v3 = m4.w+p4.w;
    ushort4 st; st.x = f2bf(v0); st.y = f2bf(v1); st.z = f2bf(v2); st.w = f2bf(v3);
    *(ushort4*)&MuS[((size_t)bb*512 + s)*64 + sub*4] = st;
    cp0 += mf*v0; cp1 += mf*v1; cp2 += mf*v2; cp3 += mf*v3;
    if (sub == 0){
      mf_s[sl] = mf;
      float pa = pos_alpha[s];
      float sg = __builtin_amdgcn_rcpf(1.f + __builtin_amdgcn_exp2f(-1.44269504f*pa));
      al_g[bb*512 + s] = alpha_tab[id] * sg * mf;
    }
  }
  gpart[grp][sub*4+0] = cp0; gpart[grp][sub*4+1] = cp1;
  gpart[grp][sub*4+2] = cp2; gpart[grp][sub*4+3] = cp3;
  __syncthreads();
  if (t < 64){
    float c = 0.f;
    #pragma unroll
    for (int g = 0; g < 16; ++g) c += gpart[g][t];
    cent_p[(size_t)blk*64 + t] = c;
  }
  float ms = blk_sum256(red, t, (t < 64) ? mf_s[t] : 0.f);
  if (t == 0) msum_p[blk] = ms;
}

// ---------------- S1b ----------------
__global__ __launch_bounds__(64)
void k_cent_reduce(const float* __restrict__ cent_p, const float* __restrict__ msum_p,
                   float* __restrict__ cent){
  int bb = blockIdx.x, d = threadIdx.x;
  float c = 0.f, ms = 0.f;
  #pragma unroll
  for (int q = 0; q < 8; ++q){
    c  += cent_p[(size_t)(bb*8+q)*64 + d];
    ms += msum_p[bb*8+q];
  }
  cent[bb*64 + d] = c / fmaxf(ms, 1.f);
}

// ---------------- S1c ----------------
__global__ __launch_bounds__(256)
void k_wrender(const int* __restrict__ ids_a, const int* __restrict__ ids_b,
               const float* __restrict__ ivar_tab, const ushort* __restrict__ MuS,
               const float* __restrict__ cent, const float* __restrict__ al_g,
               const float* __restrict__ log_tau, const float* __restrict__ feat_tab,
               float* __restrict__ wsum_p, float* __restrict__ sgs_p){
  int blk = blockIdx.x;
  int bb = blk >> 3, qr = blk & 7;
  int b = bb & 127;
  const int* ids = (bb < 128) ? ids_a : ids_b;
  int t = threadIdx.x;
  int grp = t >> 4, sub = t & 15;
  __shared__ float wl[64];
  __shared__ int   idl[64];
  __shared__ float pacc[4][304];
  __shared__ float red[256];
  float itau = __builtin_amdgcn_exp2f(-1.44269504f*log_tau[0]);
  float c0 = cent[bb*64 + sub*4+0], c1 = cent[bb*64 + sub*4+1];
  float c2 = cent[bb*64 + sub*4+2], c3 = cent[bb*64 + sub*4+3];
  #pragma unroll
  for (int k = 0; k < 4; ++k){
    int sl = grp*4 + k, s = qr*64 + sl;
    int id = ids[b*512 + s];
    float4 iv = *(const float4*)&ivar_tab[(size_t)id*64 + sub*4];
    ushort4 mu = *(const ushort4*)&MuS[((size_t)bb*512 + s)*64 + sub*4];
    float d0 = bf2f(mu.x)-c0, d1 = bf2f(mu.y)-c1, d2v = bf2f(mu.z)-c2, d3 = bf2f(mu.w)-c3;
    float val = d0*d0*iv.x + d1*d1*iv.y + d2v*d2v*iv.z + d3*d3*iv.w;
    val += __shfl_xor(val, 1); val += __shfl_xor(val, 2);
    val += __shfl_xor(val, 4); val += __shfl_xor(val, 8);
    if (sub == 0){
      idl[sl] = id;
      float K = __builtin_amdgcn_exp2f(-0.72134752f * val * itau);
      wl[sl] = al_g[bb*512 + s] * K;
    }
  }
  __syncthreads();
  float ws = blk_sum256(red, t, (t < 64) ? wl[t] : 0.f);
  if (t == 0) wsum_p[blk] = ws;
  int wv = t >> 6, ln = t & 63;
  float a10=0.f,a11=0.f,a12=0.f,a13=0.f, a20=0.f,a21=0.f,a22=0.f,a23=0.f;
  for (int k = 0; k < 16; ++k){
    int sl = (wv << 4) | k;
    float w = wl[sl];
    const float* fr = &feat_tab[(size_t)idl[sl]*300];
    float4 v1 = *(const float4*)&fr[ln*4];
    a10 += w*v1.x; a11 += w*v1.y; a12 += w*v1.z; a13 += w*v1.w;
    if (ln < 11){
      float4 v2 = *(const float4*)&fr[256 + ln*4];
      a20 += w*v2.x; a21 += w*v2.y; a22 += w*v2.z; a23 += w*v2.w;
    }
  }
  pacc[wv][ln*4+0]=a10; pacc[wv][ln*4+1]=a11; pacc[wv][ln*4+2]=a12; pacc[wv][ln*4+3]=a13;
  if (ln < 11){
    pacc[wv][256+ln*4+0]=a20; pacc[wv][256+ln*4+1]=a21;
    pacc[wv][256+ln*4+2]=a22; pacc[wv][256+ln*4+3]=a23;
  }
  __syncthreads();
  for (int j = t; j < 300; j += 256)
    sgs_p[(size_t)blk*304 + j] = pacc[0][j] + pacc[1][j] + pacc[2][j] + pacc[3][j];
}

// ---------------- S1d ----------------
__global__ __launch_bounds__(512)
void k_stage1c(const int* __restrict__ ids_a, const void* __restrict__ mask_a,
               const int* __restrict__ ids_b, const void* __restrict__ mask_b,
               const ushort* __restrict__ MuS, const float* __restrict__ sgs_p,
               const float* __restrict__ wsum_p,
               const float* __restrict__ wq, const float* __restrict__ bq,
               const float* __restrict__ wk, const float* __restrict__ bk,
               float* __restrict__ sgs_g, float* __restrict__ ssum_g, float* __restrict__ ssq_g,
               float* __restrict__ wgt_g)
{
  int bb = blockIdx.x;
  const void* msk = (bb < 128) ? mask_a : mask_b;
  int b = bb & 127;
  int t = threadIdx.x;
  __shared__ float mf_l[512], w_l[512], red[512];
  __shared__ float q_l[64], qk_l[64];
  __shared__ float sgs_l[304];
  __shared__ float bkq_s;
  __shared__ int mmode;
  if (t == 0) mmode = mask_mode((const unsigned char*)msk);
  __syncthreads();
  mf_l[t] = mask_read(msk, b*512 + t, mmode);

  float wsum = 0.f;
  #pragma unroll
  for (int q = 0; q < 8; ++q) wsum += wsum_p[bb*8 + q];
  wsum = fmaxf(wsum, 1e-8f);
  if (t < 300){
    float sa = 0.f;
    #pragma unroll
    for (int q = 0; q < 8; ++q) sa += sgs_p[(size_t)(bb*8+q)*304 + t];
    float sv = sa / wsum;
    sgs_l[t] = sv;
    sgs_g[bb*300 + t] = sv;
  }
  __syncthreads();
  float ssum = blk_sum512(red, t, (t < 300) ? sgs_l[t] : 0.f);
  float ssq  = blk_sum512(red, t, (t < 300) ? sgs_l[t]*sgs_l[t] : 0.f);
  if (t == 0){ ssum_g[bb] = ssum; ssq_g[bb] = ssq; }

  if (t < 64){
    float q = bq[t];
    for (int i = 0; i < 300; ++i) q += sgs_l[i]*wq[i*64 + t];
    q_l[t] = q;
  }
  __syncthreads();
  if (t < 64){
    float a = 0.f;
    for (int j = 0; j < 64; ++j) a += wk[t*64 + j]*q_l[j];
    qk_l[t] = a;
  }
  if (t == 0){
    float s = 0.f;
    for (int j = 0; j < 64; ++j) s += bk[j]*q_l[j];
    bkq_s = s;
  }
  __syncthreads();

  int grp = t >> 4, sub = t & 15;
  {
    float q0 = qk_l[sub*4+0], q1 = qk_l[sub*4+1], q2 = qk_l[sub*4+2], q3 = qk_l[sub*4+3];
    for (int k = 0; k < 16; ++k){
      int s = (grp << 4) | k;
      ushort4 mu = *(const ushort4*)&MuS[((size_t)bb*512 + s)*64 + sub*4];
      float val = bf2f(mu.x)*q0 + bf2f(mu.y)*q1 + bf2f(mu.z)*q2 + bf2f(mu.w)*q3;
      val += __shfl_xor(val, 1); val += __shfl_xor(val, 2);
      val += __shfl_xor(val, 4); val += __shfl_xor(val, 8);
      if (sub == 0){
        float sv = (val + bkq_s) * 0.125f;
        w_l[s] = (mf_l[s] != 0.f) ? sv : -1e30f;
      }
    }
  }
  __syncthreads();

  float mx = blk_max512(red, t, w_l[t]);
  float ex = __expf(w_l[t] - mx);
  float Z  = blk_sum512(red, t, ex);
  wgt_g[bb*512 + t] = ex / Z;
}

// ---------------- k_vgemm2 ----------------
__global__ __launch_bounds__(256)
void k_vgemm2(const float* __restrict__ sgs, const float* __restrict__ w1,
              const float* __restrict__ ln1g, float* __restrict__ V_g){
  __shared__ float As[32][33], Bs[32][33];
  int t = threadIdx.x;
  int bm = blockIdx.x*32, bn = blockIdx.y*32;
  int tx = t & 15, ty = t >> 4;
  float a00=0.f,a01=0.f,a10=0.f,a11=0.f;
  for (int k0 = 0; k0 < 300; k0 += 32){
    #pragma unroll
    for (int i = 0; i < 4; ++i){
      int idx = t + i*256;
      int kk = idx & 31, m = idx >> 5;
      int kg = k0 + kk;
      As[kk][m] = (kg < 300) ? sgs[(size_t)(bm+m)*300 + kg] : 0.f;
    }
    #pragma unroll
    for (int i = 0; i < 4; ++i){
      int idx = t + i*256;
      int n = idx & 31, kk = idx >> 5;
      int kg = k0 + kk, cg = bn + n;
      Bs[kk][n] = (kg < 300 && cg < 600) ? ln1g[300 + kg]*w1[(size_t)(300 + kg)*600 + cg] : 0.f;
    }
    __syncthreads();
    #pragma unroll
    for (int kk = 0; kk < 32; ++kk){
      float x0 = As[kk][ty*2], x1 = As[kk][ty*2+1];
      float y0 = Bs[kk][tx*2], y1 = Bs[kk][tx*2+1];
      a00 += x0*y0; a01 += x0*y1; a10 += x1*y0; a11 += x1*y1;
    }
    __syncthreads();
  }
  int r0 = bm + ty*2, c0 = bn + tx*2;
  #pragma unroll
  for (int i = 0; i < 2; ++i){
    #pragma unroll
    for (int j = 0; j < 2; ++j){
      int r = r0 + i, c = c0 + j;
      if (c < 600) V_g[(size_t)r*600 + c] = (i==0 ? (j==0?a00:a01) : (j==0?a10:a11));
    }
  }
}

// ---------------- K2: hbar + Fbar eighth-split ----------------
__global__ __launch_bounds__(256)
void k_hbar_fbar(const int* __restrict__ ids_a, const int* __restrict__ ids_b,
                 const __hip_bfloat16* __restrict__ U, const float* __restrict__ feat_tab,
                 const float* __restrict__ fsum, const float* __restrict__ fsq,
                 const float* __restrict__ ssum_g, const float* __restrict__ ssq_g,
                 const float* __restrict__ V_g, const float* __restrict__ gw_g,
                 const float* __restrict__ c_g, const float* __restrict__ wgt_g,
                 float* __restrict__ hbar_p, float* __restrict__ Fbar_p)
{
  int blk = blockIdx.x;
  int bb = blk >> 3, qr = blk & 7;
  int b = bb & 127;
  const int* ids = (bb < 128) ? ids_a : ids_b;
  int t = threadIdx.x;
  __shared__ int id_l[64];
  __shared__ float m_l[64], rs_l[64], wg_l[64];
  __shared__ float hp[4][600];
  __shared__ float fp[4][304];
  float ss = ssum_g[bb], sq = ssq_g[bb];
  if (t < 64){
    int s = qr*64 + t;
    int id = ids[b*512 + s];
    id_l[t] = id;
    float m = (fsum[id] + ss) * (1.f/600.f);
    float var = (fsq[id] + sq) * (1.f/600.f) - m*m;
    m_l[t] = m;
    rs_l[t] = 1.f / sqrtf(var + 1e-5f);
    wg_l[t] = wgt_g[bb*512 + s];
  }
  __syncthreads();

  int wv = t >> 6, ln = t & 63;
  float Vp[8], gwp[8], cp[8], Vs[8], gws[8], cs[8];
  #pragma unroll
  for (int r = 0; r < 8; ++r){
    int j = ln*8 + r;
    Vp[r] = V_g[bb*600 + j]; gwp[r] = gw_g[j]; cp[r] = c_g[j];
    Vs[r] = 0.f; gws[r] = 0.f; cs[r] = 0.f;
  }
  if (ln < 11){
    #pragma unroll
    for (int r = 0; r < 8; ++r){
      int j = 512 + ln*8 + r;
      Vs[r] = V_g[bb*600 + j]; gws[r] = gw_g[j]; cs[r] = c_g[j];
    }
  }
  float h1[8] = {}, h2[8] = {};
  float f10=0.f,f11=0.f,f12=0.f,f13=0.f, f20=0.f,f21=0.f,f22=0.f,f23=0.f;

  for (int k = 0; k < 16; ++k){
    int s = (wv << 4) | k;
    int id = id_l[s];
    float w = wg_l[s], m = m_l[s], rs = rs_l[s];
    const __hip_bfloat16* ur = &U[(size_t)id*600];
    const float* fr = &feat_tab[(size_t)id*300];
    bf16x8 u8 = *(const bf16x8*)&ur[ln*8];
    float4 fv = *(const float4*)&fr[ln*4];
    #pragma unroll
    for (int r = 0; r < 8; ++r){
      float u = bf2f((ushort)u8[r]);
      float a = (u + Vp[r] - m*gwp[r])*rs + cp[r];
      h1[r] += w*gelu_fast(a);
    }
    f10 += w*fv.x; f11 += w*fv.y; f12 += w*fv.z; f13 += w*fv.w;
    if (ln < 11){
      bf16x8 u8b = *(const bf16x8*)&ur[512 + ln*8];
      float4 fvb = *(const float4*)&fr[256 + ln*4];
      #pragma unroll
      for (int r = 0; r < 8; ++r){
        float u = bf2f((ushort)u8b[r]);
        float a = (u + Vs[r] - m*gws[r])*rs + cs[r];
        h2[r] += w*gelu_fast(a);
      }
      f20 += w*fvb.x; f21 += w*fvb.y; f22 += w*fvb.z; f23 += w*fvb.w;
    }
  }
  #pragma unroll
  for (int r = 0; r < 8; ++r) hp[wv][ln*8 + r] = h1[r];
  if (ln < 11){
    #pragma unroll
    for (int r = 0; r < 8; ++r) hp[wv][512 + ln*8 + r] = h2[r];
  }
  fp[wv][ln*4+0]=f10; fp[wv][ln*4+1]=f11; fp[wv][ln*4+2]=f12; fp[wv][ln*4+3]=f13;
  if (ln < 11){
    fp[wv][256+ln*4+0]=f20; fp[wv][256+ln*4+1]=f21;
    fp[wv][256+ln*4+2]=f22; fp[wv][256+ln*4+3]=f23;
  }
  __syncthreads();
  size_t hbase = ((size_t)qr*256 + bb)*608;
  for (int j = t; j < 600; j += 256){
    hbar_p[hbase + j] = hp[0][j] + hp[1][j] + hp[2][j] + hp[3][j];
  }
  if (t < 8) hbar_p[hbase + 600 + t] = 0.f;
  size_t fbase = ((size_t)qr*256 + bb)*300;
  for (int j = t; j < 300; j += 256){
    Fbar_p[fbase + j] = fp[0][j] + fp[1][j] + fp[2][j] + fp[3][j];
  }
}

// ---------------- k_hreduce ----------------
__global__ __launch_bounds__(256)
void k_hreduce(const float* __restrict__ hbar_p, const float* __restrict__ Fbar_p,
               float* __restrict__ hbar_s, float* __restrict__ Fbar_s){
  int i = blockIdx.x*256 + threadIdx.x;
  const size_t Q  = (size_t)256*608;
  const size_t QF = (size_t)256*300;
  if (i < 256*608){
    float s0 = hbar_p[i]       + hbar_p[Q + i];
    float s1 = hbar_p[2*Q + i] + hbar_p[3*Q + i];
    float s2 = hbar_p[4*Q + i] + hbar_p[5*Q + i];
    float s3 = hbar_p[6*Q + i] + hbar_p[7*Q + i];
    hbar_s[i] = (s0 + s1) + (s2 + s3);
  }
  if (i < 256*300){
    float s0 = Fbar_p[i]        + Fbar_p[QF + i];
    float s1 = Fbar_p[2*QF + i] + Fbar_p[3*QF + i];
    float s2 = Fbar_p[4*QF + i] + Fbar_p[5*QF + i];
    float s3 = Fbar_p[6*QF + i] + Fbar_p[7*QF + i];
    Fbar_s[i] = (s0 + s1) + (s2 + s3);
  }
}

// ============ final chain: split-K tiled fp32 GEMMs ============
// K=608 split into 4 chunks of 160/160/160/128 via blockIdx.z.

// att partial: att_p[kc][256][300] = hbar_s[:, kchunk] @ w2[kchunk, :]
__global__ __launch_bounds__(256)
void k_att_sk(const float* __restrict__ hbar_s, const float* __restrict__ w2,
              float* __restrict__ att_p){
  __shared__ float As[32][33], Bs[32][33];
  int t = threadIdx.x;
  int bm = blockIdx.x*32, bn = blockIdx.y*32, kc = blockIdx.z;
  int tx = t & 15, ty = t >> 4;
  int kbeg = kc*160, kend = (kc == 3) ? 608 : kbeg + 160;
  float a00=0.f,a01=0.f,a10=0.f,a11=0.f;
  for (int k0 = kbeg; k0 < kend; k0 += 32){
    #pragma unroll
    for (int i = 0; i < 4; ++i){
      int idx = t + i*256;
      int kk = idx & 31, m = idx >> 5;
      As[kk][m] = hbar_s[(size_t)(bm+m)*608 + k0 + kk];
    }
    #pragma unroll
    for (int i = 0; i < 4; ++i){
      int idx = t + i*256;
      int n = idx & 31, kk = idx >> 5;
      int kg = k0 + kk, cg = bn + n;
      Bs[kk][n] = (kg < 600 && cg < 300) ? w2[(size_t)kg*300 + cg] : 0.f;
    }
    __syncthreads();
    #pragma unroll
    for (int kk = 0; kk < 32; ++kk){
      float x0 = As[kk][ty*2], x1 = As[kk][ty*2+1];
      float y0 = Bs[kk][tx*2], y1 = Bs[kk][tx*2+1];
      a00 += x0*y0; a01 += x0*y1; a10 += x1*y0; a11 += x1*y1;
    }
    __syncthreads();
  }
  float* outp = att_p + (size_t)kc*256*300;
  int r0 = bm + ty*2, c0 = bn + tx*2;
  #pragma unroll
  for (int i = 0; i < 2; ++i){
    #pragma unroll
    for (int j = 0; j < 2; ++j){
      int r = r0 + i, c = c0 + j;
      if (c < 300)
        outp[(size_t)r*300 + c] = (i==0 ? (j==0?a00:a01) : (j==0?a10:a11));
    }
  }
}

__global__ __launch_bounds__(256)
void k_att_red(const float* __restrict__ att_p, const float* __restrict__ Fbar_s,
               const float* __restrict__ b2, float* __restrict__ att){
  int i = blockIdx.x*256 + threadIdx.x;
  if (i >= 256*300) return;
  const size_t Q = (size_t)256*300;
  float s = (att_p[i] + att_p[Q+i]) + (att_p[2*Q+i] + att_p[3*Q+i]);
  att[i] = s + b2[i % 300] + Fbar_s[i];
}

__global__ __launch_bounds__(64)
void k_lnstats(const float* __restrict__ att, const float* __restrict__ ssum_g,
               const float* __restrict__ ssq_g, float* __restrict__ m_g, float* __restrict__ rs_g){
  int bb = blockIdx.x, lane = threadIdx.x;
  float s = 0.f, q = 0.f;
  for (int i = lane; i < 300; i += 64){
    float v = att[(size_t)bb*300 + i];
    s += v; q += v*v;
  }
  for (int o = 32; o > 0; o >>= 1){ s += __shfl_xor(s, o); q += __shfl_xor(q, o); }
  if (lane == 0){
    float m = (ssum_g[bb] + s) * (1.f/600.f);
    float var = (ssq_g[bb] + q) * (1.f/600.f) - m*m;
    m_g[bb] = m;
    rs_g[bb] = 1.f / sqrtf(var + 1e-5f);
  }
}

// mlp1 partial: g2_p[kc][256][608] = LN2(x)[:, kchunk] @ aw1[kchunk, :]
__global__ __launch_bounds__(256)
void k_mlp1_sk(const float* __restrict__ sgs, const float* __restrict__ att,
               const float* __restrict__ m_g, const float* __restrict__ rs_g,
               const float* __restrict__ ln2g, const float* __restrict__ ln2b,
               const float* __restrict__ aw1, float* __restrict__ g2_p){
  __shared__ float As[32][33], Bs[32][33];
  int t = threadIdx.x;
  int bm = blockIdx.x*32, bn = blockIdx.y*32, kc = blockIdx.z;
  int tx = t & 15, ty = t >> 4;
  int kbeg = kc*160, kend = (kc == 3) ? 608 : kbeg + 160;
  float a00=0.f,a01=0.f,a10=0.f,a11=0.f;
  for (int k0 = kbeg; k0 < kend; k0 += 32){
    #pragma unroll
    for (int i = 0; i < 4; ++i){
      int idx = t + i*256;
      int kk = idx & 31, m = idx >> 5;
      int kg = k0 + kk, row = bm + m;
      float t2 = 0.f;
      if (kg < 600){
        float x = (kg < 300) ? sgs[(size_t)row*300 + kg] : att[(size_t)row*300 + kg - 300];
        t2 = (x - m_g[row])*rs_g[row]*ln2g[kg] + ln2b[kg];
      }
      As[kk][m] = t2;
    }
    #pragma unroll
    for (int i = 0; i < 4; ++i){
      int idx = t + i*256;
      int n = idx & 31, kk = idx >> 5;
      int kg = k0 + kk, cg = bn + n;
      Bs[kk][n] = (kg < 600 && cg < 600) ? aw1[(size_t)kg*600 + cg] : 0.f;
    }
    __syncthreads();
    #pragma unroll
    for (int kk = 0; kk < 32; ++kk){
      float x0 = As[kk][ty*2], x1 = As[kk][ty*2+1];
      float y0 = Bs[kk][tx*2], y1 = Bs[kk][tx*2+1];
      a00 += x0*y0; a01 += x0*y1; a10 += x1*y0; a11 += x1*y1;
    }
    __syncthreads();
  }
  float* outp = g2_p + (size_t)kc*256*608;
  int r0 = bm + ty*2, c0 = bn + tx*2;
  #pragma unroll
  for (int i = 0; i < 2; ++i){
    #pragma unroll
    for (int j = 0; j < 2; ++j){
      int r = r0 + i, c = c0 + j;
      outp[(size_t)r*608 + c] = (i==0 ? (j==0?a00:a01) : (j==0?a10:a11));
    }
  }
}

__global__ __launch_bounds__(256)
void k_mlp1_red(const float* __restrict__ g2_p, const float* __restrict__ ab1,
                float* __restrict__ g2){
  int i = blockIdx.x*256 + threadIdx.x;
  if (i >= 256*608) return;
  const size_t Q = (size_t)256*608;
  int c = i % 608;
  float s = (g2_p[i] + g2_p[Q+i]) + (g2_p[2*Q+i] + g2_p[3*Q+i]);
  g2[i] = (c < 600) ? geluf(s + ab1[c]) : 0.f;
}

// mlp2 partial: fin_p[kc][256][300] = g2[:, kchunk] @ aw2[kchunk, :]
__global__ __launch_bounds__(256)
void k_mlp2_sk(const float* __restrict__ g2, const float* __restrict__ aw2,
               float* __restrict__ fin_p){
  __shared__ float As[32][33], Bs[32][33];
  int t = threadIdx.x;
  int bm = blockIdx.x*32, bn = blockIdx.y*32, kc = blockIdx.z;
  int tx = t & 15, ty = t >> 4;
  int kbeg = kc*160, kend = (kc == 3) ? 608 : kbeg + 160;
  float a00=0.f,a01=0.f,a10=0.f,a11=0.f;
  for (int k0 = kbeg; k0 < kend; k0 += 32){
    #pragma unroll
    for (int i = 0; i < 4; ++i){
      int idx = t + i*256;
      int kk = idx & 31, m = idx >> 5;
      As[kk][m] = g2[(size_t)(bm+m)*608 + k0 + kk];
    }
    #pragma unroll
    for (int i = 0; i < 4; ++i){
      int idx = t + i*256;
      int n = idx & 31, kk = idx >> 5;
      int kg = k0 + kk, cg = bn + n;
      Bs[kk][n] = (kg < 600 && cg < 300) ? aw2[(size_t)kg*300 + cg] : 0.f;
    }
    __syncthreads();
    #pragma unroll
    for (int kk = 0; kk < 32; ++kk){
      float x0 = As[kk][ty*2], x1 = As[kk][ty*2+1];
      float y0 = Bs[kk][tx*2], y1 = Bs[kk][tx*2+1];
      a00 += x0*y0; a01 += x0*y1; a10 += x1*y0; a11 += x1*y1;
    }
    __syncthreads();
  }
  float* outp = fin_p + (size_t)kc*256*300;
  int r0 = bm + ty*2, c0 = bn + tx*2;
  #pragma unroll
  for (int i = 0; i < 2; ++i){
    #pragma unroll
    for (int j = 0; j < 2; ++j){
      int r = r0 + i, c = c0 + j;
      if (c < 300)
        outp[(size_t)r*300 + c] = (i==0 ? (j==0?a00:a01) : (j==0?a10:a11));
    }
  }
}

__global__ __launch_bounds__(256)
void k_mlp2_red(const float* __restrict__ fin_p, const float* __restrict__ sgs,
                const float* __restrict__ ab2, float* __restrict__ final_g){
  int i = blockIdx.x*256 + threadIdx.x;
  if (i >= 256*300) return;
  const size_t Q = (size_t)256*300;
  float s = (fin_p[i] + fin_p[Q+i]) + (fin_p[2*Q+i] + fin_p[3*Q+i]);
  final_g[i] = s + ab2[i % 300] + sgs[i];
}

__global__ __launch_bounds__(64)
void k_cos(const float* __restrict__ final_g, float* __restrict__ out){
  int b = blockIdx.x; int lane = threadIdx.x;
  const float* A  = final_g + b*300;
  const float* Bv = final_g + (128 + b)*300;
  float dot = 0.f, na = 0.f, nb = 0.f;
  for (int i = lane; i < 300; i += 64){
    float x = A[i], y = Bv[i];
    dot += x*y; na += x*x; nb += y*y;
  }
  for (int o = 32; o > 0; o >>= 1){
    dot += __shfl_xor(dot, o); na += __shfl_xor(na, o); nb += __shfl_xor(nb, o);
  }
  if (lane == 0){
    float den = fmaxf(sqrtf(na), 1e-8f) * fmaxf(sqrtf(nb), 1e-8f);
    out[b] = 5.f * dot / den;
  }
}

extern "C" void kernel_launch(void* const* d_in, const int* in_sizes, int n_in,
                              void* d_out, int out_size, void* d_ws, size_t ws_size,
                              hipStream_t stream) {
  const int* ids_a = (const int*)d_in[0];
  const void* mask_a = d_in[1];
  const int* ids_b = (const int*)d_in[2];
  const void* mask_b = d_in[3];
  const float* mu_tab     = (const float*)d_in[4];
  const float* logvar_tab = (const float*)d_in[5];
  const float* alpha_tab  = (const float*)d_in[6];
  const float* feat_tab   = (const float*)d_in[7];
  const float* log_tau    = (const float*)d_in[8];
  const float* pos_mu     = (const float*)d_in[9];
  const float* pos_alpha  = (const float*)d_in[10];
  const float* ln1g = (const float*)d_in[11];
  const float* ln1b = (const float*)d_in[12];
  const float* w1   = (const float*)d_in[13];
  const float* b1   = (const float*)d_in[14];
  const float* w2   = (const float*)d_in[15];
  const float* b2   = (const float*)d_in[16];
  const float* wq   = (const float*)d_in[17];
  const float* bq   = (const float*)d_in[18];
  const float* wk   = (const float*)d_in[19];
  const float* bk   = (const float*)d_in[20];
  const float* ln2g = (const float*)d_in[21];
  const float* ln2b = (const float*)d_in[22];
  const float* aw1  = (const float*)d_in[23];
  const float* ab1  = (const float*)d_in[24];
  const float* aw2  = (const float*)d_in[25];
  const float* ab2  = (const float*)d_in[26];
  float* out = (float*)d_out;

  char* wsb = (char*)d_ws;
  size_t off = 0;
  auto take = [&](size_t bytes) -> void* {
    void* p = wsb + off;
    off += (bytes + 255) & ~(size_t)255;
    return p;
  };

  const size_t uBytes  = (size_t)30000 * 600 * 2;   // 36.0 MB
  const size_t aBytes  = (size_t)30080 * 320 * 2;   // 19.3 MB (ivar aliases after ugemm)
  const size_t btBytes = (size_t)640 * 320 * 2;     // 0.41 MB
  const size_t muBytes = (size_t)256 * 512 * 64 * 2;// 16.8 MB (aliased post-stage1)
  const size_t need = uBytes + aBytes + btBytes + muBytes + ((size_t)8 << 20);
  if (ws_size < need) return;

  __hip_bfloat16* U = (__hip_bfloat16*)take(uBytes);
  char* abfRegion = (char*)take(aBytes);
  ushort* Abf = (ushort*)abfRegion;
  float* ivar_tab = (float*)abfRegion;               // alias (Abf dead after ugemm)
  ushort* BTbf = (ushort*)take(btBytes);
  char* muRegion = (char*)take(muBytes);
  ushort* MuS = (ushort*)muRegion;
  // alias post-stage1 buffers onto the (dead-after-stage1c) MuS region (16.8 MB):
  float* hbar_p = (float*)(muRegion + 0);                 // 8*256*608*4 = 4,980,736
  float* Fbar_p = (float*)(muRegion + 4980736);           // 8*256*300*4 = 2,457,600
  float* att_g  = (float*)(muRegion + 7438336);           //   307,200
  float* g2_g   = (float*)(muRegion + 7745536);           //   622,592
  float* final_g= (float*)(muRegion + 8368128);           //   307,200
  float* hbar_s = (float*)(muRegion + 8675328);           //   622,592
  float* Fbar_s = (float*)(muRegion + 9297920);           //   307,200
  float* att_p  = (float*)(muRegion + 9605120);           // 4*256*300*4 = 1,228,800
  float* g2_p   = (float*)(muRegion + 10833920);          // 4*256*608*4 = 2,490,368
  float* fin_p  = (float*)(muRegion + 13324288);          // 4*256*300*4 = 1,228,800 (ends 14.55MB)

  float* fsum   = (float*)take(30000*4);
  float* fsq    = (float*)take(30000*4);
  float* pgw    = (float*)take(8*600*4);
  float* pcv    = (float*)take(8*600*4);
  float* gw_g   = (float*)take(600*4);
  float* c_g    = (float*)take(600*4);
  float* sgs_g  = (float*)take(256*300*4);
  float* ssum_g = (float*)take(256*4);
  float* ssq_g  = (float*)take(256*4);
  float* V_g    = (float*)take(256*600*4);
  float* wgt_g  = (float*)take(256*512*4);
  float* m_g    = (float*)take(256*4);
  float* rs_g   = (float*)take(256*4);
  float* cent_p = (float*)take((size_t)2048*64*4);
  float* msum_p = (float*)take(2048*4);
  float* cent   = (float*)take(256*64*4);
  float* al_g   = (float*)take((size_t)256*512*4);
  float* wsum_p = (float*)take(2048*4);
  float* sgs_p  = (float*)take((size_t)2048*304*4);

  k_pack_stats<<<7520, 256, 0, stream>>>(feat_tab, Abf, fsum, fsq);
  k_pack_b<<<(640*320 + 255)/256, 256, 0, stream>>>(w1, ln1g, BTbf);
  k_gw1_part<<<dim3(3, 8), 256, 0, stream>>>(w1, ln1g, ln1b, pgw, pcv);
  k_gw_reduce<<<3, 256, 0, stream>>>(pgw, pcv, b1, gw_g, c_g);
  k_ugemm_mfma<<<dim3(235, 5), 256, 0, stream>>>(Abf, BTbf, U);
  k_ivar<<<7500, 256, 0, stream>>>(logvar_tab, ivar_tab);
  k_mu_stage<<<2048, 256, 0, stream>>>(ids_a, mask_a, ids_b, mask_b,
                                       mu_tab, pos_mu, alpha_tab, pos_alpha,
                                       MuS, cent_p, msum_p, al_g);
  k_cent_reduce<<<256, 64, 0, stream>>>(cent_p, msum_p, cent);
  k_wrender<<<2048, 256, 0, stream>>>(ids_a, ids_b, ivar_tab, MuS, cent, al_g,
                                      log_tau, feat_tab, wsum_p, sgs_p);
  k_stage1c<<<256, 512, 0, stream>>>(ids_a, mask_a, ids_b, mask_b,
                                     MuS, sgs_p, wsum_p,
                                     wq, bq, wk, bk,
                                     sgs_g, ssum_g, ssq_g, wgt_g);
  k_vgemm2<<<dim3(8, 19), 256, 0, stream>>>(sgs_g, w1, ln1g, V_g);
  k_hbar_fbar<<<2048, 256, 0, stream>>>(ids_a, ids_b, U, feat_tab, fsum, fsq,
                                        ssum_g, ssq_g, V_g, gw_g, c_g, wgt_g,
                                        hbar_p, Fbar_p);
  k_hreduce<<<608, 256, 0, stream>>>(hbar_p, Fbar_p, hbar_s, Fbar_s);
  k_att_sk<<<dim3(8, 10, 4), 256, 0, stream>>>(hbar_s, w2, att_p);
  k_att_red<<<300, 256, 0, stream>>>(att_p, Fbar_s, b2, att_g);
  k_lnstats<<<256, 64, 0, stream>>>(att_g, ssum_g, ssq_g, m_g, rs_g);
  k_mlp1_sk<<<dim3(8, 19, 4), 256, 0, stream>>>(sgs_g, att_g, m_g, rs_g, ln2g, ln2b, aw1, g2_p);
  k_mlp1_red<<<608, 256, 0, stream>>>(g2_p, ab1, g2_g);
  k_mlp2_sk<<<dim3(8, 10, 4), 256, 0, stream>>>(g2_g, aw2, fin_p);
  k_mlp2_red<<<300, 256, 0, stream>>>(fin_p, sgs_g, ab2, final_g);
  k_cos<<<128, 64, 0, stream>>>(final_g, out);
}

// Round 12
// 265.644 us; speedup vs baseline: 1.8913x; 1.0578x over previous
//
#include <hip/hip_runtime.h>
#include <hip/hip_bf16.h>
#include <cstdint>
#include <cstddef>

#define DEV __device__ __forceinline__

// problem constants: B=128, S=512, V=30000, DS=64, DF=300, H=600, BB=256

typedef __attribute__((ext_vector_type(8))) short bf16x8;
typedef __attribute__((ext_vector_type(4))) float f32x4;

DEV float geluf(float x){ return 0.5f*x*(1.f + erff(x*0.7071067811865475f)); }
DEV float gelu_fast(float x){
  float x2 = x*x;
  float e = __builtin_amdgcn_exp2f(x * __builtin_fmaf(x2, -0.102953f, -2.302218f));
  return x * __builtin_amdgcn_rcpf(1.f + e);
}

DEV float blk_sum512(float* red, int t, float v){
  red[t] = v; __syncthreads();
  for (int o = 256; o > 0; o >>= 1){ if (t < o) red[t] += red[t+o]; __syncthreads(); }
  float r = red[0]; __syncthreads(); return r;
}
DEV float blk_max512(float* red, int t, float v){
  red[t] = v; __syncthreads();
  for (int o = 256; o > 0; o >>= 1){ if (t < o) red[t] = fmaxf(red[t], red[t+o]); __syncthreads(); }
  float r = red[0]; __syncthreads(); return r;
}
DEV float blk_sum256(float* red, int t, float v){
  red[t] = v; __syncthreads();
  for (int o = 128; o > 0; o >>= 1){ if (t < o) red[t] += red[t+o]; __syncthreads(); }
  float r = red[0]; __syncthreads(); return r;
}

DEV ushort f2bf(float v){ __hip_bfloat16 h = __float2bfloat16(v); return *(ushort*)&h; }
DEV float bf2f(ushort u){ __hip_bfloat16 h; *(ushort*)&h = u; return __bfloat162float(h); }

// ---- mask dtype classifier ----
DEV int mask_mode(const unsigned char* m){
  bool big = false, off123 = false, off0one = false;
  #pragma unroll
  for (int i = 0; i < 16; ++i){
    unsigned char c = m[i];
    if (c > 1) big = true;
    if ((i & 3) != 0 && c != 0) off123 = true;
    if ((i & 3) == 0 && c == 1) off0one = true;
  }
  if (big) return 2;
  if (!off123 && off0one) return 1;
  return 0;
}
DEV float mask_read(const void* m, int idx, int mode){
  if (mode == 1) return ((const int*)m)[idx] ? 1.f : 0.f;
  if (mode == 2) return ((const unsigned short*)m)[idx] ? 1.f : 0.f;
  return ((const unsigned char*)m)[idx] ? 1.f : 0.f;
}

// ---------------- fused: pack A + per-vocab stats ----------------
__global__ __launch_bounds__(256)
void k_pack_stats(const float* __restrict__ feat, ushort* __restrict__ A,
                  float* __restrict__ fsum, float* __restrict__ fsq){
  int v = blockIdx.x*4 + (threadIdx.x >> 6);
  int ln = threadIdx.x & 63;
  if (v >= 30080) return;
  float vals[8] = {0.f,0.f,0.f,0.f,0.f,0.f,0.f,0.f};
  if (v < 30000 && ln < 38){
    const float* fr = &feat[(size_t)v*300];
    if (ln < 37){
      float4 a = *(const float4*)&fr[ln*8];
      float4 b = *(const float4*)&fr[ln*8 + 4];
      vals[0]=a.x; vals[1]=a.y; vals[2]=a.z; vals[3]=a.w;
      vals[4]=b.x; vals[5]=b.y; vals[6]=b.z; vals[7]=b.w;
    } else {
      float4 a = *(const float4*)&fr[296];
      vals[0]=a.x; vals[1]=a.y; vals[2]=a.z; vals[3]=a.w;
    }
  }
  if (ln < 40){
    union { ushort u[8]; bf16x8 v8; } pk;
    #pragma unroll
    for (int i = 0; i < 8; ++i) pk.u[i] = f2bf(vals[i]);
    *(bf16x8*)&A[(size_t)v*320 + ln*8] = pk.v8;
  }
  float s = 0.f, q = 0.f;
  #pragma unroll
  for (int i = 0; i < 8; ++i){ s += vals[i]; q += vals[i]*vals[i]; }
  for (int o = 32; o > 0; o >>= 1){ s += __shfl_xor(s, o); q += __shfl_xor(q, o); }
  if (ln == 0 && v < 30000){ fsum[v] = s; fsq[v] = q; }
}

// ---------------- P0b ----------------
__global__ __launch_bounds__(256)
void k_gw1_part(const float* __restrict__ w1, const float* __restrict__ g,
                const float* __restrict__ bln, float* __restrict__ pgw, float* __restrict__ pcv){
  int j = blockIdx.x*256 + threadIdx.x;
  int ic = blockIdx.y;
  if (j >= 600) return;
  float a = 0.f, c = 0.f;
  for (int i = ic*75; i < ic*75 + 75; ++i){
    float w = w1[i*600 + j];
    a += g[i]*w; c += bln[i]*w;
  }
  pgw[ic*600 + j] = a; pcv[ic*600 + j] = c;
}

__global__ __launch_bounds__(256)
void k_gw_reduce(const float* __restrict__ pgw, const float* __restrict__ pcv,
                 const float* __restrict__ b1, float* __restrict__ gw_g, float* __restrict__ c_g){
  int j = blockIdx.x*256 + threadIdx.x;
  if (j >= 600) return;
  float a = 0.f, c = 0.f;
  for (int k = 0; k < 8; ++k){ a += pgw[k*600 + j]; c += pcv[k*600 + j]; }
  gw_g[j] = a; c_g[j] = c + b1[j];
}

// ---------------- pack B^T ----------------
__global__ __launch_bounds__(256)
void k_pack_b(const float* __restrict__ w1, const float* __restrict__ g, ushort* __restrict__ BT){
  int id = blockIdx.x*256 + threadIdx.x;
  if (id >= 640*320) return;
  int n = id % 640, k = id / 640;
  float val = (k < 300 && n < 600) ? g[k]*w1[k*600 + n] : 0.f;
  BT[(size_t)n*320 + k] = f2bf(val);
}

// ---------------- P1: U GEMM (MFMA) ----------------
__global__ __launch_bounds__(256)
void k_ugemm_mfma(const ushort* __restrict__ A, const ushort* __restrict__ BT,
                  __hip_bfloat16* __restrict__ U){
  __shared__ ushort As[128][40];
  __shared__ ushort Bs[128][40];
  int tid = threadIdx.x;
  int bm = blockIdx.x * 128, bn = blockIdx.y * 128;
  int wid = tid >> 6, lane = tid & 63;
  int wr = wid >> 1, wc = wid & 1;
  int lr = lane & 15, lk = lane >> 4;
  f32x4 acc[4][4] = {};
  for (int k0 = 0; k0 < 320; k0 += 32){
    #pragma unroll
    for (int j = 0; j < 2; ++j){
      int idx = tid + 256*j;
      int row = idx >> 2, ko = (idx & 3)*8;
      *(bf16x8*)&As[row][ko] = *(const bf16x8*)&A[(size_t)(bm+row)*320 + k0 + ko];
      *(bf16x8*)&Bs[row][ko] = *(const bf16x8*)&BT[(size_t)(bn+row)*320 + k0 + ko];
    }
    __syncthreads();
    bf16x8 af[4], bfr[4];
    #pragma unroll
    for (int f = 0; f < 4; ++f){
      af[f]  = *(const bf16x8*)&As[wr*64 + f*16 + lr][lk*8];
      bfr[f] = *(const bf16x8*)&Bs[wc*64 + f*16 + lr][lk*8];
    }
    #pragma unroll
    for (int i = 0; i < 4; ++i)
      #pragma unroll
      for (int j = 0; j < 4; ++j)
        acc[i][j] = __builtin_amdgcn_mfma_f32_16x16x32_bf16(af[i], bfr[j], acc[i][j], 0, 0, 0);
    __syncthreads();
  }
  #pragma unroll
  for (int i = 0; i < 4; ++i){
    #pragma unroll
    for (int j = 0; j < 4; ++j){
      #pragma unroll
      for (int r = 0; r < 4; ++r){
        int row = bm + wr*64 + i*16 + lk*4 + r;
        int col = bn + wc*64 + j*16 + lr;
        if (row < 30000 && col < 600)
          U[(size_t)row*600 + col] = __float2bfloat16(acc[i][j][r]);
      }
    }
  }
}

// ---------------- S1a: mu gather+stage ----------------
__global__ __launch_bounds__(256)
void k_mu_stage(const int* __restrict__ ids_a, const void* __restrict__ mask_a,
                const int* __restrict__ ids_b, const void* __restrict__ mask_b,
                const float* __restrict__ mu_tab, const float* __restrict__ pos_mu,
                const float* __restrict__ alpha_tab, const float* __restrict__ pos_alpha,
                ushort* __restrict__ MuS, float* __restrict__ cent_p,
                float* __restrict__ msum_p, float* __restrict__ al_g){
  int blk = blockIdx.x;
  int bb = blk >> 3, qr = blk & 7;
  int b = bb & 127;
  const int* ids = (bb < 128) ? ids_a : ids_b;
  const void* msk = (bb < 128) ? mask_a : mask_b;
  int t = threadIdx.x;
  int grp = t >> 4, sub = t & 15;
  __shared__ int mmode_s;
  __shared__ float gpart[16][64];
  __shared__ float mf_s[64];
  __shared__ float red[256];
  if (t == 0) mmode_s = mask_mode((const unsigned char*)msk);
  __syncthreads();
  int mmode = mmode_s;
  float cp0=0.f, cp1=0.f, cp2=0.f, cp3=0.f;
  #pragma unroll
  for (int k = 0; k < 4; ++k){
    int sl = grp*4 + k;
    int s  = qr*64 + sl;
    int id = ids[b*512 + s];
    float mf = mask_read(msk, b*512 + s, mmode);
    float4 m4 = *(const float4*)&mu_tab[(size_t)id*64 + sub*4];
    float4 p4 = *(const float4*)&pos_mu[s*64 + sub*4];
    float v0 = m4.x+p4.x, v1 = m4.y+p4.y, v2 = m4.z+p4.z, v3 = m4.w+p4.w;
    ushort4 st; st.x = f2bf(v0); st.y = f2bf(v1); st.z = f2bf(v2); st.w = f2bf(v3);
    *(ushort4*)&MuS[((size_t)bb*512 + s)*64 + sub*4] = st;
    cp0 += mf*v0; cp1 += mf*v1; cp2 += mf*v2; cp3 += mf*v3;
    if (sub == 0){
      mf_s[sl] = mf;
      float pa = pos_alpha[s];
      float sg = __builtin_amdgcn_rcpf(1.f + __builtin_amdgcn_exp2f(-1.44269504f*pa));
      al_g[bb*512 + s] = alpha_tab[id] * sg * mf;
    }
  }
  gpart[grp][sub*4+0] = cp0; gpart[grp][sub*4+1] = cp1;
  gpart[grp][sub*4+2] = cp2; gpart[grp][sub*4+3] = cp3;
  __syncthreads();
  if (t < 64){
    float c = 0.f;
    #pragma unroll
    for (int g = 0; g < 16; ++g) c += gpart[g][t];
    cent_p[(size_t)blk*64 + t] = c;
  }
  float ms = blk_sum256(red, t, (t < 64) ? mf_s[t] : 0.f);
  if (t == 0) msum_p[blk] = ms;
}

// ---------------- S1b ----------------
__global__ __launch_bounds__(64)
void k_cent_reduce(const float* __restrict__ cent_p, const float* __restrict__ msum_p,
                   float* __restrict__ cent){
  int bb = blockIdx.x, d = threadIdx.x;
  float c = 0.f, ms = 0.f;
  #pragma unroll
  for (int q = 0; q < 8; ++q){
    c  += cent_p[(size_t)(bb*8+q)*64 + d];
    ms += msum_p[bb*8+q];
  }
  cent[bb*64 + d] = c / fmaxf(ms, 1.f);
}

// ---------------- S1c: w = alpha*K (inline exp2 ivar), render partials (bf16 Abf) ----------------
__global__ __launch_bounds__(256)
void k_wrender(const int* __restrict__ ids_a, const int* __restrict__ ids_b,
               const float* __restrict__ logvar_tab, const ushort* __restrict__ MuS,
               const float* __restrict__ cent, const float* __restrict__ al_g,
               const float* __restrict__ log_tau, const ushort* __restrict__ Abf,
               float* __restrict__ wsum_p, float* __restrict__ sgs_p){
  int blk = blockIdx.x;
  int bb = blk >> 3, qr = blk & 7;
  int b = bb & 127;
  const int* ids = (bb < 128) ? ids_a : ids_b;
  int t = threadIdx.x;
  int grp = t >> 4, sub = t & 15;
  __shared__ float wl[64];
  __shared__ int   idl[64];
  __shared__ float pacc[4][304];
  __shared__ float red[256];
  float itau = __builtin_amdgcn_exp2f(-1.44269504f*log_tau[0]);
  float c0 = cent[bb*64 + sub*4+0], c1 = cent[bb*64 + sub*4+1];
  float c2 = cent[bb*64 + sub*4+2], c3 = cent[bb*64 + sub*4+3];
  #pragma unroll
  for (int k = 0; k < 4; ++k){
    int sl = grp*4 + k, s = qr*64 + sl;
    int id = ids[b*512 + s];
    float4 lv = *(const float4*)&logvar_tab[(size_t)id*64 + sub*4];
    float iv0 = __builtin_amdgcn_exp2f(-1.44269504f*lv.x);
    float iv1 = __builtin_amdgcn_exp2f(-1.44269504f*lv.y);
    float iv2 = __builtin_amdgcn_exp2f(-1.44269504f*lv.z);
    float iv3 = __builtin_amdgcn_exp2f(-1.44269504f*lv.w);
    ushort4 mu = *(const ushort4*)&MuS[((size_t)bb*512 + s)*64 + sub*4];
    float d0 = bf2f(mu.x)-c0, d1 = bf2f(mu.y)-c1, d2v = bf2f(mu.z)-c2, d3 = bf2f(mu.w)-c3;
    float val = d0*d0*iv0 + d1*d1*iv1 + d2v*d2v*iv2 + d3*d3*iv3;
    val += __shfl_xor(val, 1); val += __shfl_xor(val, 2);
    val += __shfl_xor(val, 4); val += __shfl_xor(val, 8);
    if (sub == 0){
      idl[sl] = id;
      float K = __builtin_amdgcn_exp2f(-0.72134752f * val * itau);
      wl[sl] = al_g[bb*512 + s] * K;
    }
  }
  __syncthreads();
  float ws = blk_sum256(red, t, (t < 64) ? wl[t] : 0.f);
  if (t == 0) wsum_p[blk] = ws;
  int wv = t >> 6, ln = t & 63;
  if (ln < 38){
    float a[8] = {};
    for (int k = 0; k < 16; ++k){
      int sl = (wv << 4) | k;
      float w = wl[sl];
      bf16x8 f8 = *(const bf16x8*)&Abf[(size_t)idl[sl]*320 + ln*8];
      #pragma unroll
      for (int r = 0; r < 8; ++r) a[r] += w * bf2f((ushort)f8[r]);
    }
    #pragma unroll
    for (int r = 0; r < 8; ++r) pacc[wv][ln*8 + r] = a[r];
  }
  __syncthreads();
  for (int j = t; j < 300; j += 256)
    sgs_p[(size_t)blk*304 + j] = pacc[0][j] + pacc[1][j] + pacc[2][j] + pacc[3][j];
}

// ---------------- S1d ----------------
__global__ __launch_bounds__(512)
void k_stage1c(const int* __restrict__ ids_a, const void* __restrict__ mask_a,
               const int* __restrict__ ids_b, const void* __restrict__ mask_b,
               const ushort* __restrict__ MuS, const float* __restrict__ sgs_p,
               const float* __restrict__ wsum_p,
               const float* __restrict__ wq, const float* __restrict__ bq,
               const float* __restrict__ wk, const float* __restrict__ bk,
               float* __restrict__ sgs_g, float* __restrict__ ssum_g, float* __restrict__ ssq_g,
               float* __restrict__ wgt_g)
{
  int bb = blockIdx.x;
  const void* msk = (bb < 128) ? mask_a : mask_b;
  int b = bb & 127;
  int t = threadIdx.x;
  __shared__ float mf_l[512], w_l[512], red[512];
  __shared__ float q_l[64], qk_l[64];
  __shared__ float sgs_l[304];
  __shared__ float bkq_s;
  __shared__ int mmode;
  if (t == 0) mmode = mask_mode((const unsigned char*)msk);
  __syncthreads();
  mf_l[t] = mask_read(msk, b*512 + t, mmode);

  float wsum = 0.f;
  #pragma unroll
  for (int q = 0; q < 8; ++q) wsum += wsum_p[bb*8 + q];
  wsum = fmaxf(wsum, 1e-8f);
  if (t < 300){
    float sa = 0.f;
    #pragma unroll
    for (int q = 0; q < 8; ++q) sa += sgs_p[(size_t)(bb*8+q)*304 + t];
    float sv = sa / wsum;
    sgs_l[t] = sv;
    sgs_g[bb*300 + t] = sv;
  }
  __syncthreads();
  float ssum = blk_sum512(red, t, (t < 300) ? sgs_l[t] : 0.f);
  float ssq  = blk_sum512(red, t, (t < 300) ? sgs_l[t]*sgs_l[t] : 0.f);
  if (t == 0){ ssum_g[bb] = ssum; ssq_g[bb] = ssq; }

  if (t < 64){
    float q = bq[t];
    for (int i = 0; i < 300; ++i) q += sgs_l[i]*wq[i*64 + t];
    q_l[t] = q;
  }
  __syncthreads();
  if (t < 64){
    float a = 0.f;
    for (int j = 0; j < 64; ++j) a += wk[t*64 + j]*q_l[j];
    qk_l[t] = a;
  }
  if (t == 0){
    float s = 0.f;
    for (int j = 0; j < 64; ++j) s += bk[j]*q_l[j];
    bkq_s = s;
  }
  __syncthreads();

  int grp = t >> 4, sub = t & 15;
  {
    float q0 = qk_l[sub*4+0], q1 = qk_l[sub*4+1], q2 = qk_l[sub*4+2], q3 = qk_l[sub*4+3];
    for (int k = 0; k < 16; ++k){
      int s = (grp << 4) | k;
      ushort4 mu = *(const ushort4*)&MuS[((size_t)bb*512 + s)*64 + sub*4];
      float val = bf2f(mu.x)*q0 + bf2f(mu.y)*q1 + bf2f(mu.z)*q2 + bf2f(mu.w)*q3;
      val += __shfl_xor(val, 1); val += __shfl_xor(val, 2);
      val += __shfl_xor(val, 4); val += __shfl_xor(val, 8);
      if (sub == 0){
        float sv = (val + bkq_s) * 0.125f;
        w_l[s] = (mf_l[s] != 0.f) ? sv : -1e30f;
      }
    }
  }
  __syncthreads();

  float mx = blk_max512(red, t, w_l[t]);
  float ex = __expf(w_l[t] - mx);
  float Z  = blk_sum512(red, t, ex);
  wgt_g[bb*512 + t] = ex / Z;
}

// ---------------- k_vgemm2 ----------------
__global__ __launch_bounds__(256)
void k_vgemm2(const float* __restrict__ sgs, const float* __restrict__ w1,
              const float* __restrict__ ln1g, float* __restrict__ V_g){
  __shared__ float As[32][33], Bs[32][33];
  int t = threadIdx.x;
  int bm = blockIdx.x*32, bn = blockIdx.y*32;
  int tx = t & 15, ty = t >> 4;
  float a00=0.f,a01=0.f,a10=0.f,a11=0.f;
  for (int k0 = 0; k0 < 300; k0 += 32){
    #pragma unroll
    for (int i = 0; i < 4; ++i){
      int idx = t + i*256;
      int kk = idx & 31, m = idx >> 5;
      int kg = k0 + kk;
      As[kk][m] = (kg < 300) ? sgs[(size_t)(bm+m)*300 + kg] : 0.f;
    }
    #pragma unroll
    for (int i = 0; i < 4; ++i){
      int idx = t + i*256;
      int n = idx & 31, kk = idx >> 5;
      int kg = k0 + kk, cg = bn + n;
      Bs[kk][n] = (kg < 300 && cg < 600) ? ln1g[300 + kg]*w1[(size_t)(300 + kg)*600 + cg] : 0.f;
    }
    __syncthreads();
    #pragma unroll
    for (int kk = 0; kk < 32; ++kk){
      float x0 = As[kk][ty*2], x1 = As[kk][ty*2+1];
      float y0 = Bs[kk][tx*2], y1 = Bs[kk][tx*2+1];
      a00 += x0*y0; a01 += x0*y1; a10 += x1*y0; a11 += x1*y1;
    }
    __syncthreads();
  }
  int r0 = bm + ty*2, c0 = bn + tx*2;
  #pragma unroll
  for (int i = 0; i < 2; ++i){
    #pragma unroll
    for (int j = 0; j < 2; ++j){
      int r = r0 + i, c = c0 + j;
      if (c < 600) V_g[(size_t)r*600 + c] = (i==0 ? (j==0?a00:a01) : (j==0?a10:a11));
    }
  }
}

// ---------------- K2: hbar + Fbar eighth-split (bf16 feat from Abf) ----------------
__global__ __launch_bounds__(256)
void k_hbar_fbar(const int* __restrict__ ids_a, const int* __restrict__ ids_b,
                 const __hip_bfloat16* __restrict__ U, const ushort* __restrict__ Abf,
                 const float* __restrict__ fsum, const float* __restrict__ fsq,
                 const float* __restrict__ ssum_g, const float* __restrict__ ssq_g,
                 const float* __restrict__ V_g, const float* __restrict__ gw_g,
                 const float* __restrict__ c_g, const float* __restrict__ wgt_g,
                 float* __restrict__ hbar_p, float* __restrict__ Fbar_p)
{
  int blk = blockIdx.x;
  int bb = blk >> 3, qr = blk & 7;
  int b = bb & 127;
  const int* ids = (bb < 128) ? ids_a : ids_b;
  int t = threadIdx.x;
  __shared__ int id_l[64];
  __shared__ float m_l[64], rs_l[64], wg_l[64];
  __shared__ float hp[4][600];
  __shared__ float fp[4][304];
  float ss = ssum_g[bb], sq = ssq_g[bb];
  if (t < 64){
    int s = qr*64 + t;
    int id = ids[b*512 + s];
    id_l[t] = id;
    float m = (fsum[id] + ss) * (1.f/600.f);
    float var = (fsq[id] + sq) * (1.f/600.f) - m*m;
    m_l[t] = m;
    rs_l[t] = 1.f / sqrtf(var + 1e-5f);
    wg_l[t] = wgt_g[bb*512 + s];
  }
  __syncthreads();

  int wv = t >> 6, ln = t & 63;
  float Vp[8], gwp[8], cp[8], Vs[8], gws[8], cs[8];
  #pragma unroll
  for (int r = 0; r < 8; ++r){
    int j = ln*8 + r;
    Vp[r] = V_g[bb*600 + j]; gwp[r] = gw_g[j]; cp[r] = c_g[j];
    Vs[r] = 0.f; gws[r] = 0.f; cs[r] = 0.f;
  }
  if (ln < 11){
    #pragma unroll
    for (int r = 0; r < 8; ++r){
      int j = 512 + ln*8 + r;
      Vs[r] = V_g[bb*600 + j]; gws[r] = gw_g[j]; cs[r] = c_g[j];
    }
  }
  float h1[8] = {}, h2[8] = {}, fa[8] = {};

  for (int k = 0; k < 16; ++k){
    int s = (wv << 4) | k;
    int id = id_l[s];
    float w = wg_l[s], m = m_l[s], rs = rs_l[s];
    const __hip_bfloat16* ur = &U[(size_t)id*600];
    bf16x8 u8 = *(const bf16x8*)&ur[ln*8];
    #pragma unroll
    for (int r = 0; r < 8; ++r){
      float u = bf2f((ushort)u8[r]);
      float a = (u + Vp[r] - m*gwp[r])*rs + cp[r];
      h1[r] += w*gelu_fast(a);
    }
    if (ln < 11){
      bf16x8 u8b = *(const bf16x8*)&ur[512 + ln*8];
      #pragma unroll
      for (int r = 0; r < 8; ++r){
        float u = bf2f((ushort)u8b[r]);
        float a = (u + Vs[r] - m*gws[r])*rs + cs[r];
        h2[r] += w*gelu_fast(a);
      }
    }
    if (ln < 38){
      bf16x8 f8 = *(const bf16x8*)&Abf[(size_t)id*320 + ln*8];
      #pragma unroll
      for (int r = 0; r < 8; ++r) fa[r] += w * bf2f((ushort)f8[r]);
    }
  }
  #pragma unroll
  for (int r = 0; r < 8; ++r) hp[wv][ln*8 + r] = h1[r];
  if (ln < 11){
    #pragma unroll
    for (int r = 0; r < 8; ++r) hp[wv][512 + ln*8 + r] = h2[r];
  }
  if (ln < 38){
    #pragma unroll
    for (int r = 0; r < 8; ++r) fp[wv][ln*8 + r] = fa[r];
  }
  __syncthreads();
  size_t hbase = ((size_t)qr*256 + bb)*608;
  for (int j = t; j < 600; j += 256){
    hbar_p[hbase + j] = hp[0][j] + hp[1][j] + hp[2][j] + hp[3][j];
  }
  if (t < 8) hbar_p[hbase + 600 + t] = 0.f;
  size_t fbase = ((size_t)qr*256 + bb)*300;
  for (int j = t; j < 300; j += 256){
    Fbar_p[fbase + j] = fp[0][j] + fp[1][j] + fp[2][j] + fp[3][j];
  }
}

// ---------------- k_hreduce ----------------
__global__ __launch_bounds__(256)
void k_hreduce(const float* __restrict__ hbar_p, const float* __restrict__ Fbar_p,
               float* __restrict__ hbar_s, float* __restrict__ Fbar_s){
  int i = blockIdx.x*256 + threadIdx.x;
  const size_t Q  = (size_t)256*608;
  const size_t QF = (size_t)256*300;
  if (i < 256*608){
    float s0 = hbar_p[i]       + hbar_p[Q + i];
    float s1 = hbar_p[2*Q + i] + hbar_p[3*Q + i];
    float s2 = hbar_p[4*Q + i] + hbar_p[5*Q + i];
    float s3 = hbar_p[6*Q + i] + hbar_p[7*Q + i];
    hbar_s[i] = (s0 + s1) + (s2 + s3);
  }
  if (i < 256*300){
    float s0 = Fbar_p[i]        + Fbar_p[QF + i];
    float s1 = Fbar_p[2*QF + i] + Fbar_p[3*QF + i];
    float s2 = Fbar_p[4*QF + i] + Fbar_p[5*QF + i];
    float s3 = Fbar_p[6*QF + i] + Fbar_p[7*QF + i];
    Fbar_s[i] = (s0 + s1) + (s2 + s3);
  }
}

// ============ final chain: split-K tiled fp32 GEMMs ============

__global__ __launch_bounds__(256)
void k_att_sk(const float* __restrict__ hbar_s, const float* __restrict__ w2,
              float* __restrict__ att_p){
  __shared__ float As[32][33], Bs[32][33];
  int t = threadIdx.x;
  int bm = blockIdx.x*32, bn = blockIdx.y*32, kc = blockIdx.z;
  int tx = t & 15, ty = t >> 4;
  int kbeg = kc*160, kend = (kc == 3) ? 608 : kbeg + 160;
  float a00=0.f,a01=0.f,a10=0.f,a11=0.f;
  for (int k0 = kbeg; k0 < kend; k0 += 32){
    #pragma unroll
    for (int i = 0; i < 4; ++i){
      int idx = t + i*256;
      int kk = idx & 31, m = idx >> 5;
      As[kk][m] = hbar_s[(size_t)(bm+m)*608 + k0 + kk];
    }
    #pragma unroll
    for (int i = 0; i < 4; ++i){
      int idx = t + i*256;
      int n = idx & 31, kk = idx >> 5;
      int kg = k0 + kk, cg = bn + n;
      Bs[kk][n] = (kg < 600 && cg < 300) ? w2[(size_t)kg*300 + cg] : 0.f;
    }
    __syncthreads();
    #pragma unroll
    for (int kk = 0; kk < 32; ++kk){
      float x0 = As[kk][ty*2], x1 = As[kk][ty*2+1];
      float y0 = Bs[kk][tx*2], y1 = Bs[kk][tx*2+1];
      a00 += x0*y0; a01 += x0*y1; a10 += x1*y0; a11 += x1*y1;
    }
    __syncthreads();
  }
  float* outp = att_p + (size_t)kc*256*300;
  int r0 = bm + ty*2, c0 = bn + tx*2;
  #pragma unroll
  for (int i = 0; i < 2; ++i){
    #pragma unroll
    for (int j = 0; j < 2; ++j){
      int r = r0 + i, c = c0 + j;
      if (c < 300)
        outp[(size_t)r*300 + c] = (i==0 ? (j==0?a00:a01) : (j==0?a10:a11));
    }
  }
}

__global__ __launch_bounds__(256)
void k_att_red(const float* __restrict__ att_p, const float* __restrict__ Fbar_s,
               const float* __restrict__ b2, float* __restrict__ att){
  int i = blockIdx.x*256 + threadIdx.x;
  if (i >= 256*300) return;
  const size_t Q = (size_t)256*300;
  float s = (att_p[i] + att_p[Q+i]) + (att_p[2*Q+i] + att_p[3*Q+i]);
  att[i] = s + b2[i % 300] + Fbar_s[i];
}

__global__ __launch_bounds__(64)
void k_lnstats(const float* __restrict__ att, const float* __restrict__ ssum_g,
               const float* __restrict__ ssq_g, float* __restrict__ m_g, float* __restrict__ rs_g){
  int bb = blockIdx.x, lane = threadIdx.x;
  float s = 0.f, q = 0.f;
  for (int i = lane; i < 300; i += 64){
    float v = att[(size_t)bb*300 + i];
    s += v; q += v*v;
  }
  for (int o = 32; o > 0; o >>= 1){ s += __shfl_xor(s, o); q += __shfl_xor(q, o); }
  if (lane == 0){
    float m = (ssum_g[bb] + s) * (1.f/600.f);
    float var = (ssq_g[bb] + q) * (1.f/600.f) - m*m;
    m_g[bb] = m;
    rs_g[bb] = 1.f / sqrtf(var + 1e-5f);
  }
}

__global__ __launch_bounds__(256)
void k_mlp1_sk(const float* __restrict__ sgs, const float* __restrict__ att,
               const float* __restrict__ m_g, const float* __restrict__ rs_g,
               const float* __restrict__ ln2g, const float* __restrict__ ln2b,
               const float* __restrict__ aw1, float* __restrict__ g2_p){
  __shared__ float As[32][33], Bs[32][33];
  int t = threadIdx.x;
  int bm = blockIdx.x*32, bn = blockIdx.y*32, kc = blockIdx.z;
  int tx = t & 15, ty = t >> 4;
  int kbeg = kc*160, kend = (kc == 3) ? 608 : kbeg + 160;
  float a00=0.f,a01=0.f,a10=0.f,a11=0.f;
  for (int k0 = kbeg; k0 < kend; k0 += 32){
    #pragma unroll
    for (int i = 0; i < 4; ++i){
      int idx = t + i*256;
      int kk = idx & 31, m = idx >> 5;
      int kg = k0 + kk, row = bm + m;
      float t2 = 0.f;
      if (kg < 600){
        float x = (kg < 300) ? sgs[(size_t)row*300 + kg] : att[(size_t)row*300 + kg - 300];
        t2 = (x - m_g[row])*rs_g[row]*ln2g[kg] + ln2b[kg];
      }
      As[kk][m] = t2;
    }
    #pragma unroll
    for (int i = 0; i < 4; ++i){
      int idx = t + i*256;
      int n = idx & 31, kk = idx >> 5;
      int kg = k0 + kk, cg = bn + n;
      Bs[kk][n] = (kg < 600 && cg < 600) ? aw1[(size_t)kg*600 + cg] : 0.f;
    }
    __syncthreads();
    #pragma unroll
    for (int kk = 0; kk < 32; ++kk){
      float x0 = As[kk][ty*2], x1 = As[kk][ty*2+1];
      float y0 = Bs[kk][tx*2], y1 = Bs[kk][tx*2+1];
      a00 += x0*y0; a01 += x0*y1; a10 += x1*y0; a11 += x1*y1;
    }
    __syncthreads();
  }
  float* outp = g2_p + (size_t)kc*256*608;
  int r0 = bm + ty*2, c0 = bn + tx*2;
  #pragma unroll
  for (int i = 0; i < 2; ++i){
    #pragma unroll
    for (int j = 0; j < 2; ++j){
      int r = r0 + i, c = c0 + j;
      outp[(size_t)r*608 + c] = (i==0 ? (j==0?a00:a01) : (j==0?a10:a11));
    }
  }
}

__global__ __launch_bounds__(256)
void k_mlp1_red(const float* __restrict__ g2_p, const float* __restrict__ ab1,
                float* __restrict__ g2){
  int i = blockIdx.x*256 + threadIdx.x;
  if (i >= 256*608) return;
  const size_t Q = (size_t)256*608;
  int c = i % 608;
  float s = (g2_p[i] + g2_p[Q+i]) + (g2_p[2*Q+i] + g2_p[3*Q+i]);
  g2[i] = (c < 600) ? geluf(s + ab1[c]) : 0.f;
}

__global__ __launch_bounds__(256)
void k_mlp2_sk(const float* __restrict__ g2, const float* __restrict__ aw2,
               float* __restrict__ fin_p){
  __shared__ float As[32][33], Bs[32][33];
  int t = threadIdx.x;
  int bm = blockIdx.x*32, bn = blockIdx.y*32, kc = blockIdx.z;
  int tx = t & 15, ty = t >> 4;
  int kbeg = kc*160, kend = (kc == 3) ? 608 : kbeg + 160;
  float a00=0.f,a01=0.f,a10=0.f,a11=0.f;
  for (int k0 = kbeg; k0 < kend; k0 += 32){
    #pragma unroll
    for (int i = 0; i < 4; ++i){
      int idx = t + i*256;
      int kk = idx & 31, m = idx >> 5;
      As[kk][m] = g2[(size_t)(bm+m)*608 + k0 + kk];
    }
    #pragma unroll
    for (int i = 0; i < 4; ++i){
      int idx = t + i*256;
      int n = idx & 31, kk = idx >> 5;
      int kg = k0 + kk, cg = bn + n;
      Bs[kk][n] = (kg < 600 && cg < 300) ? aw2[(size_t)kg*300 + cg] : 0.f;
    }
    __syncthreads();
    #pragma unroll
    for (int kk = 0; kk < 32; ++kk){
      float x0 = As[kk][ty*2], x1 = As[kk][ty*2+1];
      float y0 = Bs[kk][tx*2], y1 = Bs[kk][tx*2+1];
      a00 += x0*y0; a01 += x0*y1; a10 += x1*y0; a11 += x1*y1;
    }
    __syncthreads();
  }
  float* outp = fin_p + (size_t)kc*256*300;
  int r0 = bm + ty*2, c0 = bn + tx*2;
  #pragma unroll
  for (int i = 0; i < 2; ++i){
    #pragma unroll
    for (int j = 0; j < 2; ++j){
      int r = r0 + i, c = c0 + j;
      if (c < 300)
        outp[(size_t)r*300 + c] = (i==0 ? (j==0?a00:a01) : (j==0?a10:a11));
    }
  }
}

__global__ __launch_bounds__(256)
void k_mlp2_red(const float* __restrict__ fin_p, const float* __restrict__ sgs,
                const float* __restrict__ ab2, float* __restrict__ final_g){
  int i = blockIdx.x*256 + threadIdx.x;
  if (i >= 256*300) return;
  const size_t Q = (size_t)256*300;
  float s = (fin_p[i] + fin_p[Q+i]) + (fin_p[2*Q+i] + fin_p[3*Q+i]);
  final_g[i] = s + ab2[i % 300] + sgs[i];
}

__global__ __launch_bounds__(64)
void k_cos(const float* __restrict__ final_g, float* __restrict__ out){
  int b = blockIdx.x; int lane = threadIdx.x;
  const float* A  = final_g + b*300;
  const float* Bv = final_g + (128 + b)*300;
  float dot = 0.f, na = 0.f, nb = 0.f;
  for (int i = lane; i < 300; i += 64){
    float x = A[i], y = Bv[i];
    dot += x*y; na += x*x; nb += y*y;
  }
  for (int o = 32; o > 0; o >>= 1){
    dot += __shfl_xor(dot, o); na += __shfl_xor(na, o); nb += __shfl_xor(nb, o);
  }
  if (lane == 0){
    float den = fmaxf(sqrtf(na), 1e-8f) * fmaxf(sqrtf(nb), 1e-8f);
    out[b] = 5.f * dot / den;
  }
}

extern "C" void kernel_launch(void* const* d_in, const int* in_sizes, int n_in,
                              void* d_out, int out_size, void* d_ws, size_t ws_size,
                              hipStream_t stream) {
  const int* ids_a = (const int*)d_in[0];
  const void* mask_a = d_in[1];
  const int* ids_b = (const int*)d_in[2];
  const void* mask_b = d_in[3];
  const float* mu_tab     = (const float*)d_in[4];
  const float* logvar_tab = (const float*)d_in[5];
  const float* alpha_tab  = (const float*)d_in[6];
  const float* feat_tab   = (const float*)d_in[7];
  const float* log_tau    = (const float*)d_in[8];
  const float* pos_mu     = (const float*)d_in[9];
  const float* pos_alpha  = (const float*)d_in[10];
  const float* ln1g = (const float*)d_in[11];
  const float* ln1b = (const float*)d_in[12];
  const float* w1   = (const float*)d_in[13];
  const float* b1   = (const float*)d_in[14];
  const float* w2   = (const float*)d_in[15];
  const float* b2   = (const float*)d_in[16];
  const float* wq   = (const float*)d_in[17];
  const float* bq   = (const float*)d_in[18];
  const float* wk   = (const float*)d_in[19];
  const float* bk   = (const float*)d_in[20];
  const float* ln2g = (const float*)d_in[21];
  const float* ln2b = (const float*)d_in[22];
  const float* aw1  = (const float*)d_in[23];
  const float* ab1  = (const float*)d_in[24];
  const float* aw2  = (const float*)d_in[25];
  const float* ab2  = (const float*)d_in[26];
  float* out = (float*)d_out;

  char* wsb = (char*)d_ws;
  size_t off = 0;
  auto take = [&](size_t bytes) -> void* {
    void* p = wsb + off;
    off += (bytes + 255) & ~(size_t)255;
    return p;
  };

  const size_t uBytes  = (size_t)30000 * 600 * 2;   // 36.0 MB
  const size_t aBytes  = (size_t)30080 * 320 * 2;   // 19.3 MB (stays live: feat bf16 source)
  const size_t btBytes = (size_t)640 * 320 * 2;     // 0.41 MB
  const size_t muBytes = (size_t)256 * 512 * 64 * 2;// 16.8 MB (aliased post-stage1)
  const size_t need = uBytes + aBytes + btBytes + muBytes + ((size_t)8 << 20);
  if (ws_size < need) return;

  __hip_bfloat16* U = (__hip_bfloat16*)take(uBytes);
  ushort* Abf = (ushort*)take(aBytes);
  ushort* BTbf = (ushort*)take(btBytes);
  char* muRegion = (char*)take(muBytes);
  ushort* MuS = (ushort*)muRegion;
  // alias post-stage1 buffers onto the (dead-after-stage1c) MuS region (16.8 MB):
  float* hbar_p = (float*)(muRegion + 0);                 // 8*256*608*4 = 4,980,736
  float* Fbar_p = (float*)(muRegion + 4980736);           // 8*256*300*4 = 2,457,600
  float* att_g  = (float*)(muRegion + 7438336);           //   307,200
  float* g2_g   = (float*)(muRegion + 7745536);           //   622,592
  float* final_g= (float*)(muRegion + 8368128);           //   307,200
  float* hbar_s = (float*)(muRegion + 8675328);           //   622,592
  float* Fbar_s = (float*)(muRegion + 9297920);           //   307,200
  float* att_p  = (float*)(muRegion + 9605120);           // 4*256*300*4 = 1,228,800
  float* g2_p   = (float*)(muRegion + 10833920);          // 4*256*608*4 = 2,490,368
  float* fin_p  = (float*)(muRegion + 13324288);          // 4*256*300*4 = 1,228,800

  float* fsum   = (float*)take(30000*4);
  float* fsq    = (float*)take(30000*4);
  float* pgw    = (float*)take(8*600*4);
  float* pcv    = (float*)take(8*600*4);
  float* gw_g   = (float*)take(600*4);
  float* c_g    = (float*)take(600*4);
  float* sgs_g  = (float*)take(256*300*4);
  float* ssum_g = (float*)take(256*4);
  float* ssq_g  = (float*)take(256*4);
  float* V_g    = (float*)take(256*600*4);
  float* wgt_g  = (float*)take(256*512*4);
  float* m_g    = (float*)take(256*4);
  float* rs_g   = (float*)take(256*4);
  float* cent_p = (float*)take((size_t)2048*64*4);
  float* msum_p = (float*)take(2048*4);
  float* cent   = (float*)take(256*64*4);
  float* al_g   = (float*)take((size_t)256*512*4);
  float* wsum_p = (float*)take(2048*4);
  float* sgs_p  = (float*)take((size_t)2048*304*4);

  k_pack_stats<<<7520, 256, 0, stream>>>(feat_tab, Abf, fsum, fsq);
  k_pack_b<<<(640*320 + 255)/256, 256, 0, stream>>>(w1, ln1g, BTbf);
  k_gw1_part<<<dim3(3, 8), 256, 0, stream>>>(w1, ln1g, ln1b, pgw, pcv);
  k_gw_reduce<<<3, 256, 0, stream>>>(pgw, pcv, b1, gw_g, c_g);
  k_ugemm_mfma<<<dim3(235, 5), 256, 0, stream>>>(Abf, BTbf, U);
  k_mu_stage<<<2048, 256, 0, stream>>>(ids_a, mask_a, ids_b, mask_b,
                                       mu_tab, pos_mu, alpha_tab, pos_alpha,
                                       MuS, cent_p, msum_p, al_g);
  k_cent_reduce<<<256, 64, 0, stream>>>(cent_p, msum_p, cent);
  k_wrender<<<2048, 256, 0, stream>>>(ids_a, ids_b, logvar_tab, MuS, cent, al_g,
                                      log_tau, Abf, wsum_p, sgs_p);
  k_stage1c<<<256, 512, 0, stream>>>(ids_a, mask_a, ids_b, mask_b,
                                     MuS, sgs_p, wsum_p,
                                     wq, bq, wk, bk,
                                     sgs_g, ssum_g, ssq_g, wgt_g);
  k_vgemm2<<<dim3(8, 19), 256, 0, stream>>>(sgs_g, w1, ln1g, V_g);
  k_hbar_fbar<<<2048, 256, 0, stream>>>(ids_a, ids_b, U, Abf, fsum, fsq,
                                        ssum_g, ssq_g, V_g, gw_g, c_g, wgt_g,
                                        hbar_p, Fbar_p);
  k_hreduce<<<608, 256, 0, stream>>>(hbar_p, Fbar_p, hbar_s, Fbar_s);
  k_att_sk<<<dim3(8, 10, 4), 256, 0, stream>>>(hbar_s, w2, att_p);
  k_att_red<<<300, 256, 0, stream>>>(att_p, Fbar_s, b2, att_g);
  k_lnstats<<<256, 64, 0, stream>>>(att_g, ssum_g, ssq_g, m_g, rs_g);
  k_mlp1_sk<<<dim3(8, 19, 4), 256, 0, stream>>>(sgs_g, att_g, m_g, rs_g, ln2g, ln2b, aw1, g2_p);
  k_mlp1_red<<<608, 256, 0, stream>>>(g2_p, ab1, g2_g);
  k_mlp2_sk<<<dim3(8, 10, 4), 256, 0, stream>>>(g2_g, aw2, fin_p);
  k_mlp2_red<<<300, 256, 0, stream>>>(fin_p, sgs_g, ab2, final_g);
  k_cos<<<128, 64, 0, stream>>>(final_g, out);
}

// Round 13
// 252.986 us; speedup vs baseline: 1.9859x; 1.0500x over previous
//
#include <hip/hip_runtime.h>
#include <hip/hip_bf16.h>
#include <cstdint>
#include <cstddef>

#define DEV __device__ __forceinline__

// problem constants: B=128, S=512, V=30000, DS=64, DF=300, H=600, BB=256

typedef __attribute__((ext_vector_type(8))) short bf16x8;
typedef __attribute__((ext_vector_type(4))) float f32x4;

DEV float geluf(float x){ return 0.5f*x*(1.f + erff(x*0.7071067811865475f)); }
DEV float gelu_fast(float x){
  float x2 = x*x;
  float e = __builtin_amdgcn_exp2f(x * __builtin_fmaf(x2, -0.102953f, -2.302218f));
  return x * __builtin_amdgcn_rcpf(1.f + e);
}

DEV float blk_sum512(float* red, int t, float v){
  red[t] = v; __syncthreads();
  for (int o = 256; o > 0; o >>= 1){ if (t < o) red[t] += red[t+o]; __syncthreads(); }
  float r = red[0]; __syncthreads(); return r;
}
DEV float blk_max512(float* red, int t, float v){
  red[t] = v; __syncthreads();
  for (int o = 256; o > 0; o >>= 1){ if (t < o) red[t] = fmaxf(red[t], red[t+o]); __syncthreads(); }
  float r = red[0]; __syncthreads(); return r;
}
DEV float blk_sum256(float* red, int t, float v){
  red[t] = v; __syncthreads();
  for (int o = 128; o > 0; o >>= 1){ if (t < o) red[t] += red[t+o]; __syncthreads(); }
  float r = red[0]; __syncthreads(); return r;
}

DEV ushort f2bf(float v){ __hip_bfloat16 h = __float2bfloat16(v); return *(ushort*)&h; }
DEV float bf2f(ushort u){ __hip_bfloat16 h; *(ushort*)&h = u; return __bfloat162float(h); }

// ---- mask dtype classifier ----
DEV int mask_mode(const unsigned char* m){
  bool big = false, off123 = false, off0one = false;
  #pragma unroll
  for (int i = 0; i < 16; ++i){
    unsigned char c = m[i];
    if (c > 1) big = true;
    if ((i & 3) != 0 && c != 0) off123 = true;
    if ((i & 3) == 0 && c == 1) off0one = true;
  }
  if (big) return 2;
  if (!off123 && off0one) return 1;
  return 0;
}
DEV float mask_read(const void* m, int idx, int mode){
  if (mode == 1) return ((const int*)m)[idx] ? 1.f : 0.f;
  if (mode == 2) return ((const unsigned short*)m)[idx] ? 1.f : 0.f;
  return ((const unsigned char*)m)[idx] ? 1.f : 0.f;
}

// ---------------- fused: pack A + per-vocab stats ----------------
__global__ __launch_bounds__(256)
void k_pack_stats(const float* __restrict__ feat, ushort* __restrict__ A,
                  float* __restrict__ fsum, float* __restrict__ fsq){
  int v = blockIdx.x*4 + (threadIdx.x >> 6);
  int ln = threadIdx.x & 63;
  if (v >= 30080) return;
  float vals[8] = {0.f,0.f,0.f,0.f,0.f,0.f,0.f,0.f};
  if (v < 30000 && ln < 38){
    const float* fr = &feat[(size_t)v*300];
    if (ln < 37){
      float4 a = *(const float4*)&fr[ln*8];
      float4 b = *(const float4*)&fr[ln*8 + 4];
      vals[0]=a.x; vals[1]=a.y; vals[2]=a.z; vals[3]=a.w;
      vals[4]=b.x; vals[5]=b.y; vals[6]=b.z; vals[7]=b.w;
    } else {
      float4 a = *(const float4*)&fr[296];
      vals[0]=a.x; vals[1]=a.y; vals[2]=a.z; vals[3]=a.w;
    }
  }
  if (ln < 40){
    union { ushort u[8]; bf16x8 v8; } pk;
    #pragma unroll
    for (int i = 0; i < 8; ++i) pk.u[i] = f2bf(vals[i]);
    *(bf16x8*)&A[(size_t)v*320 + ln*8] = pk.v8;
  }
  float s = 0.f, q = 0.f;
  #pragma unroll
  for (int i = 0; i < 8; ++i){ s += vals[i]; q += vals[i]*vals[i]; }
  for (int o = 32; o > 0; o >>= 1){ s += __shfl_xor(s, o); q += __shfl_xor(q, o); }
  if (ln == 0 && v < 30000){ fsum[v] = s; fsq[v] = q; }
}

// ---------------- P0b ----------------
__global__ __launch_bounds__(256)
void k_gw1_part(const float* __restrict__ w1, const float* __restrict__ g,
                const float* __restrict__ bln, float* __restrict__ pgw, float* __restrict__ pcv){
  int j = blockIdx.x*256 + threadIdx.x;
  int ic = blockIdx.y;
  if (j >= 600) return;
  float a = 0.f, c = 0.f;
  for (int i = ic*75; i < ic*75 + 75; ++i){
    float w = w1[i*600 + j];
    a += g[i]*w; c += bln[i]*w;
  }
  pgw[ic*600 + j] = a; pcv[ic*600 + j] = c;
}

__global__ __launch_bounds__(256)
void k_gw_reduce(const float* __restrict__ pgw, const float* __restrict__ pcv,
                 const float* __restrict__ b1, float* __restrict__ gw_g, float* __restrict__ c_g){
  int j = blockIdx.x*256 + threadIdx.x;
  if (j >= 600) return;
  float a = 0.f, c = 0.f;
  for (int k = 0; k < 8; ++k){ a += pgw[k*600 + j]; c += pcv[k*600 + j]; }
  gw_g[j] = a; c_g[j] = c + b1[j];
}

// ---------------- pack B^T ----------------
__global__ __launch_bounds__(256)
void k_pack_b(const float* __restrict__ w1, const float* __restrict__ g, ushort* __restrict__ BT){
  int id = blockIdx.x*256 + threadIdx.x;
  if (id >= 640*320) return;
  int n = id % 640, k = id / 640;
  float val = (k < 300 && n < 600) ? g[k]*w1[k*600 + n] : 0.f;
  BT[(size_t)n*320 + k] = f2bf(val);
}

// ---------------- P1: U GEMM (MFMA) ----------------
__global__ __launch_bounds__(256)
void k_ugemm_mfma(const ushort* __restrict__ A, const ushort* __restrict__ BT,
                  __hip_bfloat16* __restrict__ U){
  __shared__ ushort As[128][40];
  __shared__ ushort Bs[128][40];
  int tid = threadIdx.x;
  int bm = blockIdx.x * 128, bn = blockIdx.y * 128;
  int wid = tid >> 6, lane = tid & 63;
  int wr = wid >> 1, wc = wid & 1;
  int lr = lane & 15, lk = lane >> 4;
  f32x4 acc[4][4] = {};
  for (int k0 = 0; k0 < 320; k0 += 32){
    #pragma unroll
    for (int j = 0; j < 2; ++j){
      int idx = tid + 256*j;
      int row = idx >> 2, ko = (idx & 3)*8;
      *(bf16x8*)&As[row][ko] = *(const bf16x8*)&A[(size_t)(bm+row)*320 + k0 + ko];
      *(bf16x8*)&Bs[row][ko] = *(const bf16x8*)&BT[(size_t)(bn+row)*320 + k0 + ko];
    }
    __syncthreads();
    bf16x8 af[4], bfr[4];
    #pragma unroll
    for (int f = 0; f < 4; ++f){
      af[f]  = *(const bf16x8*)&As[wr*64 + f*16 + lr][lk*8];
      bfr[f] = *(const bf16x8*)&Bs[wc*64 + f*16 + lr][lk*8];
    }
    #pragma unroll
    for (int i = 0; i < 4; ++i)
      #pragma unroll
      for (int j = 0; j < 4; ++j)
        acc[i][j] = __builtin_amdgcn_mfma_f32_16x16x32_bf16(af[i], bfr[j], acc[i][j], 0, 0, 0);
    __syncthreads();
  }
  #pragma unroll
  for (int i = 0; i < 4; ++i){
    #pragma unroll
    for (int j = 0; j < 4; ++j){
      #pragma unroll
      for (int r = 0; r < 4; ++r){
        int row = bm + wr*64 + i*16 + lk*4 + r;
        int col = bn + wc*64 + j*16 + lr;
        if (row < 30000 && col < 600)
          U[(size_t)row*600 + col] = __float2bfloat16(acc[i][j][r]);
      }
    }
  }
}

// ---------------- S1a: mu gather+stage ----------------
__global__ __launch_bounds__(256)
void k_mu_stage(const int* __restrict__ ids_a, const void* __restrict__ mask_a,
                const int* __restrict__ ids_b, const void* __restrict__ mask_b,
                const float* __restrict__ mu_tab, const float* __restrict__ pos_mu,
                const float* __restrict__ alpha_tab, const float* __restrict__ pos_alpha,
                ushort* __restrict__ MuS, float* __restrict__ cent_p,
                float* __restrict__ msum_p, float* __restrict__ al_g){
  int blk = blockIdx.x;
  int bb = blk >> 3, qr = blk & 7;
  int b = bb & 127;
  const int* ids = (bb < 128) ? ids_a : ids_b;
  const void* msk = (bb < 128) ? mask_a : mask_b;
  int t = threadIdx.x;
  int grp = t >> 4, sub = t & 15;
  __shared__ int mmode_s;
  __shared__ float gpart[16][64];
  __shared__ float mf_s[64];
  __shared__ float red[256];
  if (t == 0) mmode_s = mask_mode((const unsigned char*)msk);
  __syncthreads();
  int mmode = mmode_s;
  float cp0=0.f, cp1=0.f, cp2=0.f, cp3=0.f;
  #pragma unroll
  for (int k = 0; k < 4; ++k){
    int sl = grp*4 + k;
    int s  = qr*64 + sl;
    int id = ids[b*512 + s];
    float mf = mask_read(msk, b*512 + s, mmode);
    float4 m4 = *(const float4*)&mu_tab[(size_t)id*64 + sub*4];
    float4 p4 = *(const float4*)&pos_mu[s*64 + sub*4];
    float v0 = m4.x+p4.x, v1 = m4.y+p4.y, v2 = m4.z+p4.z, v3 = m4.w+p4.w;
    ushort4 st; st.x = f2bf(v0); st.y = f2bf(v1); st.z = f2bf(v2); st.w = f2bf(v3);
    *(ushort4*)&MuS[((size_t)bb*512 + s)*64 + sub*4] = st;
    cp0 += mf*v0; cp1 += mf*v1; cp2 += mf*v2; cp3 += mf*v3;
    if (sub == 0){
      mf_s[sl] = mf;
      float pa = pos_alpha[s];
      float sg = __builtin_amdgcn_rcpf(1.f + __builtin_amdgcn_exp2f(-1.44269504f*pa));
      al_g[bb*512 + s] = alpha_tab[id] * sg * mf;
    }
  }
  gpart[grp][sub*4+0] = cp0; gpart[grp][sub*4+1] = cp1;
  gpart[grp][sub*4+2] = cp2; gpart[grp][sub*4+3] = cp3;
  __syncthreads();
  if (t < 64){
    float c = 0.f;
    #pragma unroll
    for (int g = 0; g < 16; ++g) c += gpart[g][t];
    cent_p[(size_t)blk*64 + t] = c;
  }
  float ms = blk_sum256(red, t, (t < 64) ? mf_s[t] : 0.f);
  if (t == 0) msum_p[blk] = ms;
}

// ---------------- S1b ----------------
__global__ __launch_bounds__(64)
void k_cent_reduce(const float* __restrict__ cent_p, const float* __restrict__ msum_p,
                   float* __restrict__ cent){
  int bb = blockIdx.x, d = threadIdx.x;
  float c = 0.f, ms = 0.f;
  #pragma unroll
  for (int q = 0; q < 8; ++q){
    c  += cent_p[(size_t)(bb*8+q)*64 + d];
    ms += msum_p[bb*8+q];
  }
  cent[bb*64 + d] = c / fmaxf(ms, 1.f);
}

// ---------------- S1c: w = alpha*K (inline exp2), render partials (bf16 Abf) ----------------
__global__ __launch_bounds__(256)
void k_wrender(const int* __restrict__ ids_a, const int* __restrict__ ids_b,
               const float* __restrict__ logvar_tab, const ushort* __restrict__ MuS,
               const float* __restrict__ cent, const float* __restrict__ al_g,
               const float* __restrict__ log_tau, const ushort* __restrict__ Abf,
               float* __restrict__ wsum_p, float* __restrict__ sgs_p){
  int blk = blockIdx.x;
  int bb = blk >> 3, qr = blk & 7;
  int b = bb & 127;
  const int* ids = (bb < 128) ? ids_a : ids_b;
  int t = threadIdx.x;
  int grp = t >> 4, sub = t & 15;
  __shared__ float wl[64];
  __shared__ int   idl[64];
  __shared__ float pacc[4][304];
  __shared__ float red[256];
  float itau = __builtin_amdgcn_exp2f(-1.44269504f*log_tau[0]);
  float c0 = cent[bb*64 + sub*4+0], c1 = cent[bb*64 + sub*4+1];
  float c2 = cent[bb*64 + sub*4+2], c3 = cent[bb*64 + sub*4+3];
  #pragma unroll
  for (int k = 0; k < 4; ++k){
    int sl = grp*4 + k, s = qr*64 + sl;
    int id = ids[b*512 + s];
    float4 lv = *(const float4*)&logvar_tab[(size_t)id*64 + sub*4];
    float iv0 = __builtin_amdgcn_exp2f(-1.44269504f*lv.x);
    float iv1 = __builtin_amdgcn_exp2f(-1.44269504f*lv.y);
    float iv2 = __builtin_amdgcn_exp2f(-1.44269504f*lv.z);
    float iv3 = __builtin_amdgcn_exp2f(-1.44269504f*lv.w);
    ushort4 mu = *(const ushort4*)&MuS[((size_t)bb*512 + s)*64 + sub*4];
    float d0 = bf2f(mu.x)-c0, d1 = bf2f(mu.y)-c1, d2v = bf2f(mu.z)-c2, d3 = bf2f(mu.w)-c3;
    float val = d0*d0*iv0 + d1*d1*iv1 + d2v*d2v*iv2 + d3*d3*iv3;
    val += __shfl_xor(val, 1); val += __shfl_xor(val, 2);
    val += __shfl_xor(val, 4); val += __shfl_xor(val, 8);
    if (sub == 0){
      idl[sl] = id;
      float K = __builtin_amdgcn_exp2f(-0.72134752f * val * itau);
      wl[sl] = al_g[bb*512 + s] * K;
    }
  }
  __syncthreads();
  float ws = blk_sum256(red, t, (t < 64) ? wl[t] : 0.f);
  if (t == 0) wsum_p[blk] = ws;
  int wv = t >> 6, ln = t & 63;
  if (ln < 38){
    float a[8] = {};
    for (int k = 0; k < 16; ++k){
      int sl = (wv << 4) | k;
      float w = wl[sl];
      bf16x8 f8 = *(const bf16x8*)&Abf[(size_t)idl[sl]*320 + ln*8];
      #pragma unroll
      for (int r = 0; r < 8; ++r) a[r] += w * bf2f((ushort)f8[r]);
    }
    #pragma unroll
    for (int r = 0; r < 8; ++r) pacc[wv][ln*8 + r] = a[r];
  }
  __syncthreads();
  for (int j = t; j < 300; j += 256)
    sgs_p[(size_t)blk*304 + j] = pacc[0][j] + pacc[1][j] + pacc[2][j] + pacc[3][j];
}

// ---------------- S1d ----------------
__global__ __launch_bounds__(512)
void k_stage1c(const int* __restrict__ ids_a, const void* __restrict__ mask_a,
               const int* __restrict__ ids_b, const void* __restrict__ mask_b,
               const ushort* __restrict__ MuS, const float* __restrict__ sgs_p,
               const float* __restrict__ wsum_p,
               const float* __restrict__ wq, const float* __restrict__ bq,
               const float* __restrict__ wk, const float* __restrict__ bk,
               float* __restrict__ sgs_g, float* __restrict__ ssum_g, float* __restrict__ ssq_g,
               float* __restrict__ wgt_g)
{
  int bb = blockIdx.x;
  const void* msk = (bb < 128) ? mask_a : mask_b;
  int b = bb & 127;
  int t = threadIdx.x;
  __shared__ float mf_l[512], w_l[512], red[512];
  __shared__ float q_l[64], qk_l[64];
  __shared__ float sgs_l[304];
  __shared__ float bkq_s;
  __shared__ int mmode;
  if (t == 0) mmode = mask_mode((const unsigned char*)msk);
  __syncthreads();
  mf_l[t] = mask_read(msk, b*512 + t, mmode);

  float wsum = 0.f;
  #pragma unroll
  for (int q = 0; q < 8; ++q) wsum += wsum_p[bb*8 + q];
  wsum = fmaxf(wsum, 1e-8f);
  if (t < 300){
    float sa = 0.f;
    #pragma unroll
    for (int q = 0; q < 8; ++q) sa += sgs_p[(size_t)(bb*8+q)*304 + t];
    float sv = sa / wsum;
    sgs_l[t] = sv;
    sgs_g[bb*300 + t] = sv;
  }
  __syncthreads();
  float ssum = blk_sum512(red, t, (t < 300) ? sgs_l[t] : 0.f);
  float ssq  = blk_sum512(red, t, (t < 300) ? sgs_l[t]*sgs_l[t] : 0.f);
  if (t == 0){ ssum_g[bb] = ssum; ssq_g[bb] = ssq; }

  if (t < 64){
    float q = bq[t];
    for (int i = 0; i < 300; ++i) q += sgs_l[i]*wq[i*64 + t];
    q_l[t] = q;
  }
  __syncthreads();
  if (t < 64){
    float a = 0.f;
    for (int j = 0; j < 64; ++j) a += wk[t*64 + j]*q_l[j];
    qk_l[t] = a;
  }
  if (t == 0){
    float s = 0.f;
    for (int j = 0; j < 64; ++j) s += bk[j]*q_l[j];
    bkq_s = s;
  }
  __syncthreads();

  int grp = t >> 4, sub = t & 15;
  {
    float q0 = qk_l[sub*4+0], q1 = qk_l[sub*4+1], q2 = qk_l[sub*4+2], q3 = qk_l[sub*4+3];
    for (int k = 0; k < 16; ++k){
      int s = (grp << 4) | k;
      ushort4 mu = *(const ushort4*)&MuS[((size_t)bb*512 + s)*64 + sub*4];
      float val = bf2f(mu.x)*q0 + bf2f(mu.y)*q1 + bf2f(mu.z)*q2 + bf2f(mu.w)*q3;
      val += __shfl_xor(val, 1); val += __shfl_xor(val, 2);
      val += __shfl_xor(val, 4); val += __shfl_xor(val, 8);
      if (sub == 0){
        float sv = (val + bkq_s) * 0.125f;
        w_l[s] = (mf_l[s] != 0.f) ? sv : -1e30f;
      }
    }
  }
  __syncthreads();

  float mx = blk_max512(red, t, w_l[t]);
  float ex = __expf(w_l[t] - mx);
  float Z  = blk_sum512(red, t, ex);
  wgt_g[bb*512 + t] = ex / Z;
}

// ---------------- k_vgemm2 ----------------
__global__ __launch_bounds__(256)
void k_vgemm2(const float* __restrict__ sgs, const float* __restrict__ w1,
              const float* __restrict__ ln1g, float* __restrict__ V_g){
  __shared__ float As[32][33], Bs[32][33];
  int t = threadIdx.x;
  int bm = blockIdx.x*32, bn = blockIdx.y*32;
  int tx = t & 15, ty = t >> 4;
  float a00=0.f,a01=0.f,a10=0.f,a11=0.f;
  for (int k0 = 0; k0 < 300; k0 += 32){
    #pragma unroll
    for (int i = 0; i < 4; ++i){
      int idx = t + i*256;
      int kk = idx & 31, m = idx >> 5;
      int kg = k0 + kk;
      As[kk][m] = (kg < 300) ? sgs[(size_t)(bm+m)*300 + kg] : 0.f;
    }
    #pragma unroll
    for (int i = 0; i < 4; ++i){
      int idx = t + i*256;
      int n = idx & 31, kk = idx >> 5;
      int kg = k0 + kk, cg = bn + n;
      Bs[kk][n] = (kg < 300 && cg < 600) ? ln1g[300 + kg]*w1[(size_t)(300 + kg)*600 + cg] : 0.f;
    }
    __syncthreads();
    #pragma unroll
    for (int kk = 0; kk < 32; ++kk){
      float x0 = As[kk][ty*2], x1 = As[kk][ty*2+1];
      float y0 = Bs[kk][tx*2], y1 = Bs[kk][tx*2+1];
      a00 += x0*y0; a01 += x0*y1; a10 += x1*y0; a11 += x1*y1;
    }
    __syncthreads();
  }
  int r0 = bm + ty*2, c0 = bn + tx*2;
  #pragma unroll
  for (int i = 0; i < 2; ++i){
    #pragma unroll
    for (int j = 0; j < 2; ++j){
      int r = r0 + i, c = c0 + j;
      if (c < 600) V_g[(size_t)r*600 + c] = (i==0 ? (j==0?a00:a01) : (j==0?a10:a11));
    }
  }
}

// ---------------- K2: hbar + Fbar eighth-split (balanced tail: ushort4 x 22 lanes) ----------------
__global__ __launch_bounds__(256)
void k_hbar_fbar(const int* __restrict__ ids_a, const int* __restrict__ ids_b,
                 const __hip_bfloat16* __restrict__ U, const ushort* __restrict__ Abf,
                 const float* __restrict__ fsum, const float* __restrict__ fsq,
                 const float* __restrict__ ssum_g, const float* __restrict__ ssq_g,
                 const float* __restrict__ V_g, const float* __restrict__ gw_g,
                 const float* __restrict__ c_g, const float* __restrict__ wgt_g,
                 float* __restrict__ hbar_p, float* __restrict__ Fbar_p)
{
  int blk = blockIdx.x;
  int bb = blk >> 3, qr = blk & 7;
  int b = bb & 127;
  const int* ids = (bb < 128) ? ids_a : ids_b;
  int t = threadIdx.x;
  __shared__ int id_l[64];
  __shared__ float m_l[64], rs_l[64], wg_l[64];
  __shared__ float hp[4][600];
  __shared__ float fp[4][304];
  float ss = ssum_g[bb], sq = ssq_g[bb];
  if (t < 64){
    int s = qr*64 + t;
    int id = ids[b*512 + s];
    id_l[t] = id;
    float m = (fsum[id] + ss) * (1.f/600.f);
    float var = (fsq[id] + sq) * (1.f/600.f) - m*m;
    m_l[t] = m;
    rs_l[t] = 1.f / sqrtf(var + 1e-5f);
    wg_l[t] = wgt_g[bb*512 + s];
  }
  __syncthreads();

  int wv = t >> 6, ln = t & 63;
  // primary: dims ln*8 .. ln*8+7 (covers 0..511)
  float Vp[8], gwp[8], cp[8];
  #pragma unroll
  for (int r = 0; r < 8; ++r){
    int j = ln*8 + r;
    Vp[r] = V_g[bb*600 + j]; gwp[r] = gw_g[j]; cp[r] = c_g[j];
  }
  // secondary (balanced): dims 512 + ln*4 .. +3 for ln<22 (covers 512..599)
  float Vs[4] = {}, gws[4] = {}, cs[4] = {};
  if (ln < 22){
    #pragma unroll
    for (int r = 0; r < 4; ++r){
      int j = 512 + ln*4 + r;
      Vs[r] = V_g[bb*600 + j]; gws[r] = gw_g[j]; cs[r] = c_g[j];
    }
  }
  float h1[8] = {}, h2[4] = {}, fa[8] = {};

  for (int k = 0; k < 16; ++k){
    int s = (wv << 4) | k;
    int id = id_l[s];
    float w = wg_l[s], m = m_l[s], rs = rs_l[s];
    const __hip_bfloat16* ur = &U[(size_t)id*600];
    bf16x8 u8 = *(const bf16x8*)&ur[ln*8];
    #pragma unroll
    for (int r = 0; r < 8; ++r){
      float u = bf2f((ushort)u8[r]);
      float a = (u + Vp[r] - m*gwp[r])*rs + cp[r];
      h1[r] += w*gelu_fast(a);
    }
    if (ln < 22){
      ushort4 u4 = *(const ushort4*)&ur[512 + ln*4];
      float uu[4] = { bf2f(u4.x), bf2f(u4.y), bf2f(u4.z), bf2f(u4.w) };
      #pragma unroll
      for (int r = 0; r < 4; ++r){
        float a = (uu[r] + Vs[r] - m*gws[r])*rs + cs[r];
        h2[r] += w*gelu_fast(a);
      }
    }
    if (ln < 38){
      bf16x8 f8 = *(const bf16x8*)&Abf[(size_t)id*320 + ln*8];
      #pragma unroll
      for (int r = 0; r < 8; ++r) fa[r] += w * bf2f((ushort)f8[r]);
    }
  }
  #pragma unroll
  for (int r = 0; r < 8; ++r) hp[wv][ln*8 + r] = h1[r];
  if (ln < 22){
    #pragma unroll
    for (int r = 0; r < 4; ++r) hp[wv][512 + ln*4 + r] = h2[r];
  }
  if (ln < 38){
    #pragma unroll
    for (int r = 0; r < 8; ++r) fp[wv][ln*8 + r] = fa[r];
  }
  __syncthreads();
  size_t hbase = ((size_t)qr*256 + bb)*608;
  for (int j = t; j < 600; j += 256){
    hbar_p[hbase + j] = hp[0][j] + hp[1][j] + hp[2][j] + hp[3][j];
  }
  if (t < 8) hbar_p[hbase + 600 + t] = 0.f;
  size_t fbase = ((size_t)qr*256 + bb)*300;
  for (int j = t; j < 300; j += 256){
    Fbar_p[fbase + j] = fp[0][j] + fp[1][j] + fp[2][j] + fp[3][j];
  }
}

// ---------------- k_hreduce ----------------
__global__ __launch_bounds__(256)
void k_hreduce(const float* __restrict__ hbar_p, const float* __restrict__ Fbar_p,
               float* __restrict__ hbar_s, float* __restrict__ Fbar_s){
  int i = blockIdx.x*256 + threadIdx.x;
  const size_t Q  = (size_t)256*608;
  const size_t QF = (size_t)256*300;
  if (i < 256*608){
    float s0 = hbar_p[i]       + hbar_p[Q + i];
    float s1 = hbar_p[2*Q + i] + hbar_p[3*Q + i];
    float s2 = hbar_p[4*Q + i] + hbar_p[5*Q + i];
    float s3 = hbar_p[6*Q + i] + hbar_p[7*Q + i];
    hbar_s[i] = (s0 + s1) + (s2 + s3);
  }
  if (i < 256*300){
    float s0 = Fbar_p[i]        + Fbar_p[QF + i];
    float s1 = Fbar_p[2*QF + i] + Fbar_p[3*QF + i];
    float s2 = Fbar_p[4*QF + i] + Fbar_p[5*QF + i];
    float s3 = Fbar_p[6*QF + i] + Fbar_p[7*QF + i];
    Fbar_s[i] = (s0 + s1) + (s2 + s3);
  }
}

// ============ final chain: split-K tiled fp32 GEMMs ============

__global__ __launch_bounds__(256)
void k_att_sk(const float* __restrict__ hbar_s, const float* __restrict__ w2,
              float* __restrict__ att_p){
  __shared__ float As[32][33], Bs[32][33];
  int t = threadIdx.x;
  int bm = blockIdx.x*32, bn = blockIdx.y*32, kc = blockIdx.z;
  int tx = t & 15, ty = t >> 4;
  int kbeg = kc*160, kend = (kc == 3) ? 608 : kbeg + 160;
  float a00=0.f,a01=0.f,a10=0.f,a11=0.f;
  for (int k0 = kbeg; k0 < kend; k0 += 32){
    #pragma unroll
    for (int i = 0; i < 4; ++i){
      int idx = t + i*256;
      int kk = idx & 31, m = idx >> 5;
      As[kk][m] = hbar_s[(size_t)(bm+m)*608 + k0 + kk];
    }
    #pragma unroll
    for (int i = 0; i < 4; ++i){
      int idx = t + i*256;
      int n = idx & 31, kk = idx >> 5;
      int kg = k0 + kk, cg = bn + n;
      Bs[kk][n] = (kg < 600 && cg < 300) ? w2[(size_t)kg*300 + cg] : 0.f;
    }
    __syncthreads();
    #pragma unroll
    for (int kk = 0; kk < 32; ++kk){
      float x0 = As[kk][ty*2], x1 = As[kk][ty*2+1];
      float y0 = Bs[kk][tx*2], y1 = Bs[kk][tx*2+1];
      a00 += x0*y0; a01 += x0*y1; a10 += x1*y0; a11 += x1*y1;
    }
    __syncthreads();
  }
  float* outp = att_p + (size_t)kc*256*300;
  int r0 = bm + ty*2, c0 = bn + tx*2;
  #pragma unroll
  for (int i = 0; i < 2; ++i){
    #pragma unroll
    for (int j = 0; j < 2; ++j){
      int r = r0 + i, c = c0 + j;
      if (c < 300)
        outp[(size_t)r*300 + c] = (i==0 ? (j==0?a00:a01) : (j==0?a10:a11));
    }
  }
}

// fused: att = partial-sum + b2 + Fbar; plus LN2 row stats (one block per bb, 64 lanes)
__global__ __launch_bounds__(64)
void k_att_stats(const float* __restrict__ att_p, const float* __restrict__ Fbar_s,
                 const float* __restrict__ b2, const float* __restrict__ ssum_g,
                 const float* __restrict__ ssq_g,
                 float* __restrict__ att, float* __restrict__ m_g, float* __restrict__ rs_g){
  int bb = blockIdx.x, lane = threadIdx.x;
  const size_t Q = (size_t)256*300;
  float s = 0.f, q = 0.f;
  for (int j = lane; j < 300; j += 64){
    size_t i = (size_t)bb*300 + j;
    float v = (att_p[i] + att_p[Q+i]) + (att_p[2*Q+i] + att_p[3*Q+i]);
    v += b2[j] + Fbar_s[i];
    att[i] = v;
    s += v; q += v*v;
  }
  for (int o = 32; o > 0; o >>= 1){ s += __shfl_xor(s, o); q += __shfl_xor(q, o); }
  if (lane == 0){
    float m = (ssum_g[bb] + s) * (1.f/600.f);
    float var = (ssq_g[bb] + q) * (1.f/600.f) - m*m;
    m_g[bb] = m;
    rs_g[bb] = 1.f / sqrtf(var + 1e-5f);
  }
}

__global__ __launch_bounds__(256)
void k_mlp1_sk(const float* __restrict__ sgs, const float* __restrict__ att,
               const float* __restrict__ m_g, const float* __restrict__ rs_g,
               const float* __restrict__ ln2g, const float* __restrict__ ln2b,
               const float* __restrict__ aw1, float* __restrict__ g2_p){
  __shared__ float As[32][33], Bs[32][33];
  int t = threadIdx.x;
  int bm = blockIdx.x*32, bn = blockIdx.y*32, kc = blockIdx.z;
  int tx = t & 15, ty = t >> 4;
  int kbeg = kc*160, kend = (kc == 3) ? 608 : kbeg + 160;
  float a00=0.f,a01=0.f,a10=0.f,a11=0.f;
  for (int k0 = kbeg; k0 < kend; k0 += 32){
    #pragma unroll
    for (int i = 0; i < 4; ++i){
      int idx = t + i*256;
      int kk = idx & 31, m = idx >> 5;
      int kg = k0 + kk, row = bm + m;
      float t2 = 0.f;
      if (kg < 600){
        float x = (kg < 300) ? sgs[(size_t)row*300 + kg] : att[(size_t)row*300 + kg - 300];
        t2 = (x - m_g[row])*rs_g[row]*ln2g[kg] + ln2b[kg];
      }
      As[kk][m] = t2;
    }
    #pragma unroll
    for (int i = 0; i < 4; ++i){
      int idx = t + i*256;
      int n = idx & 31, kk = idx >> 5;
      int kg = k0 + kk, cg = bn + n;
      Bs[kk][n] = (kg < 600 && cg < 600) ? aw1[(size_t)kg*600 + cg] : 0.f;
    }
    __syncthreads();
    #pragma unroll
    for (int kk = 0; kk < 32; ++kk){
      float x0 = As[kk][ty*2], x1 = As[kk][ty*2+1];
      float y0 = Bs[kk][tx*2], y1 = Bs[kk][tx*2+1];
      a00 += x0*y0; a01 += x0*y1; a10 += x1*y0; a11 += x1*y1;
    }
    __syncthreads();
  }
  float* outp = g2_p + (size_t)kc*256*608;
  int r0 = bm + ty*2, c0 = bn + tx*2;
  #pragma unroll
  for (int i = 0; i < 2; ++i){
    #pragma unroll
    for (int j = 0; j < 2; ++j){
      int r = r0 + i, c = c0 + j;
      outp[(size_t)r*608 + c] = (i==0 ? (j==0?a00:a01) : (j==0?a10:a11));
    }
  }
}

__global__ __launch_bounds__(256)
void k_mlp1_red(const float* __restrict__ g2_p, const float* __restrict__ ab1,
                float* __restrict__ g2){
  int i = blockIdx.x*256 + threadIdx.x;
  if (i >= 256*608) return;
  const size_t Q = (size_t)256*608;
  int c = i % 608;
  float s = (g2_p[i] + g2_p[Q+i]) + (g2_p[2*Q+i] + g2_p[3*Q+i]);
  g2[i] = (c < 600) ? geluf(s + ab1[c]) : 0.f;
}

__global__ __launch_bounds__(256)
void k_mlp2_sk(const float* __restrict__ g2, const float* __restrict__ aw2,
               float* __restrict__ fin_p){
  __shared__ float As[32][33], Bs[32][33];
  int t = threadIdx.x;
  int bm = blockIdx.x*32, bn = blockIdx.y*32, kc = blockIdx.z;
  int tx = t & 15, ty = t >> 4;
  int kbeg = kc*160, kend = (kc == 3) ? 608 : kbeg + 160;
  float a00=0.f,a01=0.f,a10=0.f,a11=0.f;
  for (int k0 = kbeg; k0 < kend; k0 += 32){
    #pragma unroll
    for (int i = 0; i < 4; ++i){
      int idx = t + i*256;
      int kk = idx & 31, m = idx >> 5;
      As[kk][m] = g2[(size_t)(bm+m)*608 + k0 + kk];
    }
    #pragma unroll
    for (int i = 0; i < 4; ++i){
      int idx = t + i*256;
      int n = idx & 31, kk = idx >> 5;
      int kg = k0 + kk, cg = bn + n;
      Bs[kk][n] = (kg < 600 && cg < 300) ? aw2[(size_t)kg*300 + cg] : 0.f;
    }
    __syncthreads();
    #pragma unroll
    for (int kk = 0; kk < 32; ++kk){
      float x0 = As[kk][ty*2], x1 = As[kk][ty*2+1];
      float y0 = Bs[kk][tx*2], y1 = Bs[kk][tx*2+1];
      a00 += x0*y0; a01 += x0*y1; a10 += x1*y0; a11 += x1*y1;
    }
    __syncthreads();
  }
  float* outp = fin_p + (size_t)kc*256*300;
  int r0 = bm + ty*2, c0 = bn + tx*2;
  #pragma unroll
  for (int i = 0; i < 2; ++i){
    #pragma unroll
    for (int j = 0; j < 2; ++j){
      int r = r0 + i, c = c0 + j;
      if (c < 300)
        outp[(size_t)r*300 + c] = (i==0 ? (j==0?a00:a01) : (j==0?a10:a11));
    }
  }
}

// fused: final = partial-sum + ab2 + sgs for rows b and 128+b, then cosine
__global__ __launch_bounds__(64)
void k_mlp2cos(const float* __restrict__ fin_p, const float* __restrict__ sgs,
               const float* __restrict__ ab2, float* __restrict__ out){
  int b = blockIdx.x, lane = threadIdx.x;
  const size_t Q = (size_t)256*300;
  float dot = 0.f, na = 0.f, nb = 0.f;
  for (int j = lane; j < 300; j += 64){
    size_t ia = (size_t)b*300 + j;
    size_t ib = (size_t)(128 + b)*300 + j;
    float xa = (fin_p[ia] + fin_p[Q+ia]) + (fin_p[2*Q+ia] + fin_p[3*Q+ia]);
    xa += ab2[j] + sgs[ia];
    float xb = (fin_p[ib] + fin_p[Q+ib]) + (fin_p[2*Q+ib] + fin_p[3*Q+ib]);
    xb += ab2[j] + sgs[ib];
    dot += xa*xb; na += xa*xa; nb += xb*xb;
  }
  for (int o = 32; o > 0; o >>= 1){
    dot += __shfl_xor(dot, o); na += __shfl_xor(na, o); nb += __shfl_xor(nb, o);
  }
  if (lane == 0){
    float den = fmaxf(sqrtf(na), 1e-8f) * fmaxf(sqrtf(nb), 1e-8f);
    out[b] = 5.f * dot / den;
  }
}

extern "C" void kernel_launch(void* const* d_in, const int* in_sizes, int n_in,
                              void* d_out, int out_size, void* d_ws, size_t ws_size,
                              hipStream_t stream) {
  const int* ids_a = (const int*)d_in[0];
  const void* mask_a = d_in[1];
  const int* ids_b = (const int*)d_in[2];
  const void* mask_b = d_in[3];
  const float* mu_tab     = (const float*)d_in[4];
  const float* logvar_tab = (const float*)d_in[5];
  const float* alpha_tab  = (const float*)d_in[6];
  const float* feat_tab   = (const float*)d_in[7];
  const float* log_tau    = (const float*)d_in[8];
  const float* pos_mu     = (const float*)d_in[9];
  const float* pos_alpha  = (const float*)d_in[10];
  const float* ln1g = (const float*)d_in[11];
  const float* ln1b = (const float*)d_in[12];
  const float* w1   = (const float*)d_in[13];
  const float* b1   = (const float*)d_in[14];
  const float* w2   = (const float*)d_in[15];
  const float* b2   = (const float*)d_in[16];
  const float* wq   = (const float*)d_in[17];
  const float* bq   = (const float*)d_in[18];
  const float* wk   = (const float*)d_in[19];
  const float* bk   = (const float*)d_in[20];
  const float* ln2g = (const float*)d_in[21];
  const float* ln2b = (const float*)d_in[22];
  const float* aw1  = (const float*)d_in[23];
  const float* ab1  = (const float*)d_in[24];
  const float* aw2  = (const float*)d_in[25];
  const float* ab2  = (const float*)d_in[26];
  float* out = (float*)d_out;

  char* wsb = (char*)d_ws;
  size_t off = 0;
  auto take = [&](size_t bytes) -> void* {
    void* p = wsb + off;
    off += (bytes + 255) & ~(size_t)255;
    return p;
  };

  const size_t uBytes  = (size_t)30000 * 600 * 2;   // 36.0 MB
  const size_t aBytes  = (size_t)30080 * 320 * 2;   // 19.3 MB (stays live)
  const size_t btBytes = (size_t)640 * 320 * 2;     // 0.41 MB
  const size_t muBytes = (size_t)256 * 512 * 64 * 2;// 16.8 MB (aliased post-stage1)
  const size_t need = uBytes + aBytes + btBytes + muBytes + ((size_t)8 << 20);
  if (ws_size < need) return;

  __hip_bfloat16* U = (__hip_bfloat16*)take(uBytes);
  ushort* Abf = (ushort*)take(aBytes);
  ushort* BTbf = (ushort*)take(btBytes);
  char* muRegion = (char*)take(muBytes);
  ushort* MuS = (ushort*)muRegion;
  float* hbar_p = (float*)(muRegion + 0);                 // 8*256*608*4 = 4,980,736
  float* Fbar_p = (float*)(muRegion + 4980736);           // 8*256*300*4 = 2,457,600
  float* att_g  = (float*)(muRegion + 7438336);           //   307,200
  float* g2_g   = (float*)(muRegion + 7745536);           //   622,592
  float* hbar_s = (float*)(muRegion + 8675328);           //   622,592
  float* Fbar_s = (float*)(muRegion + 9297920);           //   307,200
  float* att_p  = (float*)(muRegion + 9605120);           // 4*256*300*4 = 1,228,800
  float* g2_p   = (float*)(muRegion + 10833920);          // 4*256*608*4 = 2,490,368
  float* fin_p  = (float*)(muRegion + 13324288);          // 4*256*300*4 = 1,228,800

  float* fsum   = (float*)take(30000*4);
  float* fsq    = (float*)take(30000*4);
  float* pgw    = (float*)take(8*600*4);
  float* pcv    = (float*)take(8*600*4);
  float* gw_g   = (float*)take(600*4);
  float* c_g    = (float*)take(600*4);
  float* sgs_g  = (float*)take(256*300*4);
  float* ssum_g = (float*)take(256*4);
  float* ssq_g  = (float*)take(256*4);
  float* V_g    = (float*)take(256*600*4);
  float* wgt_g  = (float*)take(256*512*4);
  float* m_g    = (float*)take(256*4);
  float* rs_g   = (float*)take(256*4);
  float* cent_p = (float*)take((size_t)2048*64*4);
  float* msum_p = (float*)take(2048*4);
  float* cent   = (float*)take(256*64*4);
  float* al_g   = (float*)take((size_t)256*512*4);
  float* wsum_p = (float*)take(2048*4);
  float* sgs_p  = (float*)take((size_t)2048*304*4);

  k_pack_stats<<<7520, 256, 0, stream>>>(feat_tab, Abf, fsum, fsq);
  k_pack_b<<<(640*320 + 255)/256, 256, 0, stream>>>(w1, ln1g, BTbf);
  k_gw1_part<<<dim3(3, 8), 256, 0, stream>>>(w1, ln1g, ln1b, pgw, pcv);
  k_gw_reduce<<<3, 256, 0, stream>>>(pgw, pcv, b1, gw_g, c_g);
  k_ugemm_mfma<<<dim3(235, 5), 256, 0, stream>>>(Abf, BTbf, U);
  k_mu_stage<<<2048, 256, 0, stream>>>(ids_a, mask_a, ids_b, mask_b,
                                       mu_tab, pos_mu, alpha_tab, pos_alpha,
                                       MuS, cent_p, msum_p, al_g);
  k_cent_reduce<<<256, 64, 0, stream>>>(cent_p, msum_p, cent);
  k_wrender<<<2048, 256, 0, stream>>>(ids_a, ids_b, logvar_tab, MuS, cent, al_g,
                                      log_tau, Abf, wsum_p, sgs_p);
  k_stage1c<<<256, 512, 0, stream>>>(ids_a, mask_a, ids_b, mask_b,
                                     MuS, sgs_p, wsum_p,
                                     wq, bq, wk, bk,
                                     sgs_g, ssum_g, ssq_g, wgt_g);
  k_vgemm2<<<dim3(8, 19), 256, 0, stream>>>(sgs_g, w1, ln1g, V_g);
  k_hbar_fbar<<<2048, 256, 0, stream>>>(ids_a, ids_b, U, Abf, fsum, fsq,
                                        ssum_g, ssq_g, V_g, gw_g, c_g, wgt_g,
                                        hbar_p, Fbar_p);
  k_hreduce<<<608, 256, 0, stream>>>(hbar_p, Fbar_p, hbar_s, Fbar_s);
  k_att_sk<<<dim3(8, 10, 4), 256, 0, stream>>>(hbar_s, w2, att_p);
  k_att_stats<<<256, 64, 0, stream>>>(att_p, Fbar_s, b2, ssum_g, ssq_g, att_g, m_g, rs_g);
  k_mlp1_sk<<<dim3(8, 19, 4), 256, 0, stream>>>(sgs_g, att_g, m_g, rs_g, ln2g, ln2b, aw1, g2_p);
  k_mlp1_red<<<608, 256, 0, stream>>>(g2_p, ab1, g2_g);
  k_mlp2_sk<<<dim3(8, 10, 4), 256, 0, stream>>>(g2_g, aw2, fin_p);
  k_mlp2cos<<<128, 64, 0, stream>>>(fin_p, sgs_g, ab2, out);
}